// Round 4
// baseline (724.588 us; speedup 1.0000x reference)
//
#include <hip/hip_runtime.h>

#define B_   16
#define T_   3000
#define N_   128
#define WIN_ 30
#define WN_  100
#define D_   64
#define HID_ 128
#define K_   32
#define G4_  512   // 4*HID_

typedef unsigned short us;
typedef __attribute__((ext_vector_type(8))) short short8;
typedef __attribute__((ext_vector_type(4))) short short4v;
typedef __attribute__((ext_vector_type(4))) float floatx4;

__device__ __forceinline__ us f2bf(float f) {
    unsigned u = __float_as_uint(f);
    u += 0x7fffu + ((u >> 16) & 1u);
    return (us)(u >> 16);
}
__device__ __forceinline__ float bf2f(us h) {
    return __uint_as_float(((unsigned)h) << 16);
}
// Single-instruction v_rcp_f32 (~1 ulp; rcp(inf)=0 keeps saturation graceful).
__device__ __forceinline__ float rcpa(float x) { return __builtin_amdgcn_rcpf(x); }
__device__ __forceinline__ float sigf(float x) { return rcpa(1.f + __expf(-x)); }
__device__ __forceinline__ float tanhfast(float x) { return 2.f / (1.f + __expf(-2.f * x)) - 1.f; }
// Barrier WITHOUT vmcnt drain: LDS ordering only.  Safe when all global
// loads/stores crossing it are wave-private (consumed by issuing wave).
__device__ __forceinline__ void ldsbar() {
    __asm__ volatile("s_waitcnt lgkmcnt(0)\n\ts_barrier" ::: "memory");
}

// ---------------------------------------------------------------------------
// Kernel 1: SignalRep conv (unchanged — verified).
// ---------------------------------------------------------------------------
__global__ __launch_bounds__(256) void conv_kernel(
    const float* __restrict__ x, const float* __restrict__ w1,
    const float* __restrict__ b1, const float* __restrict__ w2,
    const float* __restrict__ b2, const float* __restrict__ pw,
    const float* __restrict__ pb, us* __restrict__ Hs)
{
    __shared__ __align__(16) float xs_all[30 * 128];   // [t][n]
    __shared__ __align__(16) us h1s[8 * 36 * 40];      // [s][t'][ci]
    __shared__ __align__(16) float Ms[128 * 40];       // [n][co] means (/30)
    __shared__ __align__(16) us PwT_hi[64 * 40];       // [d][co]
    __shared__ __align__(16) us PwT_lo[64 * 40];
    const int tid = threadIdx.x;
    const int win = blockIdx.x;
    const int b = win / WN_, w = win - b * WN_;
    const float* xb = x + ((size_t)b * T_ + (size_t)w * WIN_) * N_;
    const int lane = tid & 63, wv = tid >> 6;
    const int l15 = lane & 15, quad = lane >> 4;

    {
        const float4* xb4 = (const float4*)xb;
        float4* xs4 = (float4*)xs_all;
        for (int i = tid; i < 960; i += 256) xs4[i] = xb4[i];
    }
    for (int i = tid; i < 2048; i += 256) {
        int co = i >> 6, d = i & 63;
        float v = pw[i];
        us hi = f2bf(v);
        PwT_hi[d * 40 + co] = hi;
        PwT_lo[d * 40 + co] = f2bf(v - bf2f(hi));
    }
    for (int i = tid; i < 1920; i += 256) {            // zero h1 pad rows
        int s = i / 240, r = i % 240;
        int ti = r / 40, c = r % 40;
        int tp = (ti < 2) ? ti : (30 + ti);
        h1s[(s * 36 + tp) * 40 + c] = 0;
    }
    short8 whf[2][5];
    #pragma unroll
    for (int cot = 0; cot < 2; cot++)
        #pragma unroll
        for (int dk = 0; dk < 5; dk++)
            #pragma unroll
            for (int j = 0; j < 8; j++)
                whf[cot][dk][j] = (short)f2bf(w2[(cot * 16 + l15) * 160 + (quad * 8 + j) * 5 + dk]);
    const float b2c0 = b2[l15], b2c1 = b2[16 + l15];
    const int ci2 = lane & 15, th = (lane >> 4) & 1, sloc = lane >> 5;
    float w1ra[5], w1rb[5];
    #pragma unroll
    for (int k = 0; k < 5; k++) {
        w1ra[k] = w1[(2 * ci2) * 5 + k];
        w1rb[k] = w1[(2 * ci2 + 1) * 5 + k];
    }
    const float b1a = b1[2 * ci2], b1b = b1[2 * ci2 + 1];
    float pbv[4];
    #pragma unroll
    for (int nt = 0; nt < 4; nt++) pbv[nt] = pb[nt * 16 + l15];
    ldsbar();

    for (int g = 0; g < 16; g++) {
        const int n1 = g * 8 + wv * 2 + sloc;
        {
            float xr[19];
            #pragma unroll
            for (int u = 0; u < 19; u++) {
                int p = th * 15 - 2 + u;
                xr[u] = ((unsigned)p < 30u) ? xs_all[p * 128 + n1] : 0.f;
            }
            const int rbase = (wv * 2 + sloc) * 36 + 2 + th * 15;
            #pragma unroll
            for (int tt = 0; tt < 15; tt++) {
                float aa = b1a, ab = b1b;
                #pragma unroll
                for (int k = 0; k < 5; k++) {
                    aa += xr[tt + k] * w1ra[k];
                    ab += xr[tt + k] * w1rb[k];
                }
                unsigned pk = (unsigned)f2bf(fmaxf(aa, 0.f))
                            | ((unsigned)f2bf(fmaxf(ab, 0.f)) << 16);
                *(unsigned*)&h1s[(rbase + tt) * 40 + 2 * ci2] = pk;
            }
        }
        __builtin_amdgcn_wave_barrier();
        #pragma unroll
        for (int s2 = 0; s2 < 2; s2++) {
            const int sl = wv * 2 + s2;
            const int nn = g * 8 + sl;
            floatx4 c00 = {b2c0, b2c0, b2c0, b2c0};
            floatx4 c01 = {b2c1, b2c1, b2c1, b2c1};
            floatx4 c10 = {b2c0, b2c0, b2c0, b2c0};
            floatx4 c11 = {b2c1, b2c1, b2c1, b2c1};
            #pragma unroll
            for (int dk = 0; dk < 5; dk++) {
                short8 a0 = *(const short8*)&h1s[(sl * 36 + l15 + dk) * 40 + quad * 8];
                short8 a1 = *(const short8*)&h1s[(sl * 36 + 16 + l15 + dk) * 40 + quad * 8];
                c00 = __builtin_amdgcn_mfma_f32_16x16x32_bf16(a0, whf[0][dk], c00, 0, 0, 0);
                c01 = __builtin_amdgcn_mfma_f32_16x16x32_bf16(a0, whf[1][dk], c01, 0, 0, 0);
                c10 = __builtin_amdgcn_mfma_f32_16x16x32_bf16(a1, whf[0][dk], c10, 0, 0, 0);
                c11 = __builtin_amdgcn_mfma_f32_16x16x32_bf16(a1, whf[1][dk], c11, 0, 0, 0);
            }
            float s0 = 0.f, s1 = 0.f;
            #pragma unroll
            for (int r = 0; r < 4; r++) {
                s0 += fmaxf(c00[r], 0.f);
                s1 += fmaxf(c01[r], 0.f);
                float m0 = (quad * 4 + r < 14) ? fmaxf(c10[r], 0.f) : 0.f;
                float m1 = (quad * 4 + r < 14) ? fmaxf(c11[r], 0.f) : 0.f;
                s0 += m0; s1 += m1;
            }
            s0 += __shfl_xor(s0, 16); s0 += __shfl_xor(s0, 32);
            s1 += __shfl_xor(s1, 16); s1 += __shfl_xor(s1, 32);
            if (quad == 0) {
                Ms[nn * 40 + l15]      = s0 * (1.f / 30.f);
                Ms[nn * 40 + 16 + l15] = s1 * (1.f / 30.f);
            }
        }
        __builtin_amdgcn_wave_barrier();
    }
    ldsbar();
    short8 Ah[2], Al[2];
    #pragma unroll
    for (int i = 0; i < 2; i++) {
        const int mt = wv * 2 + i;
        float4 v0 = *(const float4*)&Ms[(mt * 16 + l15) * 40 + quad * 8];
        float4 v1 = *(const float4*)&Ms[(mt * 16 + l15) * 40 + quad * 8 + 4];
        float vv[8] = {v0.x, v0.y, v0.z, v0.w, v1.x, v1.y, v1.z, v1.w};
        #pragma unroll
        for (int j = 0; j < 8; j++) {
            us hi = f2bf(vv[j]);
            Ah[i][j] = (short)hi;
            Al[i][j] = (short)f2bf(vv[j] - bf2f(hi));
        }
    }
    us* hp = Hs + (size_t)win * 8192;
    #pragma unroll
    for (int id = 0; id < 8; id++) {
        const int i = id >> 2, nt = id & 3;
        short8 Bh = *(const short8*)&PwT_hi[(nt * 16 + l15) * 40 + quad * 8];
        short8 Bl = *(const short8*)&PwT_lo[(nt * 16 + l15) * 40 + quad * 8];
        floatx4 a = {pbv[nt], pbv[nt], pbv[nt], pbv[nt]};
        a = __builtin_amdgcn_mfma_f32_16x16x32_bf16(Ah[i], Bh, a, 0, 0, 0);
        a = __builtin_amdgcn_mfma_f32_16x16x32_bf16(Al[i], Bh, a, 0, 0, 0);
        a = __builtin_amdgcn_mfma_f32_16x16x32_bf16(Ah[i], Bl, a, 0, 0, 0);
        const int mt = wv * 2 + i;
        #pragma unroll
        for (int r = 0; r < 4; r++)
            hp[(mt * 16 + quad * 4 + r) * 64 + nt * 16 + l15] = f2bf(a[r]);
    }
}

// ---------------------------------------------------------------------------
// Kernel 2: prep (unchanged).
// ---------------------------------------------------------------------------
__global__ __launch_bounds__(256) void prep_kernel(
    const float* __restrict__ Wh, const float* __restrict__ Wx,
    const float* __restrict__ bx, const float* __restrict__ bh,
    us* __restrict__ WhT, us* __restrict__ WxT, float* __restrict__ bs2)
{
    int i = blockIdx.x * 256 + threadIdx.x;
    if (i < 65536) {
        int jj = i >> 7, h = i & 127;
        WhT[i] = f2bf(Wh[h * G4_ + jj]);
    } else if (i < 98304) {
        int j = i - 65536;
        int jj = j >> 6, d = j & 63;
        WxT[j] = f2bf(Wx[d * G4_ + jj]);
    } else if (i < 98816) {
        int jj = i - 98304;
        bs2[jj] = bx[jj] + bh[jj];
    }
}

// ---------------------------------------------------------------------------
// Kernel 3: fused per-window — softmax S, Hsm, Xc = S^T@Hs, XWxb (unchanged).
// ---------------------------------------------------------------------------
__global__ __launch_bounds__(256) void xcwx_kernel(
    const us* __restrict__ Hs, const float* __restrict__ proto,
    const us* __restrict__ WxT, const float* __restrict__ bs2,
    us* __restrict__ S_out, us* __restrict__ XWx, float* __restrict__ Hsm)
{
    __shared__ __align__(16) us Hnd[128 * 72];
    __shared__ __align__(16) us HsT[64 * 136];
    __shared__ __align__(16) us PT_hi[32 * 72];
    __shared__ __align__(16) us SsT_hi[32 * 136];
    __shared__ __align__(16) us XcA_hi[32 * 72];
    __shared__ float bias[512];
    const int tid = threadIdx.x;
    const int win = blockIdx.x;
    const int lane = tid & 63, wv = tid >> 6;
    const int l15 = lane & 15, quad = lane >> 4;

    {
        const uint2* hp = (const uint2*)(Hs + (size_t)win * 8192);
        #pragma unroll
        for (int it = 0; it < 8; it++) {
            int idx4 = tid + 256 * it;
            int n = idx4 >> 4, dpos = (idx4 & 15) * 4;
            uint2 v = hp[idx4];
            *(uint2*)&Hnd[n * 72 + dpos] = v;
            us s0 = (us)(v.x & 0xffff), s1 = (us)(v.x >> 16);
            us s2 = (us)(v.y & 0xffff), s3 = (us)(v.y >> 16);
            HsT[(dpos + 0) * 136 + n] = s0;
            HsT[(dpos + 1) * 136 + n] = s1;
            HsT[(dpos + 2) * 136 + n] = s2;
            HsT[(dpos + 3) * 136 + n] = s3;
        }
        for (int i = tid; i < 2048; i += 256) {
            int k = i >> 6, d = i & 63;
            PT_hi[k * 72 + d] = f2bf(proto[i]);
        }
        for (int i = tid; i < 512; i += 256) bias[i] = bs2[i];
    }
    __syncthreads();
    floatx4 lg[2][2];
    #pragma unroll
    for (int p = 0; p < 2; p++) {
        const int mt = wv * 2 + p;
        #pragma unroll
        for (int kt = 0; kt < 2; kt++) {
            floatx4 a = {0.f, 0.f, 0.f, 0.f};
            #pragma unroll
            for (int kb = 0; kb < 2; kb++) {
                short8 af  = *(const short8*)&Hnd[(mt * 16 + l15) * 72 + kb * 32 + quad * 8];
                short8 bhf = *(const short8*)&PT_hi[(kt * 16 + l15) * 72 + kb * 32 + quad * 8];
                a = __builtin_amdgcn_mfma_f32_16x16x32_bf16(af, bhf, a, 0, 0, 0);
            }
            lg[p][kt] = a;
        }
    }
    #pragma unroll
    for (int p = 0; p < 2; p++) {
        #pragma unroll
        for (int r = 0; r < 4; r++) {
            float v0 = lg[p][0][r], v1 = lg[p][1][r];
            float m = fmaxf(v0, v1);
            #pragma unroll
            for (int off = 8; off; off >>= 1) m = fmaxf(m, __shfl_xor(m, off));
            float e0 = expf(v0 - m), e1 = expf(v1 - m);
            float s = e0 + e1;
            #pragma unroll
            for (int off = 8; off; off >>= 1) s += __shfl_xor(s, off);
            float inv = 1.f / s;
            e0 *= inv; e1 *= inv;
            const int n = (wv * 2 + p) * 16 + quad * 4 + r;
            us h0 = f2bf(e0), h1 = f2bf(e1);
            SsT_hi[l15 * 136 + n]        = h0;
            SsT_hi[(16 + l15) * 136 + n] = h1;
            S_out[(size_t)win * 4096 + n * 32 + l15]      = h0;
            S_out[(size_t)win * 4096 + n * 32 + 16 + l15] = h1;
        }
    }
    __syncthreads();
    {
        const int d = tid >> 2, seg = tid & 3;
        float acc = 0.f;
        const unsigned* hp2 = (const unsigned*)&HsT[d * 136 + seg * 32];
        #pragma unroll
        for (int q = 0; q < 16; q++) {
            unsigned v = hp2[q];
            acc += bf2f((us)(v & 0xffff)) + bf2f((us)(v >> 16));
        }
        acc += __shfl_xor(acc, 1);
        acc += __shfl_xor(acc, 2);
        if (seg == 0) Hsm[(size_t)win * 64 + d] = acc * (1.f / 128.f);
    }
    #pragma unroll
    for (int p = 0; p < 2; p++) {
        const int id = wv * 2 + p, mt = id >> 2, nt = id & 3;
        floatx4 a = {0.f, 0.f, 0.f, 0.f};
        #pragma unroll
        for (int kb = 0; kb < 4; kb++) {
            short8 ah = *(const short8*)&SsT_hi[(mt * 16 + l15) * 136 + kb * 32 + quad * 8];
            short8 bf_ = *(const short8*)&HsT[(nt * 16 + l15) * 136 + kb * 32 + quad * 8];
            a = __builtin_amdgcn_mfma_f32_16x16x32_bf16(ah, bf_, a, 0, 0, 0);
        }
        #pragma unroll
        for (int r = 0; r < 4; r++) {
            const int k = mt * 16 + quad * 4 + r, d = nt * 16 + l15;
            XcA_hi[k * 72 + d] = f2bf(a[r]);
        }
    }
    __syncthreads();
    short8 Ah[2][2];
    #pragma unroll
    for (int mt = 0; mt < 2; mt++)
        #pragma unroll
        for (int kb = 0; kb < 2; kb++)
            Ah[mt][kb] = *(const short8*)&XcA_hi[(mt * 16 + l15) * 72 + kb * 32 + quad * 8];
    #pragma unroll 1
    for (int i = 0; i < 8; i++) {
        const int nt = wv + 4 * i;
        const float bv = bias[nt * 16 + l15];
        floatx4 acc[2];
        acc[0] = (floatx4){bv, bv, bv, bv};
        acc[1] = (floatx4){bv, bv, bv, bv};
        #pragma unroll
        for (int kb = 0; kb < 2; kb++) {
            short8 wh8 = *(const short8*)&WxT[(size_t)(nt * 16 + l15) * 64 + kb * 32 + quad * 8];
            #pragma unroll
            for (int mt = 0; mt < 2; mt++)
                acc[mt] = __builtin_amdgcn_mfma_f32_16x16x32_bf16(Ah[mt][kb], wh8, acc[mt], 0, 0, 0);
        }
        #pragma unroll
        for (int mt = 0; mt < 2; mt++) {
            uint2 pk;
            pk.x = (unsigned)f2bf(acc[mt][0]) | ((unsigned)f2bf(acc[mt][1]) << 16);
            pk.y = (unsigned)f2bf(acc[mt][2]) | ((unsigned)f2bf(acc[mt][3]) << 16);
            ((uint2*)XWx)[((size_t)win * 64 + mt * 32 + nt) * 64 + lane] = pk;
        }
    }
}

// ---------------------------------------------------------------------------
// Kernel 4: corr -> AS -> Ac -> normalize -> An, then AXWx = An @ XWxb
// (unchanged).
// ---------------------------------------------------------------------------
__global__ __launch_bounds__(256) void corr_kernel(
    const float* __restrict__ x, const us* __restrict__ S_bf,
    us* __restrict__ An, us* __restrict__ XWx)
{
    __shared__ __align__(16) float xs[30 * 128];    // aliased by XA
    __shared__ __align__(16) us SsT[32 * 136];
    __shared__ __align__(16) us pool[21760];        // CB | AST, later XWT
    __shared__ float Acs[32 * 33];
    __shared__ __align__(16) us AnL[32 * 40];
    __shared__ float sinv[128];
    __shared__ float dinv[32];
    us* XA  = (us*)xs;                              // [128][40]
    us* CB  = pool;                                 // [128][136]
    us* AST = pool + 17408;                         // [32][136]
    us* XWT = pool;                                 // [512][40]
    const int tid = threadIdx.x;
    const int win = blockIdx.x;
    const int b = win / WN_, w = win - b * WN_;
    const float* xb = x + ((size_t)b * T_ + (size_t)w * WIN_) * N_;
    const int lane = tid & 63, wv = tid >> 6;
    const int l15 = lane & 15, quad = lane >> 4;
    const float inv29 = 1.f / (WIN_ - 1 + 1e-8f);

    for (int i = tid; i < 3840; i += 256) xs[i] = xb[i];
    for (int i = tid; i < 4096; i += 256) {
        int n = i >> 5, k = i & 31;
        SsT[k * 136 + n] = S_bf[(size_t)win * 4096 + i];
    }
    __syncthreads();
    float xr[30];
    if (tid < 128) {
        const int n = tid;
        float mean = 0.f;
        #pragma unroll
        for (int l = 0; l < 30; l++) { xr[l] = xs[l * 128 + n]; mean += xr[l]; }
        mean *= (1.f / 30.f);
        float var = 0.f;
        #pragma unroll
        for (int l = 0; l < 30; l++) {
            float v = xr[l] - mean;
            var += v * v;
            xr[l] = v;
        }
        var *= inv29;
        sinv[tid] = rsqrtf(fmaxf(var, 1e-8f));
    }
    __syncthreads();
    if (tid < 128) {
        #pragma unroll
        for (int l = 0; l < 30; l++) XA[tid * 40 + l] = f2bf(xr[l]);
        XA[tid * 40 + 30] = 0; XA[tid * 40 + 31] = 0;
    }
    __syncthreads();
    #pragma unroll 1
    for (int q = 0; q < 16; q++) {
        const int id = wv * 16 + q, mt = id >> 3, nt = id & 7;
        short8 a = *(const short8*)&XA[(mt * 16 + l15) * 40 + quad * 8];
        short8 bb = *(const short8*)&XA[(nt * 16 + l15) * 40 + quad * 8];
        floatx4 d = {0.f, 0.f, 0.f, 0.f};
        d = __builtin_amdgcn_mfma_f32_16x16x32_bf16(a, bb, d, 0, 0, 0);
        const int m = nt * 16 + l15;
        const float sm = sinv[m];
        #pragma unroll
        for (int r = 0; r < 4; r++) {
            const int n = mt * 16 + quad * 4 + r;
            float v = d[r] * inv29 * sinv[n] * sm;
            if (n == m) v = 1.f;
            CB[n * 136 + m] = f2bf(v);
        }
    }
    __syncthreads();
    #pragma unroll 1
    for (int q = 0; q < 4; q++) {
        const int id = wv * 4 + q, mt = id >> 1, lt = id & 1;
        floatx4 d = {0.f, 0.f, 0.f, 0.f};
        #pragma unroll
        for (int kb = 0; kb < 4; kb++) {
            short8 a = *(const short8*)&CB[(mt * 16 + l15) * 136 + kb * 32 + quad * 8];
            short8 bb = *(const short8*)&SsT[(lt * 16 + l15) * 136 + kb * 32 + quad * 8];
            d = __builtin_amdgcn_mfma_f32_16x16x32_bf16(a, bb, d, 0, 0, 0);
        }
        const int l = lt * 16 + l15;
        #pragma unroll
        for (int r = 0; r < 4; r++)
            AST[l * 136 + mt * 16 + quad * 4 + r] = f2bf(d[r]);
    }
    __syncthreads();
    {
        const int kt = wv >> 1, lt = wv & 1;
        floatx4 d = {0.f, 0.f, 0.f, 0.f};
        #pragma unroll
        for (int kb = 0; kb < 4; kb++) {
            short8 a = *(const short8*)&SsT[(kt * 16 + l15) * 136 + kb * 32 + quad * 8];
            short8 bb = *(const short8*)&AST[(lt * 16 + l15) * 136 + kb * 32 + quad * 8];
            d = __builtin_amdgcn_mfma_f32_16x16x32_bf16(a, bb, d, 0, 0, 0);
        }
        #pragma unroll
        for (int r = 0; r < 4; r++)
            Acs[(kt * 16 + quad * 4 + r) * 33 + lt * 16 + l15] = d[r];
    }
    __syncthreads();
    float symv[4];
    {
        int l = tid & 31, kb = tid >> 5;
        for (int r = 0; r < 4; r++) {
            int k = kb + 8 * r;
            symv[r] = 0.5f * (Acs[k * 33 + l] + Acs[l * 33 + k]) + ((k == l) ? 1.f : 0.f);
        }
    }
    __syncthreads();
    {
        int l = tid & 31, kb = tid >> 5;
        for (int r = 0; r < 4; r++) Acs[(kb + 8 * r) * 33 + l] = symv[r];
    }
    __syncthreads();
    if (tid < K_) {
        float s = 0.f;
        for (int l = 0; l < K_; l++) s += Acs[tid * 33 + l];
        dinv[tid] = rsqrtf(fmaxf(s, 1e-8f));
    }
    __syncthreads();
    us* Anw = An + (size_t)win * K_ * K_;
    for (int i = tid; i < K_ * K_; i += 256) {
        int k = i >> 5, l = i & 31;
        us v = f2bf(dinv[k] * Acs[k * 33 + l] * dinv[l]);
        Anw[i] = v;
        AnL[k * 40 + l] = v;
    }
    __syncthreads();
    // ---- stage XWxb (swizzled uint2) -> XWT[jj][m] (pool reuse) ----
    {
        const uint2* xw2 = (const uint2*)XWx + (size_t)win * 4096;
        for (int i = tid; i < 4096; i += 256) {
            uint2 v = xw2[i];
            int tile = i >> 6, lane2 = i & 63;
            int mt2 = tile >> 5, nt2 = tile & 31;
            int jj = nt2 * 16 + (lane2 & 15);
            int m0 = mt2 * 16 + (lane2 >> 4) * 4;
            *(uint2*)&XWT[jj * 40 + m0] = v;
        }
    }
    __syncthreads();
    // ---- AXWx = An @ XWxb, stored back in-place (swizzled) ----
    short8 anA[2];
    anA[0] = *(const short8*)&AnL[l15 * 40 + quad * 8];
    anA[1] = *(const short8*)&AnL[(16 + l15) * 40 + quad * 8];
    #pragma unroll 1
    for (int i = 0; i < 8; i++) {
        const int nt = wv + 4 * i;
        short8 bfr = *(const short8*)&XWT[(nt * 16 + l15) * 40 + quad * 8];
        #pragma unroll
        for (int mt2 = 0; mt2 < 2; mt2++) {
            floatx4 a = {0.f, 0.f, 0.f, 0.f};
            a = __builtin_amdgcn_mfma_f32_16x16x32_bf16(anA[mt2], bfr, a, 0, 0, 0);
            uint2 pk;
            pk.x = (unsigned)f2bf(a[0]) | ((unsigned)f2bf(a[1]) << 16);
            pk.y = (unsigned)f2bf(a[2]) | ((unsigned)f2bf(a[3]) << 16);
            ((uint2*)XWx)[((size_t)win * 64 + mt2 * 32 + nt) * 64 + lane] = pk;
        }
    }
}

// ---------------------------------------------------------------------------
// Kernel 5: GCLSTM scan.  Round-13 = exact r1 body (228 us verified: sigf/
// tanhfast gates, end-of-step Hsq store, f2bf packs) + ONE minimal change:
// the 4-deep dependent MFMA chain per gate accumulator (kb=0..3) is split
// into two 2-deep chains (acc_a: kb 0-1, acc_b: kb 2-3) merged by 16
// v_add_f32.  Cuts ~100cy of MFMA dependency latency from window2's tail;
// f32-ulp-class reassociation only.  Also: Hsq shfl pair issued before the
// HpT pack (bit-exact reorder; shfl latency overlaps pack VALU).
// ---------------------------------------------------------------------------
__global__ __launch_bounds__(1024) void scan_kernel(
    const us* __restrict__ An_bf,   // [bt][k][m]
    const us* __restrict__ AXWx,    // swizzled C-frag layout (gate-major jj)
    const us* __restrict__ WhT,     // [jj][h]
    float* __restrict__ Hsq2)       // [bt][2][128] partial sums (fully written)
{
    __shared__ __align__(16) us HpT[2][128 * 40];   // [h][k]
    __shared__ __align__(16) us P_lds[32 * 136];    // [k][h]

    const int tid  = threadIdx.x;
    const int lane = tid & 63;
    const int wv   = tid >> 6;          // 0..15
    const int b    = blockIdx.x;
    const int l15  = lane & 15, quad = lane >> 4;
    const int mt   = wv >> 3, hb = wv & 7;

    // Wh B-fragments: 4 gates x 4 kb = 64 VGPR
    short8 Bw[4][4];
    #pragma unroll
    for (int g4 = 0; g4 < 4; g4++) {
        const int jj = g4 * 128 + hb * 16 + l15;
        #pragma unroll
        for (int kb = 0; kb < 4; kb++)
            Bw[g4][kb] = *(const short8*)&WhT[(size_t)jj * 128 + kb * 32 + quad * 8];
    }
    // state: cells (k = mt*16 + quad*4 + r, h = hb*16 + l15)
    float Cst[4] = {0.f, 0.f, 0.f, 0.f};
    float Hst[4] = {0.f, 0.f, 0.f, 0.f};
    float H2t[4] = {0.f, 0.f, 0.f, 0.f};

    for (int i = tid; i < 2560; i += 1024) ((unsigned*)HpT[0])[i] = 0;

    const size_t bt0 = (size_t)b * WN_;
    // strength-reduced prefetch pointers (advance per step)
    const uint2* xq = (const uint2*)AXWx + (bt0 * 64 + (size_t)mt * 32 + hb) * 64 + lane;
    const us*   anp = An_bf + bt0 * 1024 + (size_t)(mt * 16 + l15) * 32 + quad * 8;

    uint2 xw[4];
    #pragma unroll
    for (int g4 = 0; g4 < 4; g4++) xw[g4] = xq[g4 * 512];
    short8 anf = *(const short8*)anp;

    #pragma unroll 1
    for (int t = 0; t < WN_; t++) {
        const int buf = t & 1;
        ldsbar();                                   // HpT[buf] ready
        // ---- P = An @ Hp (1 MFMA/wave); anf was prefetched last step ----
        short8 hpB = *(const short8*)&HpT[buf][(hb * 16 + l15) * 40 + quad * 8];
        floatx4 Pa = {0.f, 0.f, 0.f, 0.f};
        Pa = __builtin_amdgcn_mfma_f32_16x16x32_bf16(anf, hpB, Pa, 0, 0, 0);
        #pragma unroll
        for (int r = 0; r < 4; r++)
            P_lds[(mt * 16 + quad * 4 + r) * 136 + hb * 16 + l15] = f2bf(Pa[r]);
        // ---- g acc init from AXWx(t) (1-op unpacks); split accumulators ----
        floatx4 acc_a[4], acc_b[4];
        #pragma unroll
        for (int g4 = 0; g4 < 4; g4++) {
            acc_a[g4][0] = __uint_as_float(xw[g4].x << 16);
            acc_a[g4][1] = __uint_as_float(xw[g4].x & 0xffff0000u);
            acc_a[g4][2] = __uint_as_float(xw[g4].y << 16);
            acc_a[g4][3] = __uint_as_float(xw[g4].y & 0xffff0000u);
            acc_b[g4] = (floatx4){0.f, 0.f, 0.f, 0.f};
        }
        // ---- prefetch t+1 (An and AXWx) — latency hides under the MFMAs ----
        if (t + 1 < WN_) { xq += 4096; anp += 1024; }
        #pragma unroll
        for (int g4 = 0; g4 < 4; g4++) xw[g4] = xq[g4 * 512];
        anf = *(const short8*)anp;
        ldsbar();                                   // P ready
        // ---- g += P @ Wh'  (two 2-deep chains per gate) ----
        #pragma unroll
        for (int kb = 0; kb < 2; kb++) {
            short8 pA = *(const short8*)&P_lds[(mt * 16 + l15) * 136 + kb * 32 + quad * 8];
            #pragma unroll
            for (int g4 = 0; g4 < 4; g4++)
                acc_a[g4] = __builtin_amdgcn_mfma_f32_16x16x32_bf16(pA, Bw[g4][kb], acc_a[g4], 0, 0, 0);
        }
        #pragma unroll
        for (int kb = 2; kb < 4; kb++) {
            short8 pA = *(const short8*)&P_lds[(mt * 16 + l15) * 136 + kb * 32 + quad * 8];
            #pragma unroll
            for (int g4 = 0; g4 < 4; g4++)
                acc_b[g4] = __builtin_amdgcn_mfma_f32_16x16x32_bf16(pA, Bw[g4][kb], acc_b[g4], 0, 0, 0);
        }
        // ---- gates + state (fully in-lane, r1 forms) ----
        #pragma unroll
        for (int r = 0; r < 4; r++) {
            float gi = acc_a[0][r] + acc_b[0][r];
            float gf = acc_a[1][r] + acc_b[1][r];
            float go = acc_a[2][r] + acc_b[2][r];
            float gc = acc_a[3][r] + acc_b[3][r];
            float cn = sigf(gf) * Cst[r] + sigf(gi) * tanhfast(gc);
            float hn = sigf(go) * tanhfast(cn);
            Cst[r] = cn;
            H2t[r] = Hst[r];
            Hst[r] = hn;
        }
        // ---- Hsq partial (shfl issued early; store overlaps HpT pack) ----
        {
            float s = Hst[0] + Hst[1] + Hst[2] + Hst[3];
            s += __shfl_xor(s, 16); s += __shfl_xor(s, 32);
            if (quad == 0)
                Hsq2[((bt0 + t) * 2 + mt) * HID_ + hb * 16 + l15] = s;
        }
        // ---- HpT(t+1): packed b64 write [h][4 consecutive k] ----
        if (t + 1 < WN_) {
            const float dninv = (t + 1 == 1) ? 0.5f : (1.f / 3.f);
            short4v hv;
            #pragma unroll
            for (int r = 0; r < 4; r++)
                hv[r] = (short)f2bf((2.f * Hst[r] + H2t[r]) * dninv);
            *(short4v*)&HpT[buf ^ 1][(hb * 16 + l15) * 40 + mt * 16 + quad * 4] = hv;
        }
    }
}

// ---------------------------------------------------------------------------
// Kernel 6: temporal attention pooling + classifier (unchanged from r1).
// ---------------------------------------------------------------------------
__global__ __launch_bounds__(128) void final_kernel(
    const float* __restrict__ Hsq2, const float* __restrict__ Hsm,
    const float* __restrict__ q_t, const float* __restrict__ q_s,
    const float* __restrict__ cls_w, const float* __restrict__ cls_b,
    float* __restrict__ out)
{
    __shared__ float red[128];
    __shared__ float wt[WN_];
    const int b = blockIdx.x, tid = threadIdx.x;
    float v = q_t[tid];
    red[tid] = v * v;
    __syncthreads();
    for (int off = 64; off; off >>= 1) {
        if (tid < off) red[tid] += red[tid + off];
        __syncthreads();
    }
    const float qtn = sqrtf(red[0]) + 1e-8f;
    __syncthreads();
    float v2 = (tid < D_) ? q_s[tid] : 0.f;
    red[tid] = v2 * v2;
    __syncthreads();
    for (int off = 64; off; off >>= 1) {
        if (tid < off) red[tid] += red[tid + off];
        __syncthreads();
    }
    const float qsn = sqrtf(red[0]) + 1e-8f;
    __syncthreads();
    float sc_t = -1e30f;
    if (tid < WN_) {
        float s = 0.f;
        const float* zr = Hsq2 + ((size_t)b * WN_ + tid) * (2 * HID_);
        for (int h = 0; h < HID_; h++) s += (zr[h] + zr[HID_ + h]) * q_t[h];
        sc_t = s * (1.f / 32.f) / qtn;
    }
    red[tid] = sc_t;
    __syncthreads();
    for (int off = 64; off; off >>= 1) {
        if (tid < off) red[tid] = fmaxf(red[tid], red[tid + off]);
        __syncthreads();
    }
    const float mt_ = red[0];
    __syncthreads();
    float e_t = (tid < WN_) ? expf(sc_t - mt_) : 0.f;
    red[tid] = e_t;
    __syncthreads();
    for (int off = 64; off; off >>= 1) {
        if (tid < off) red[tid] += red[tid + off];
        __syncthreads();
    }
    const float sinv_t = 1.f / red[0];
    __syncthreads();
    if (tid < WN_) wt[tid] = e_t * sinv_t;
    __syncthreads();
    float part = 0.f;
    {
        float z = 0.f;
        for (int w = 0; w < WN_; w++) {
            const float* p = Hsq2 + ((size_t)b * WN_ + w) * (2 * HID_);
            z += wt[w] * (p[tid] + p[HID_ + tid]);
        }
        part += z * (1.f / 32.f) * cls_w[tid];
    }
    __syncthreads();
    float sc_s = -1e30f;
    if (tid < WN_) {
        float s = 0.f;
        const float* zr = Hsm + ((size_t)b * WN_ + tid) * D_;
        for (int dd = 0; dd < D_; dd++) s += zr[dd] * q_s[dd];
        sc_s = s / qsn;
    }
    red[tid] = sc_s;
    __syncthreads();
    for (int off = 64; off; off >>= 1) {
        if (tid < off) red[tid] = fmaxf(red[tid], red[tid + off]);
        __syncthreads();
    }
    const float ms_ = red[0];
    __syncthreads();
    float e_s = (tid < WN_) ? expf(sc_s - ms_) : 0.f;
    red[tid] = e_s;
    __syncthreads();
    for (int off = 64; off; off >>= 1) {
        if (tid < off) red[tid] += red[tid + off];
        __syncthreads();
    }
    const float sinv_s = 1.f / red[0];
    __syncthreads();
    if (tid < WN_) wt[tid] = e_s * sinv_s;
    __syncthreads();
    if (tid < D_) {
        float z = 0.f;
        for (int w = 0; w < WN_; w++)
            z += wt[w] * Hsm[((size_t)b * WN_ + w) * D_ + tid];
        part += z * cls_w[HID_ + tid];
    }
    red[tid] = part;
    __syncthreads();
    for (int off = 64; off; off >>= 1) {
        if (tid < off) red[tid] += red[tid + off];
        __syncthreads();
    }
    if (tid == 0) out[b] = 1.f / (1.f + expf(-(red[0] + cls_b[0])));
}

// ---------------------------------------------------------------------------
extern "C" void kernel_launch(void* const* d_in, const int* in_sizes, int n_in,
                              void* d_out, int out_size, void* d_ws, size_t ws_size,
                              hipStream_t stream)
{
    (void)in_sizes; (void)n_in; (void)out_size; (void)ws_size;
    const float* x     = (const float*)d_in[0];
    const float* w1    = (const float*)d_in[1];
    const float* b1    = (const float*)d_in[2];
    const float* w2    = (const float*)d_in[3];
    const float* b2    = (const float*)d_in[4];
    const float* pw    = (const float*)d_in[5];
    const float* pb    = (const float*)d_in[6];
    const float* proto = (const float*)d_in[7];
    const float* Wx    = (const float*)d_in[8];
    const float* bx    = (const float*)d_in[9];
    const float* Wh    = (const float*)d_in[10];
    const float* bh    = (const float*)d_in[11];
    const float* q_t   = (const float*)d_in[12];
    const float* q_s   = (const float*)d_in[13];
    const float* clw   = (const float*)d_in[14];
    const float* clb   = (const float*)d_in[15];

    float* ws = (float*)d_ws;
    us*    Hs_bf  = (us*)d_ws;                      // [0, 6553600)
    us*    S_bf   = (us*)(ws + 6553600);            // [6553600, 9830400)
    us*    XWx    = (us*)(ws + 9830400);            // XWxb, then AXWx in place
    us*    An_bf  = (us*)(ws + 22937600);           // [22937600, 23756800)
    float* Hsm    = ws + 23756800;                  // [23756800, 23859200)
    // Hsq2 reuses the S_bf region: S is only read by corr_kernel, which
    // completes before scan_kernel writes here (stream-ordered).
    float* Hsq2   = ws + 6553600;
    us*    WhT    = (us*)(ws + 24064000);           // [24064000, 24096768)
    us*    WxT    = (us*)(ws + 24096768);           // [24096768, 24113152)
    float* bs2    = ws + 24129536;                  // [24129536, 24130048)

    prep_kernel<<<386, 256, 0, stream>>>(Wh, Wx, bx, bh, WhT, WxT, bs2);
    conv_kernel<<<B_ * WN_, 256, 0, stream>>>(x, w1, b1, w2, b2, pw, pb, Hs_bf);
    xcwx_kernel<<<B_ * WN_, 256, 0, stream>>>(Hs_bf, proto, WxT, bs2,
                                              S_bf, XWx, Hsm);
    corr_kernel<<<B_ * WN_, 256, 0, stream>>>(x, S_bf, An_bf, XWx);
    scan_kernel<<<B_, 1024, 0, stream>>>(An_bf, XWx, WhT, Hsq2);
    final_kernel<<<B_, 128, 0, stream>>>(Hsq2, Hsm, q_t, q_s, clw, clb,
                                         (float*)d_out);
}

// Round 5
// 576.741 us; speedup vs baseline: 1.2563x; 1.2563x over previous
//
#include <hip/hip_runtime.h>

#define B_   16
#define T_   3000
#define N_   128
#define WIN_ 30
#define WN_  100
#define D_   64
#define HID_ 128
#define K_   32
#define G4_  512   // 4*HID_

typedef unsigned short us;
typedef __attribute__((ext_vector_type(8))) short short8;
typedef __attribute__((ext_vector_type(4))) short short4v;
typedef __attribute__((ext_vector_type(4))) float floatx4;

__device__ __forceinline__ us f2bf(float f) {
    unsigned u = __float_as_uint(f);
    u += 0x7fffu + ((u >> 16) & 1u);
    return (us)(u >> 16);
}
__device__ __forceinline__ float bf2f(us h) {
    return __uint_as_float(((unsigned)h) << 16);
}
// Single-instruction v_rcp_f32 (~1 ulp; rcp(inf)=0 keeps saturation graceful).
__device__ __forceinline__ float rcpa(float x) { return __builtin_amdgcn_rcpf(x); }
__device__ __forceinline__ float sigf(float x) { return rcpa(1.f + __expf(-x)); }
// r5: divide -> rcpa (one v_rcp instead of the ~9-op precise-div sequence).
// Same numeric class as sigf's rcpa (r1-verified, absmax 0.0).
__device__ __forceinline__ float tanhfast(float x) { return 2.f * rcpa(1.f + __expf(-2.f * x)) - 1.f; }
// Barrier WITHOUT vmcnt drain: LDS ordering only.  Safe when all global
// loads/stores crossing it are wave-private (consumed by issuing wave).
__device__ __forceinline__ void ldsbar() {
    __asm__ volatile("s_waitcnt lgkmcnt(0)\n\ts_barrier" ::: "memory");
}

// ---------------------------------------------------------------------------
// Kernel 1: SignalRep conv (unchanged — verified).
// ---------------------------------------------------------------------------
__global__ __launch_bounds__(256) void conv_kernel(
    const float* __restrict__ x, const float* __restrict__ w1,
    const float* __restrict__ b1, const float* __restrict__ w2,
    const float* __restrict__ b2, const float* __restrict__ pw,
    const float* __restrict__ pb, us* __restrict__ Hs)
{
    __shared__ __align__(16) float xs_all[30 * 128];   // [t][n]
    __shared__ __align__(16) us h1s[8 * 36 * 40];      // [s][t'][ci]
    __shared__ __align__(16) float Ms[128 * 40];       // [n][co] means (/30)
    __shared__ __align__(16) us PwT_hi[64 * 40];       // [d][co]
    __shared__ __align__(16) us PwT_lo[64 * 40];
    const int tid = threadIdx.x;
    const int win = blockIdx.x;
    const int b = win / WN_, w = win - b * WN_;
    const float* xb = x + ((size_t)b * T_ + (size_t)w * WIN_) * N_;
    const int lane = tid & 63, wv = tid >> 6;
    const int l15 = lane & 15, quad = lane >> 4;

    {
        const float4* xb4 = (const float4*)xb;
        float4* xs4 = (float4*)xs_all;
        for (int i = tid; i < 960; i += 256) xs4[i] = xb4[i];
    }
    for (int i = tid; i < 2048; i += 256) {
        int co = i >> 6, d = i & 63;
        float v = pw[i];
        us hi = f2bf(v);
        PwT_hi[d * 40 + co] = hi;
        PwT_lo[d * 40 + co] = f2bf(v - bf2f(hi));
    }
    for (int i = tid; i < 1920; i += 256) {            // zero h1 pad rows
        int s = i / 240, r = i % 240;
        int ti = r / 40, c = r % 40;
        int tp = (ti < 2) ? ti : (30 + ti);
        h1s[(s * 36 + tp) * 40 + c] = 0;
    }
    short8 whf[2][5];
    #pragma unroll
    for (int cot = 0; cot < 2; cot++)
        #pragma unroll
        for (int dk = 0; dk < 5; dk++)
            #pragma unroll
            for (int j = 0; j < 8; j++)
                whf[cot][dk][j] = (short)f2bf(w2[(cot * 16 + l15) * 160 + (quad * 8 + j) * 5 + dk]);
    const float b2c0 = b2[l15], b2c1 = b2[16 + l15];
    const int ci2 = lane & 15, th = (lane >> 4) & 1, sloc = lane >> 5;
    float w1ra[5], w1rb[5];
    #pragma unroll
    for (int k = 0; k < 5; k++) {
        w1ra[k] = w1[(2 * ci2) * 5 + k];
        w1rb[k] = w1[(2 * ci2 + 1) * 5 + k];
    }
    const float b1a = b1[2 * ci2], b1b = b1[2 * ci2 + 1];
    float pbv[4];
    #pragma unroll
    for (int nt = 0; nt < 4; nt++) pbv[nt] = pb[nt * 16 + l15];
    ldsbar();

    for (int g = 0; g < 16; g++) {
        const int n1 = g * 8 + wv * 2 + sloc;
        {
            float xr[19];
            #pragma unroll
            for (int u = 0; u < 19; u++) {
                int p = th * 15 - 2 + u;
                xr[u] = ((unsigned)p < 30u) ? xs_all[p * 128 + n1] : 0.f;
            }
            const int rbase = (wv * 2 + sloc) * 36 + 2 + th * 15;
            #pragma unroll
            for (int tt = 0; tt < 15; tt++) {
                float aa = b1a, ab = b1b;
                #pragma unroll
                for (int k = 0; k < 5; k++) {
                    aa += xr[tt + k] * w1ra[k];
                    ab += xr[tt + k] * w1rb[k];
                }
                unsigned pk = (unsigned)f2bf(fmaxf(aa, 0.f))
                            | ((unsigned)f2bf(fmaxf(ab, 0.f)) << 16);
                *(unsigned*)&h1s[(rbase + tt) * 40 + 2 * ci2] = pk;
            }
        }
        __builtin_amdgcn_wave_barrier();
        #pragma unroll
        for (int s2 = 0; s2 < 2; s2++) {
            const int sl = wv * 2 + s2;
            const int nn = g * 8 + sl;
            floatx4 c00 = {b2c0, b2c0, b2c0, b2c0};
            floatx4 c01 = {b2c1, b2c1, b2c1, b2c1};
            floatx4 c10 = {b2c0, b2c0, b2c0, b2c0};
            floatx4 c11 = {b2c1, b2c1, b2c1, b2c1};
            #pragma unroll
            for (int dk = 0; dk < 5; dk++) {
                short8 a0 = *(const short8*)&h1s[(sl * 36 + l15 + dk) * 40 + quad * 8];
                short8 a1 = *(const short8*)&h1s[(sl * 36 + 16 + l15 + dk) * 40 + quad * 8];
                c00 = __builtin_amdgcn_mfma_f32_16x16x32_bf16(a0, whf[0][dk], c00, 0, 0, 0);
                c01 = __builtin_amdgcn_mfma_f32_16x16x32_bf16(a0, whf[1][dk], c01, 0, 0, 0);
                c10 = __builtin_amdgcn_mfma_f32_16x16x32_bf16(a1, whf[0][dk], c10, 0, 0, 0);
                c11 = __builtin_amdgcn_mfma_f32_16x16x32_bf16(a1, whf[1][dk], c11, 0, 0, 0);
            }
            float s0 = 0.f, s1 = 0.f;
            #pragma unroll
            for (int r = 0; r < 4; r++) {
                s0 += fmaxf(c00[r], 0.f);
                s1 += fmaxf(c01[r], 0.f);
                float m0 = (quad * 4 + r < 14) ? fmaxf(c10[r], 0.f) : 0.f;
                float m1 = (quad * 4 + r < 14) ? fmaxf(c11[r], 0.f) : 0.f;
                s0 += m0; s1 += m1;
            }
            s0 += __shfl_xor(s0, 16); s0 += __shfl_xor(s0, 32);
            s1 += __shfl_xor(s1, 16); s1 += __shfl_xor(s1, 32);
            if (quad == 0) {
                Ms[nn * 40 + l15]      = s0 * (1.f / 30.f);
                Ms[nn * 40 + 16 + l15] = s1 * (1.f / 30.f);
            }
        }
        __builtin_amdgcn_wave_barrier();
    }
    ldsbar();
    short8 Ah[2], Al[2];
    #pragma unroll
    for (int i = 0; i < 2; i++) {
        const int mt = wv * 2 + i;
        float4 v0 = *(const float4*)&Ms[(mt * 16 + l15) * 40 + quad * 8];
        float4 v1 = *(const float4*)&Ms[(mt * 16 + l15) * 40 + quad * 8 + 4];
        float vv[8] = {v0.x, v0.y, v0.z, v0.w, v1.x, v1.y, v1.z, v1.w};
        #pragma unroll
        for (int j = 0; j < 8; j++) {
            us hi = f2bf(vv[j]);
            Ah[i][j] = (short)hi;
            Al[i][j] = (short)f2bf(vv[j] - bf2f(hi));
        }
    }
    us* hp = Hs + (size_t)win * 8192;
    #pragma unroll
    for (int id = 0; id < 8; id++) {
        const int i = id >> 2, nt = id & 3;
        short8 Bh = *(const short8*)&PwT_hi[(nt * 16 + l15) * 40 + quad * 8];
        short8 Bl = *(const short8*)&PwT_lo[(nt * 16 + l15) * 40 + quad * 8];
        floatx4 a = {pbv[nt], pbv[nt], pbv[nt], pbv[nt]};
        a = __builtin_amdgcn_mfma_f32_16x16x32_bf16(Ah[i], Bh, a, 0, 0, 0);
        a = __builtin_amdgcn_mfma_f32_16x16x32_bf16(Al[i], Bh, a, 0, 0, 0);
        a = __builtin_amdgcn_mfma_f32_16x16x32_bf16(Ah[i], Bl, a, 0, 0, 0);
        const int mt = wv * 2 + i;
        #pragma unroll
        for (int r = 0; r < 4; r++)
            hp[(mt * 16 + quad * 4 + r) * 64 + nt * 16 + l15] = f2bf(a[r]);
    }
}

// ---------------------------------------------------------------------------
// Kernel 2: prep (unchanged).
// ---------------------------------------------------------------------------
__global__ __launch_bounds__(256) void prep_kernel(
    const float* __restrict__ Wh, const float* __restrict__ Wx,
    const float* __restrict__ bx, const float* __restrict__ bh,
    us* __restrict__ WhT, us* __restrict__ WxT, float* __restrict__ bs2)
{
    int i = blockIdx.x * 256 + threadIdx.x;
    if (i < 65536) {
        int jj = i >> 7, h = i & 127;
        WhT[i] = f2bf(Wh[h * G4_ + jj]);
    } else if (i < 98304) {
        int j = i - 65536;
        int jj = j >> 6, d = j & 63;
        WxT[j] = f2bf(Wx[d * G4_ + jj]);
    } else if (i < 98816) {
        int jj = i - 98304;
        bs2[jj] = bx[jj] + bh[jj];
    }
}

// ---------------------------------------------------------------------------
// Kernel 3: fused per-window — softmax S, Hsm, Xc = S^T@Hs, XWxb (unchanged).
// ---------------------------------------------------------------------------
__global__ __launch_bounds__(256) void xcwx_kernel(
    const us* __restrict__ Hs, const float* __restrict__ proto,
    const us* __restrict__ WxT, const float* __restrict__ bs2,
    us* __restrict__ S_out, us* __restrict__ XWx, float* __restrict__ Hsm)
{
    __shared__ __align__(16) us Hnd[128 * 72];
    __shared__ __align__(16) us HsT[64 * 136];
    __shared__ __align__(16) us PT_hi[32 * 72];
    __shared__ __align__(16) us SsT_hi[32 * 136];
    __shared__ __align__(16) us XcA_hi[32 * 72];
    __shared__ float bias[512];
    const int tid = threadIdx.x;
    const int win = blockIdx.x;
    const int lane = tid & 63, wv = tid >> 6;
    const int l15 = lane & 15, quad = lane >> 4;

    {
        const uint2* hp = (const uint2*)(Hs + (size_t)win * 8192);
        #pragma unroll
        for (int it = 0; it < 8; it++) {
            int idx4 = tid + 256 * it;
            int n = idx4 >> 4, dpos = (idx4 & 15) * 4;
            uint2 v = hp[idx4];
            *(uint2*)&Hnd[n * 72 + dpos] = v;
            us s0 = (us)(v.x & 0xffff), s1 = (us)(v.x >> 16);
            us s2 = (us)(v.y & 0xffff), s3 = (us)(v.y >> 16);
            HsT[(dpos + 0) * 136 + n] = s0;
            HsT[(dpos + 1) * 136 + n] = s1;
            HsT[(dpos + 2) * 136 + n] = s2;
            HsT[(dpos + 3) * 136 + n] = s3;
        }
        for (int i = tid; i < 2048; i += 256) {
            int k = i >> 6, d = i & 63;
            PT_hi[k * 72 + d] = f2bf(proto[i]);
        }
        for (int i = tid; i < 512; i += 256) bias[i] = bs2[i];
    }
    __syncthreads();
    floatx4 lg[2][2];
    #pragma unroll
    for (int p = 0; p < 2; p++) {
        const int mt = wv * 2 + p;
        #pragma unroll
        for (int kt = 0; kt < 2; kt++) {
            floatx4 a = {0.f, 0.f, 0.f, 0.f};
            #pragma unroll
            for (int kb = 0; kb < 2; kb++) {
                short8 af  = *(const short8*)&Hnd[(mt * 16 + l15) * 72 + kb * 32 + quad * 8];
                short8 bhf = *(const short8*)&PT_hi[(kt * 16 + l15) * 72 + kb * 32 + quad * 8];
                a = __builtin_amdgcn_mfma_f32_16x16x32_bf16(af, bhf, a, 0, 0, 0);
            }
            lg[p][kt] = a;
        }
    }
    #pragma unroll
    for (int p = 0; p < 2; p++) {
        #pragma unroll
        for (int r = 0; r < 4; r++) {
            float v0 = lg[p][0][r], v1 = lg[p][1][r];
            float m = fmaxf(v0, v1);
            #pragma unroll
            for (int off = 8; off; off >>= 1) m = fmaxf(m, __shfl_xor(m, off));
            float e0 = expf(v0 - m), e1 = expf(v1 - m);
            float s = e0 + e1;
            #pragma unroll
            for (int off = 8; off; off >>= 1) s += __shfl_xor(s, off);
            float inv = 1.f / s;
            e0 *= inv; e1 *= inv;
            const int n = (wv * 2 + p) * 16 + quad * 4 + r;
            us h0 = f2bf(e0), h1 = f2bf(e1);
            SsT_hi[l15 * 136 + n]        = h0;
            SsT_hi[(16 + l15) * 136 + n] = h1;
            S_out[(size_t)win * 4096 + n * 32 + l15]      = h0;
            S_out[(size_t)win * 4096 + n * 32 + 16 + l15] = h1;
        }
    }
    __syncthreads();
    {
        const int d = tid >> 2, seg = tid & 3;
        float acc = 0.f;
        const unsigned* hp2 = (const unsigned*)&HsT[d * 136 + seg * 32];
        #pragma unroll
        for (int q = 0; q < 16; q++) {
            unsigned v = hp2[q];
            acc += bf2f((us)(v & 0xffff)) + bf2f((us)(v >> 16));
        }
        acc += __shfl_xor(acc, 1);
        acc += __shfl_xor(acc, 2);
        if (seg == 0) Hsm[(size_t)win * 64 + d] = acc * (1.f / 128.f);
    }
    #pragma unroll
    for (int p = 0; p < 2; p++) {
        const int id = wv * 2 + p, mt = id >> 2, nt = id & 3;
        floatx4 a = {0.f, 0.f, 0.f, 0.f};
        #pragma unroll
        for (int kb = 0; kb < 4; kb++) {
            short8 ah = *(const short8*)&SsT_hi[(mt * 16 + l15) * 136 + kb * 32 + quad * 8];
            short8 bf_ = *(const short8*)&HsT[(nt * 16 + l15) * 136 + kb * 32 + quad * 8];
            a = __builtin_amdgcn_mfma_f32_16x16x32_bf16(ah, bf_, a, 0, 0, 0);
        }
        #pragma unroll
        for (int r = 0; r < 4; r++) {
            const int k = mt * 16 + quad * 4 + r, d = nt * 16 + l15;
            XcA_hi[k * 72 + d] = f2bf(a[r]);
        }
    }
    __syncthreads();
    short8 Ah[2][2];
    #pragma unroll
    for (int mt = 0; mt < 2; mt++)
        #pragma unroll
        for (int kb = 0; kb < 2; kb++)
            Ah[mt][kb] = *(const short8*)&XcA_hi[(mt * 16 + l15) * 72 + kb * 32 + quad * 8];
    #pragma unroll 1
    for (int i = 0; i < 8; i++) {
        const int nt = wv + 4 * i;
        const float bv = bias[nt * 16 + l15];
        floatx4 acc[2];
        acc[0] = (floatx4){bv, bv, bv, bv};
        acc[1] = (floatx4){bv, bv, bv, bv};
        #pragma unroll
        for (int kb = 0; kb < 2; kb++) {
            short8 wh8 = *(const short8*)&WxT[(size_t)(nt * 16 + l15) * 64 + kb * 32 + quad * 8];
            #pragma unroll
            for (int mt = 0; mt < 2; mt++)
                acc[mt] = __builtin_amdgcn_mfma_f32_16x16x32_bf16(Ah[mt][kb], wh8, acc[mt], 0, 0, 0);
        }
        #pragma unroll
        for (int mt = 0; mt < 2; mt++) {
            uint2 pk;
            pk.x = (unsigned)f2bf(acc[mt][0]) | ((unsigned)f2bf(acc[mt][1]) << 16);
            pk.y = (unsigned)f2bf(acc[mt][2]) | ((unsigned)f2bf(acc[mt][3]) << 16);
            ((uint2*)XWx)[((size_t)win * 64 + mt * 32 + nt) * 64 + lane] = pk;
        }
    }
}

// ---------------------------------------------------------------------------
// Kernel 4: corr -> AS -> Ac -> normalize -> An, then AXWx = An @ XWxb
// (unchanged).
// ---------------------------------------------------------------------------
__global__ __launch_bounds__(256) void corr_kernel(
    const float* __restrict__ x, const us* __restrict__ S_bf,
    us* __restrict__ An, us* __restrict__ XWx)
{
    __shared__ __align__(16) float xs[30 * 128];    // aliased by XA
    __shared__ __align__(16) us SsT[32 * 136];
    __shared__ __align__(16) us pool[21760];        // CB | AST, later XWT
    __shared__ float Acs[32 * 33];
    __shared__ __align__(16) us AnL[32 * 40];
    __shared__ float sinv[128];
    __shared__ float dinv[32];
    us* XA  = (us*)xs;                              // [128][40]
    us* CB  = pool;                                 // [128][136]
    us* AST = pool + 17408;                         // [32][136]
    us* XWT = pool;                                 // [512][40]
    const int tid = threadIdx.x;
    const int win = blockIdx.x;
    const int b = win / WN_, w = win - b * WN_;
    const float* xb = x + ((size_t)b * T_ + (size_t)w * WIN_) * N_;
    const int lane = tid & 63, wv = tid >> 6;
    const int l15 = lane & 15, quad = lane >> 4;
    const float inv29 = 1.f / (WIN_ - 1 + 1e-8f);

    for (int i = tid; i < 3840; i += 256) xs[i] = xb[i];
    for (int i = tid; i < 4096; i += 256) {
        int n = i >> 5, k = i & 31;
        SsT[k * 136 + n] = S_bf[(size_t)win * 4096 + i];
    }
    __syncthreads();
    float xr[30];
    if (tid < 128) {
        const int n = tid;
        float mean = 0.f;
        #pragma unroll
        for (int l = 0; l < 30; l++) { xr[l] = xs[l * 128 + n]; mean += xr[l]; }
        mean *= (1.f / 30.f);
        float var = 0.f;
        #pragma unroll
        for (int l = 0; l < 30; l++) {
            float v = xr[l] - mean;
            var += v * v;
            xr[l] = v;
        }
        var *= inv29;
        sinv[tid] = rsqrtf(fmaxf(var, 1e-8f));
    }
    __syncthreads();
    if (tid < 128) {
        #pragma unroll
        for (int l = 0; l < 30; l++) XA[tid * 40 + l] = f2bf(xr[l]);
        XA[tid * 40 + 30] = 0; XA[tid * 40 + 31] = 0;
    }
    __syncthreads();
    #pragma unroll 1
    for (int q = 0; q < 16; q++) {
        const int id = wv * 16 + q, mt = id >> 3, nt = id & 7;
        short8 a = *(const short8*)&XA[(mt * 16 + l15) * 40 + quad * 8];
        short8 bb = *(const short8*)&XA[(nt * 16 + l15) * 40 + quad * 8];
        floatx4 d = {0.f, 0.f, 0.f, 0.f};
        d = __builtin_amdgcn_mfma_f32_16x16x32_bf16(a, bb, d, 0, 0, 0);
        const int m = nt * 16 + l15;
        const float sm = sinv[m];
        #pragma unroll
        for (int r = 0; r < 4; r++) {
            const int n = mt * 16 + quad * 4 + r;
            float v = d[r] * inv29 * sinv[n] * sm;
            if (n == m) v = 1.f;
            CB[n * 136 + m] = f2bf(v);
        }
    }
    __syncthreads();
    #pragma unroll 1
    for (int q = 0; q < 4; q++) {
        const int id = wv * 4 + q, mt = id >> 1, lt = id & 1;
        floatx4 d = {0.f, 0.f, 0.f, 0.f};
        #pragma unroll
        for (int kb = 0; kb < 4; kb++) {
            short8 a = *(const short8*)&CB[(mt * 16 + l15) * 136 + kb * 32 + quad * 8];
            short8 bb = *(const short8*)&SsT[(lt * 16 + l15) * 136 + kb * 32 + quad * 8];
            d = __builtin_amdgcn_mfma_f32_16x16x32_bf16(a, bb, d, 0, 0, 0);
        }
        const int l = lt * 16 + l15;
        #pragma unroll
        for (int r = 0; r < 4; r++)
            AST[l * 136 + mt * 16 + quad * 4 + r] = f2bf(d[r]);
    }
    __syncthreads();
    {
        const int kt = wv >> 1, lt = wv & 1;
        floatx4 d = {0.f, 0.f, 0.f, 0.f};
        #pragma unroll
        for (int kb = 0; kb < 4; kb++) {
            short8 a = *(const short8*)&SsT[(kt * 16 + l15) * 136 + kb * 32 + quad * 8];
            short8 bb = *(const short8*)&AST[(lt * 16 + l15) * 136 + kb * 32 + quad * 8];
            d = __builtin_amdgcn_mfma_f32_16x16x32_bf16(a, bb, d, 0, 0, 0);
        }
        #pragma unroll
        for (int r = 0; r < 4; r++)
            Acs[(kt * 16 + quad * 4 + r) * 33 + lt * 16 + l15] = d[r];
    }
    __syncthreads();
    float symv[4];
    {
        int l = tid & 31, kb = tid >> 5;
        for (int r = 0; r < 4; r++) {
            int k = kb + 8 * r;
            symv[r] = 0.5f * (Acs[k * 33 + l] + Acs[l * 33 + k]) + ((k == l) ? 1.f : 0.f);
        }
    }
    __syncthreads();
    {
        int l = tid & 31, kb = tid >> 5;
        for (int r = 0; r < 4; r++) Acs[(kb + 8 * r) * 33 + l] = symv[r];
    }
    __syncthreads();
    if (tid < K_) {
        float s = 0.f;
        for (int l = 0; l < K_; l++) s += Acs[tid * 33 + l];
        dinv[tid] = rsqrtf(fmaxf(s, 1e-8f));
    }
    __syncthreads();
    us* Anw = An + (size_t)win * K_ * K_;
    for (int i = tid; i < K_ * K_; i += 256) {
        int k = i >> 5, l = i & 31;
        us v = f2bf(dinv[k] * Acs[k * 33 + l] * dinv[l]);
        Anw[i] = v;
        AnL[k * 40 + l] = v;
    }
    __syncthreads();
    // ---- stage XWxb (swizzled uint2) -> XWT[jj][m] (pool reuse) ----
    {
        const uint2* xw2 = (const uint2*)XWx + (size_t)win * 4096;
        for (int i = tid; i < 4096; i += 256) {
            uint2 v = xw2[i];
            int tile = i >> 6, lane2 = i & 63;
            int mt2 = tile >> 5, nt2 = tile & 31;
            int jj = nt2 * 16 + (lane2 & 15);
            int m0 = mt2 * 16 + (lane2 >> 4) * 4;
            *(uint2*)&XWT[jj * 40 + m0] = v;
        }
    }
    __syncthreads();
    // ---- AXWx = An @ XWxb, stored back in-place (swizzled) ----
    short8 anA[2];
    anA[0] = *(const short8*)&AnL[l15 * 40 + quad * 8];
    anA[1] = *(const short8*)&AnL[(16 + l15) * 40 + quad * 8];
    #pragma unroll 1
    for (int i = 0; i < 8; i++) {
        const int nt = wv + 4 * i;
        short8 bfr = *(const short8*)&XWT[(nt * 16 + l15) * 40 + quad * 8];
        #pragma unroll
        for (int mt2 = 0; mt2 < 2; mt2++) {
            floatx4 a = {0.f, 0.f, 0.f, 0.f};
            a = __builtin_amdgcn_mfma_f32_16x16x32_bf16(anA[mt2], bfr, a, 0, 0, 0);
            uint2 pk;
            pk.x = (unsigned)f2bf(a[0]) | ((unsigned)f2bf(a[1]) << 16);
            pk.y = (unsigned)f2bf(a[2]) | ((unsigned)f2bf(a[3]) << 16);
            ((uint2*)XWx)[((size_t)win * 64 + mt2 * 32 + nt) * 64 + lane] = pk;
        }
    }
}

// ---------------------------------------------------------------------------
// Kernel 5: GCLSTM scan — EXACT r1 body (verified 228 us / 580 total), with
// the single r5 change living in tanhfast() above (div -> v_rcp).  All
// r2/r3/r4 experiments reverted: single gacc accumulators, kb 0..3 chain,
// HpT write then Hsq store last (store stays OUT of the prefetch wait-set).
// ---------------------------------------------------------------------------
__global__ __launch_bounds__(1024) void scan_kernel(
    const us* __restrict__ An_bf,   // [bt][k][m]
    const us* __restrict__ AXWx,    // swizzled C-frag layout (gate-major jj)
    const us* __restrict__ WhT,     // [jj][h]
    float* __restrict__ Hsq2)       // [bt][2][128] partial sums (fully written)
{
    __shared__ __align__(16) us HpT[2][128 * 40];   // [h][k]
    __shared__ __align__(16) us P_lds[32 * 136];    // [k][h]

    const int tid  = threadIdx.x;
    const int lane = tid & 63;
    const int wv   = tid >> 6;          // 0..15
    const int b    = blockIdx.x;
    const int l15  = lane & 15, quad = lane >> 4;
    const int mt   = wv >> 3, hb = wv & 7;

    // Wh B-fragments: 4 gates x 4 kb = 64 VGPR
    short8 Bw[4][4];
    #pragma unroll
    for (int g4 = 0; g4 < 4; g4++) {
        const int jj = g4 * 128 + hb * 16 + l15;
        #pragma unroll
        for (int kb = 0; kb < 4; kb++)
            Bw[g4][kb] = *(const short8*)&WhT[(size_t)jj * 128 + kb * 32 + quad * 8];
    }
    // state: cells (k = mt*16 + quad*4 + r, h = hb*16 + l15)
    float Cst[4] = {0.f, 0.f, 0.f, 0.f};
    float Hst[4] = {0.f, 0.f, 0.f, 0.f};
    float H2t[4] = {0.f, 0.f, 0.f, 0.f};

    for (int i = tid; i < 2560; i += 1024) ((unsigned*)HpT[0])[i] = 0;

    const size_t bt0 = (size_t)b * WN_;
    // strength-reduced prefetch pointers (advance per step)
    const uint2* xq = (const uint2*)AXWx + (bt0 * 64 + (size_t)mt * 32 + hb) * 64 + lane;
    const us*   anp = An_bf + bt0 * 1024 + (size_t)(mt * 16 + l15) * 32 + quad * 8;

    uint2 xw[4];
    #pragma unroll
    for (int g4 = 0; g4 < 4; g4++) xw[g4] = xq[g4 * 512];
    short8 anf = *(const short8*)anp;

    #pragma unroll 1
    for (int t = 0; t < WN_; t++) {
        const int buf = t & 1;
        ldsbar();                                   // HpT[buf] ready
        // ---- P = An @ Hp (1 MFMA/wave); anf was prefetched last step ----
        short8 hpB = *(const short8*)&HpT[buf][(hb * 16 + l15) * 40 + quad * 8];
        floatx4 Pa = {0.f, 0.f, 0.f, 0.f};
        Pa = __builtin_amdgcn_mfma_f32_16x16x32_bf16(anf, hpB, Pa, 0, 0, 0);
        #pragma unroll
        for (int r = 0; r < 4; r++)
            P_lds[(mt * 16 + quad * 4 + r) * 136 + hb * 16 + l15] = f2bf(Pa[r]);
        // ---- g acc init from AXWx(t) (1-op unpacks) ----
        floatx4 gacc[4];
        #pragma unroll
        for (int g4 = 0; g4 < 4; g4++) {
            gacc[g4][0] = __uint_as_float(xw[g4].x << 16);
            gacc[g4][1] = __uint_as_float(xw[g4].x & 0xffff0000u);
            gacc[g4][2] = __uint_as_float(xw[g4].y << 16);
            gacc[g4][3] = __uint_as_float(xw[g4].y & 0xffff0000u);
        }
        // ---- prefetch t+1 (An and AXWx) — latency hides under the MFMAs ----
        if (t + 1 < WN_) { xq += 4096; anp += 1024; }
        #pragma unroll
        for (int g4 = 0; g4 < 4; g4++) xw[g4] = xq[g4 * 512];
        anf = *(const short8*)anp;
        ldsbar();                                   // P ready
        // ---- g += P @ Wh' ----
        #pragma unroll
        for (int kb = 0; kb < 4; kb++) {
            short8 pA = *(const short8*)&P_lds[(mt * 16 + l15) * 136 + kb * 32 + quad * 8];
            #pragma unroll
            for (int g4 = 0; g4 < 4; g4++)
                gacc[g4] = __builtin_amdgcn_mfma_f32_16x16x32_bf16(pA, Bw[g4][kb], gacc[g4], 0, 0, 0);
        }
        // ---- gates + state (fully in-lane, v_rcp based) ----
        #pragma unroll
        for (int r = 0; r < 4; r++) {
            float gi = gacc[0][r], gf = gacc[1][r];
            float go = gacc[2][r], gc = gacc[3][r];
            float cn = sigf(gf) * Cst[r] + sigf(gi) * tanhfast(gc);
            float hn = sigf(go) * tanhfast(cn);
            Cst[r] = cn;
            H2t[r] = Hst[r];
            Hst[r] = hn;
        }
        // ---- HpT(t+1): packed b64 write [h][4 consecutive k] ----
        if (t + 1 < WN_) {
            const float dninv = (t + 1 == 1) ? 0.5f : (1.f / 3.f);
            short4v hv;
            #pragma unroll
            for (int r = 0; r < 4; r++)
                hv[r] = (short)f2bf((2.f * Hst[r] + H2t[r]) * dninv);
            *(short4v*)&HpT[buf ^ 1][(hb * 16 + l15) * 40 + mt * 16 + quad * 4] = hv;
        }
        // ---- Hsq partial (per-mt, plain store — LAST VMEM op of the step) ----
        {
            float s = Hst[0] + Hst[1] + Hst[2] + Hst[3];
            s += __shfl_xor(s, 16); s += __shfl_xor(s, 32);
            if (quad == 0)
                Hsq2[((bt0 + t) * 2 + mt) * HID_ + hb * 16 + l15] = s;
        }
    }
}

// ---------------------------------------------------------------------------
// Kernel 6: temporal attention pooling + classifier (unchanged from r1).
// ---------------------------------------------------------------------------
__global__ __launch_bounds__(128) void final_kernel(
    const float* __restrict__ Hsq2, const float* __restrict__ Hsm,
    const float* __restrict__ q_t, const float* __restrict__ q_s,
    const float* __restrict__ cls_w, const float* __restrict__ cls_b,
    float* __restrict__ out)
{
    __shared__ float red[128];
    __shared__ float wt[WN_];
    const int b = blockIdx.x, tid = threadIdx.x;
    float v = q_t[tid];
    red[tid] = v * v;
    __syncthreads();
    for (int off = 64; off; off >>= 1) {
        if (tid < off) red[tid] += red[tid + off];
        __syncthreads();
    }
    const float qtn = sqrtf(red[0]) + 1e-8f;
    __syncthreads();
    float v2 = (tid < D_) ? q_s[tid] : 0.f;
    red[tid] = v2 * v2;
    __syncthreads();
    for (int off = 64; off; off >>= 1) {
        if (tid < off) red[tid] += red[tid + off];
        __syncthreads();
    }
    const float qsn = sqrtf(red[0]) + 1e-8f;
    __syncthreads();
    float sc_t = -1e30f;
    if (tid < WN_) {
        float s = 0.f;
        const float* zr = Hsq2 + ((size_t)b * WN_ + tid) * (2 * HID_);
        for (int h = 0; h < HID_; h++) s += (zr[h] + zr[HID_ + h]) * q_t[h];
        sc_t = s * (1.f / 32.f) / qtn;
    }
    red[tid] = sc_t;
    __syncthreads();
    for (int off = 64; off; off >>= 1) {
        if (tid < off) red[tid] = fmaxf(red[tid], red[tid + off]);
        __syncthreads();
    }
    const float mt_ = red[0];
    __syncthreads();
    float e_t = (tid < WN_) ? expf(sc_t - mt_) : 0.f;
    red[tid] = e_t;
    __syncthreads();
    for (int off = 64; off; off >>= 1) {
        if (tid < off) red[tid] += red[tid + off];
        __syncthreads();
    }
    const float sinv_t = 1.f / red[0];
    __syncthreads();
    if (tid < WN_) wt[tid] = e_t * sinv_t;
    __syncthreads();
    float part = 0.f;
    {
        float z = 0.f;
        for (int w = 0; w < WN_; w++) {
            const float* p = Hsq2 + ((size_t)b * WN_ + w) * (2 * HID_);
            z += wt[w] * (p[tid] + p[HID_ + tid]);
        }
        part += z * (1.f / 32.f) * cls_w[tid];
    }
    __syncthreads();
    float sc_s = -1e30f;
    if (tid < WN_) {
        float s = 0.f;
        const float* zr = Hsm + ((size_t)b * WN_ + tid) * D_;
        for (int dd = 0; dd < D_; dd++) s += zr[dd] * q_s[dd];
        sc_s = s / qsn;
    }
    red[tid] = sc_s;
    __syncthreads();
    for (int off = 64; off; off >>= 1) {
        if (tid < off) red[tid] = fmaxf(red[tid], red[tid + off]);
        __syncthreads();
    }
    const float ms_ = red[0];
    __syncthreads();
    float e_s = (tid < WN_) ? expf(sc_s - ms_) : 0.f;
    red[tid] = e_s;
    __syncthreads();
    for (int off = 64; off; off >>= 1) {
        if (tid < off) red[tid] += red[tid + off];
        __syncthreads();
    }
    const float sinv_s = 1.f / red[0];
    __syncthreads();
    if (tid < WN_) wt[tid] = e_s * sinv_s;
    __syncthreads();
    if (tid < D_) {
        float z = 0.f;
        for (int w = 0; w < WN_; w++)
            z += wt[w] * Hsm[((size_t)b * WN_ + w) * D_ + tid];
        part += z * cls_w[HID_ + tid];
    }
    red[tid] = part;
    __syncthreads();
    for (int off = 64; off; off >>= 1) {
        if (tid < off) red[tid] += red[tid + off];
        __syncthreads();
    }
    if (tid == 0) out[b] = 1.f / (1.f + expf(-(red[0] + cls_b[0])));
}

// ---------------------------------------------------------------------------
extern "C" void kernel_launch(void* const* d_in, const int* in_sizes, int n_in,
                              void* d_out, int out_size, void* d_ws, size_t ws_size,
                              hipStream_t stream)
{
    (void)in_sizes; (void)n_in; (void)out_size; (void)ws_size;
    const float* x     = (const float*)d_in[0];
    const float* w1    = (const float*)d_in[1];
    const float* b1    = (const float*)d_in[2];
    const float* w2    = (const float*)d_in[3];
    const float* b2    = (const float*)d_in[4];
    const float* pw    = (const float*)d_in[5];
    const float* pb    = (const float*)d_in[6];
    const float* proto = (const float*)d_in[7];
    const float* Wx    = (const float*)d_in[8];
    const float* bx    = (const float*)d_in[9];
    const float* Wh    = (const float*)d_in[10];
    const float* bh    = (const float*)d_in[11];
    const float* q_t   = (const float*)d_in[12];
    const float* q_s   = (const float*)d_in[13];
    const float* clw   = (const float*)d_in[14];
    const float* clb   = (const float*)d_in[15];

    float* ws = (float*)d_ws;
    us*    Hs_bf  = (us*)d_ws;                      // [0, 6553600)
    us*    S_bf   = (us*)(ws + 6553600);            // [6553600, 9830400)
    us*    XWx    = (us*)(ws + 9830400);            // XWxb, then AXWx in place
    us*    An_bf  = (us*)(ws + 22937600);           // [22937600, 23756800)
    float* Hsm    = ws + 23756800;                  // [23756800, 23859200)
    // Hsq2 reuses the S_bf region: S is only read by corr_kernel, which
    // completes before scan_kernel writes here (stream-ordered).
    float* Hsq2   = ws + 6553600;
    us*    WhT    = (us*)(ws + 24064000);           // [24064000, 24096768)
    us*    WxT    = (us*)(ws + 24096768);           // [24096768, 24113152)
    float* bs2    = ws + 24129536;                  // [24129536, 24130048)

    prep_kernel<<<386, 256, 0, stream>>>(Wh, Wx, bx, bh, WhT, WxT, bs2);
    conv_kernel<<<B_ * WN_, 256, 0, stream>>>(x, w1, b1, w2, b2, pw, pb, Hs_bf);
    xcwx_kernel<<<B_ * WN_, 256, 0, stream>>>(Hs_bf, proto, WxT, bs2,
                                              S_bf, XWx, Hsm);
    corr_kernel<<<B_ * WN_, 256, 0, stream>>>(x, S_bf, An_bf, XWx);
    scan_kernel<<<B_, 1024, 0, stream>>>(An_bf, XWx, WhT, Hsq2);
    final_kernel<<<B_, 128, 0, stream>>>(Hsq2, Hsm, q_t, q_s, clw, clb,
                                         (float*)d_out);
}

// Round 6
// 564.351 us; speedup vs baseline: 1.2839x; 1.0220x over previous
//
#include <hip/hip_runtime.h>

#define B_   16
#define T_   3000
#define N_   128
#define WIN_ 30
#define WN_  100
#define D_   64
#define HID_ 128
#define K_   32
#define G4_  512   // 4*HID_

typedef unsigned short us;
typedef __attribute__((ext_vector_type(8))) short short8;
typedef __attribute__((ext_vector_type(4))) short short4v;
typedef __attribute__((ext_vector_type(4))) float floatx4;

__device__ __forceinline__ us f2bf(float f) {
    unsigned u = __float_as_uint(f);
    u += 0x7fffu + ((u >> 16) & 1u);
    return (us)(u >> 16);
}
__device__ __forceinline__ float bf2f(us h) {
    return __uint_as_float(((unsigned)h) << 16);
}
// Single-instruction v_rcp_f32 (~1 ulp; rcp(inf)=0 keeps saturation graceful).
__device__ __forceinline__ float rcpa(float x) { return __builtin_amdgcn_rcpf(x); }
__device__ __forceinline__ float ex2(float x) { return __builtin_amdgcn_exp2f(x); }
// Barrier WITHOUT vmcnt drain: LDS ordering only.  Safe when all global
// loads/stores crossing it are wave-private (consumed by issuing wave).
__device__ __forceinline__ void ldsbar() {
    __asm__ volatile("s_waitcnt lgkmcnt(0)\n\ts_barrier" ::: "memory");
}

// exp-prescale constants folded into the gate weights (r6):
//   gates i,f,o:  arg' = -log2e   * arg   -> sig(arg)  = rcp(1+2^arg')
//   gate  c:      arg' = -2*log2e * arg   -> tanh(arg) = 2*rcp(1+2^arg')-1
#define SC_IFO (-1.4426950408889634f)
#define SC_C   (-2.8853900817779268f)

// ---------------------------------------------------------------------------
// Kernel 1: SignalRep conv (unchanged — verified).
// ---------------------------------------------------------------------------
__global__ __launch_bounds__(256) void conv_kernel(
    const float* __restrict__ x, const float* __restrict__ w1,
    const float* __restrict__ b1, const float* __restrict__ w2,
    const float* __restrict__ b2, const float* __restrict__ pw,
    const float* __restrict__ pb, us* __restrict__ Hs)
{
    __shared__ __align__(16) float xs_all[30 * 128];   // [t][n]
    __shared__ __align__(16) us h1s[8 * 36 * 40];      // [s][t'][ci]
    __shared__ __align__(16) float Ms[128 * 40];       // [n][co] means (/30)
    __shared__ __align__(16) us PwT_hi[64 * 40];       // [d][co]
    __shared__ __align__(16) us PwT_lo[64 * 40];
    const int tid = threadIdx.x;
    const int win = blockIdx.x;
    const int b = win / WN_, w = win - b * WN_;
    const float* xb = x + ((size_t)b * T_ + (size_t)w * WIN_) * N_;
    const int lane = tid & 63, wv = tid >> 6;
    const int l15 = lane & 15, quad = lane >> 4;

    {
        const float4* xb4 = (const float4*)xb;
        float4* xs4 = (float4*)xs_all;
        for (int i = tid; i < 960; i += 256) xs4[i] = xb4[i];
    }
    for (int i = tid; i < 2048; i += 256) {
        int co = i >> 6, d = i & 63;
        float v = pw[i];
        us hi = f2bf(v);
        PwT_hi[d * 40 + co] = hi;
        PwT_lo[d * 40 + co] = f2bf(v - bf2f(hi));
    }
    for (int i = tid; i < 1920; i += 256) {            // zero h1 pad rows
        int s = i / 240, r = i % 240;
        int ti = r / 40, c = r % 40;
        int tp = (ti < 2) ? ti : (30 + ti);
        h1s[(s * 36 + tp) * 40 + c] = 0;
    }
    short8 whf[2][5];
    #pragma unroll
    for (int cot = 0; cot < 2; cot++)
        #pragma unroll
        for (int dk = 0; dk < 5; dk++)
            #pragma unroll
            for (int j = 0; j < 8; j++)
                whf[cot][dk][j] = (short)f2bf(w2[(cot * 16 + l15) * 160 + (quad * 8 + j) * 5 + dk]);
    const float b2c0 = b2[l15], b2c1 = b2[16 + l15];
    const int ci2 = lane & 15, th = (lane >> 4) & 1, sloc = lane >> 5;
    float w1ra[5], w1rb[5];
    #pragma unroll
    for (int k = 0; k < 5; k++) {
        w1ra[k] = w1[(2 * ci2) * 5 + k];
        w1rb[k] = w1[(2 * ci2 + 1) * 5 + k];
    }
    const float b1a = b1[2 * ci2], b1b = b1[2 * ci2 + 1];
    float pbv[4];
    #pragma unroll
    for (int nt = 0; nt < 4; nt++) pbv[nt] = pb[nt * 16 + l15];
    ldsbar();

    for (int g = 0; g < 16; g++) {
        const int n1 = g * 8 + wv * 2 + sloc;
        {
            float xr[19];
            #pragma unroll
            for (int u = 0; u < 19; u++) {
                int p = th * 15 - 2 + u;
                xr[u] = ((unsigned)p < 30u) ? xs_all[p * 128 + n1] : 0.f;
            }
            const int rbase = (wv * 2 + sloc) * 36 + 2 + th * 15;
            #pragma unroll
            for (int tt = 0; tt < 15; tt++) {
                float aa = b1a, ab = b1b;
                #pragma unroll
                for (int k = 0; k < 5; k++) {
                    aa += xr[tt + k] * w1ra[k];
                    ab += xr[tt + k] * w1rb[k];
                }
                unsigned pk = (unsigned)f2bf(fmaxf(aa, 0.f))
                            | ((unsigned)f2bf(fmaxf(ab, 0.f)) << 16);
                *(unsigned*)&h1s[(rbase + tt) * 40 + 2 * ci2] = pk;
            }
        }
        __builtin_amdgcn_wave_barrier();
        #pragma unroll
        for (int s2 = 0; s2 < 2; s2++) {
            const int sl = wv * 2 + s2;
            const int nn = g * 8 + sl;
            floatx4 c00 = {b2c0, b2c0, b2c0, b2c0};
            floatx4 c01 = {b2c1, b2c1, b2c1, b2c1};
            floatx4 c10 = {b2c0, b2c0, b2c0, b2c0};
            floatx4 c11 = {b2c1, b2c1, b2c1, b2c1};
            #pragma unroll
            for (int dk = 0; dk < 5; dk++) {
                short8 a0 = *(const short8*)&h1s[(sl * 36 + l15 + dk) * 40 + quad * 8];
                short8 a1 = *(const short8*)&h1s[(sl * 36 + 16 + l15 + dk) * 40 + quad * 8];
                c00 = __builtin_amdgcn_mfma_f32_16x16x32_bf16(a0, whf[0][dk], c00, 0, 0, 0);
                c01 = __builtin_amdgcn_mfma_f32_16x16x32_bf16(a0, whf[1][dk], c01, 0, 0, 0);
                c10 = __builtin_amdgcn_mfma_f32_16x16x32_bf16(a1, whf[0][dk], c10, 0, 0, 0);
                c11 = __builtin_amdgcn_mfma_f32_16x16x32_bf16(a1, whf[1][dk], c11, 0, 0, 0);
            }
            float s0 = 0.f, s1 = 0.f;
            #pragma unroll
            for (int r = 0; r < 4; r++) {
                s0 += fmaxf(c00[r], 0.f);
                s1 += fmaxf(c01[r], 0.f);
                float m0 = (quad * 4 + r < 14) ? fmaxf(c10[r], 0.f) : 0.f;
                float m1 = (quad * 4 + r < 14) ? fmaxf(c11[r], 0.f) : 0.f;
                s0 += m0; s1 += m1;
            }
            s0 += __shfl_xor(s0, 16); s0 += __shfl_xor(s0, 32);
            s1 += __shfl_xor(s1, 16); s1 += __shfl_xor(s1, 32);
            if (quad == 0) {
                Ms[nn * 40 + l15]      = s0 * (1.f / 30.f);
                Ms[nn * 40 + 16 + l15] = s1 * (1.f / 30.f);
            }
        }
        __builtin_amdgcn_wave_barrier();
    }
    ldsbar();
    short8 Ah[2], Al[2];
    #pragma unroll
    for (int i = 0; i < 2; i++) {
        const int mt = wv * 2 + i;
        float4 v0 = *(const float4*)&Ms[(mt * 16 + l15) * 40 + quad * 8];
        float4 v1 = *(const float4*)&Ms[(mt * 16 + l15) * 40 + quad * 8 + 4];
        float vv[8] = {v0.x, v0.y, v0.z, v0.w, v1.x, v1.y, v1.z, v1.w};
        #pragma unroll
        for (int j = 0; j < 8; j++) {
            us hi = f2bf(vv[j]);
            Ah[i][j] = (short)hi;
            Al[i][j] = (short)f2bf(vv[j] - bf2f(hi));
        }
    }
    us* hp = Hs + (size_t)win * 8192;
    #pragma unroll
    for (int id = 0; id < 8; id++) {
        const int i = id >> 2, nt = id & 3;
        short8 Bh = *(const short8*)&PwT_hi[(nt * 16 + l15) * 40 + quad * 8];
        short8 Bl = *(const short8*)&PwT_lo[(nt * 16 + l15) * 40 + quad * 8];
        floatx4 a = {pbv[nt], pbv[nt], pbv[nt], pbv[nt]};
        a = __builtin_amdgcn_mfma_f32_16x16x32_bf16(Ah[i], Bh, a, 0, 0, 0);
        a = __builtin_amdgcn_mfma_f32_16x16x32_bf16(Al[i], Bh, a, 0, 0, 0);
        a = __builtin_amdgcn_mfma_f32_16x16x32_bf16(Ah[i], Bl, a, 0, 0, 0);
        const int mt = wv * 2 + i;
        #pragma unroll
        for (int r = 0; r < 4; r++)
            hp[(mt * 16 + quad * 4 + r) * 64 + nt * 16 + l15] = f2bf(a[r]);
    }
}

// ---------------------------------------------------------------------------
// Kernel 2: prep — r6: fold the exp2 prescale into the gate weights.
// Gate id = jj>>7 (gate-major jj); gates 0-2 (i,f,o) scaled by -log2e,
// gate 3 (c) by -2*log2e.  bf16 re-rounding of scaled weights is random
// +-ulp relative (zero-mean) — same numeric class as the r1-verified rcpa.
// ---------------------------------------------------------------------------
__global__ __launch_bounds__(256) void prep_kernel(
    const float* __restrict__ Wh, const float* __restrict__ Wx,
    const float* __restrict__ bx, const float* __restrict__ bh,
    us* __restrict__ WhT, us* __restrict__ WxT, float* __restrict__ bs2)
{
    int i = blockIdx.x * 256 + threadIdx.x;
    if (i < 65536) {
        int jj = i >> 7, h = i & 127;
        float sc = (jj >> 7) == 3 ? SC_C : SC_IFO;
        WhT[i] = f2bf(Wh[h * G4_ + jj] * sc);
    } else if (i < 98304) {
        int j = i - 65536;
        int jj = j >> 6, d = j & 63;
        float sc = (jj >> 7) == 3 ? SC_C : SC_IFO;
        WxT[j] = f2bf(Wx[d * G4_ + jj] * sc);
    } else if (i < 98816) {
        int jj = i - 98304;
        float sc = (jj >> 7) == 3 ? SC_C : SC_IFO;
        bs2[jj] = (bx[jj] + bh[jj]) * sc;
    }
}

// ---------------------------------------------------------------------------
// Kernel 3: fused per-window — softmax S, Hsm, Xc = S^T@Hs, XWxb (unchanged;
// the prescale rides through linearly via WxT/bs2).
// ---------------------------------------------------------------------------
__global__ __launch_bounds__(256) void xcwx_kernel(
    const us* __restrict__ Hs, const float* __restrict__ proto,
    const us* __restrict__ WxT, const float* __restrict__ bs2,
    us* __restrict__ S_out, us* __restrict__ XWx, float* __restrict__ Hsm)
{
    __shared__ __align__(16) us Hnd[128 * 72];
    __shared__ __align__(16) us HsT[64 * 136];
    __shared__ __align__(16) us PT_hi[32 * 72];
    __shared__ __align__(16) us SsT_hi[32 * 136];
    __shared__ __align__(16) us XcA_hi[32 * 72];
    __shared__ float bias[512];
    const int tid = threadIdx.x;
    const int win = blockIdx.x;
    const int lane = tid & 63, wv = tid >> 6;
    const int l15 = lane & 15, quad = lane >> 4;

    {
        const uint2* hp = (const uint2*)(Hs + (size_t)win * 8192);
        #pragma unroll
        for (int it = 0; it < 8; it++) {
            int idx4 = tid + 256 * it;
            int n = idx4 >> 4, dpos = (idx4 & 15) * 4;
            uint2 v = hp[idx4];
            *(uint2*)&Hnd[n * 72 + dpos] = v;
            us s0 = (us)(v.x & 0xffff), s1 = (us)(v.x >> 16);
            us s2 = (us)(v.y & 0xffff), s3 = (us)(v.y >> 16);
            HsT[(dpos + 0) * 136 + n] = s0;
            HsT[(dpos + 1) * 136 + n] = s1;
            HsT[(dpos + 2) * 136 + n] = s2;
            HsT[(dpos + 3) * 136 + n] = s3;
        }
        for (int i = tid; i < 2048; i += 256) {
            int k = i >> 6, d = i & 63;
            PT_hi[k * 72 + d] = f2bf(proto[i]);
        }
        for (int i = tid; i < 512; i += 256) bias[i] = bs2[i];
    }
    __syncthreads();
    floatx4 lg[2][2];
    #pragma unroll
    for (int p = 0; p < 2; p++) {
        const int mt = wv * 2 + p;
        #pragma unroll
        for (int kt = 0; kt < 2; kt++) {
            floatx4 a = {0.f, 0.f, 0.f, 0.f};
            #pragma unroll
            for (int kb = 0; kb < 2; kb++) {
                short8 af  = *(const short8*)&Hnd[(mt * 16 + l15) * 72 + kb * 32 + quad * 8];
                short8 bhf = *(const short8*)&PT_hi[(kt * 16 + l15) * 72 + kb * 32 + quad * 8];
                a = __builtin_amdgcn_mfma_f32_16x16x32_bf16(af, bhf, a, 0, 0, 0);
            }
            lg[p][kt] = a;
        }
    }
    #pragma unroll
    for (int p = 0; p < 2; p++) {
        #pragma unroll
        for (int r = 0; r < 4; r++) {
            float v0 = lg[p][0][r], v1 = lg[p][1][r];
            float m = fmaxf(v0, v1);
            #pragma unroll
            for (int off = 8; off; off >>= 1) m = fmaxf(m, __shfl_xor(m, off));
            float e0 = expf(v0 - m), e1 = expf(v1 - m);
            float s = e0 + e1;
            #pragma unroll
            for (int off = 8; off; off >>= 1) s += __shfl_xor(s, off);
            float inv = 1.f / s;
            e0 *= inv; e1 *= inv;
            const int n = (wv * 2 + p) * 16 + quad * 4 + r;
            us h0 = f2bf(e0), h1 = f2bf(e1);
            SsT_hi[l15 * 136 + n]        = h0;
            SsT_hi[(16 + l15) * 136 + n] = h1;
            S_out[(size_t)win * 4096 + n * 32 + l15]      = h0;
            S_out[(size_t)win * 4096 + n * 32 + 16 + l15] = h1;
        }
    }
    __syncthreads();
    {
        const int d = tid >> 2, seg = tid & 3;
        float acc = 0.f;
        const unsigned* hp2 = (const unsigned*)&HsT[d * 136 + seg * 32];
        #pragma unroll
        for (int q = 0; q < 16; q++) {
            unsigned v = hp2[q];
            acc += bf2f((us)(v & 0xffff)) + bf2f((us)(v >> 16));
        }
        acc += __shfl_xor(acc, 1);
        acc += __shfl_xor(acc, 2);
        if (seg == 0) Hsm[(size_t)win * 64 + d] = acc * (1.f / 128.f);
    }
    #pragma unroll
    for (int p = 0; p < 2; p++) {
        const int id = wv * 2 + p, mt = id >> 2, nt = id & 3;
        floatx4 a = {0.f, 0.f, 0.f, 0.f};
        #pragma unroll
        for (int kb = 0; kb < 4; kb++) {
            short8 ah = *(const short8*)&SsT_hi[(mt * 16 + l15) * 136 + kb * 32 + quad * 8];
            short8 bf_ = *(const short8*)&HsT[(nt * 16 + l15) * 136 + kb * 32 + quad * 8];
            a = __builtin_amdgcn_mfma_f32_16x16x32_bf16(ah, bf_, a, 0, 0, 0);
        }
        #pragma unroll
        for (int r = 0; r < 4; r++) {
            const int k = mt * 16 + quad * 4 + r, d = nt * 16 + l15;
            XcA_hi[k * 72 + d] = f2bf(a[r]);
        }
    }
    __syncthreads();
    short8 Ah[2][2];
    #pragma unroll
    for (int mt = 0; mt < 2; mt++)
        #pragma unroll
        for (int kb = 0; kb < 2; kb++)
            Ah[mt][kb] = *(const short8*)&XcA_hi[(mt * 16 + l15) * 72 + kb * 32 + quad * 8];
    #pragma unroll 1
    for (int i = 0; i < 8; i++) {
        const int nt = wv + 4 * i;
        const float bv = bias[nt * 16 + l15];
        floatx4 acc[2];
        acc[0] = (floatx4){bv, bv, bv, bv};
        acc[1] = (floatx4){bv, bv, bv, bv};
        #pragma unroll
        for (int kb = 0; kb < 2; kb++) {
            short8 wh8 = *(const short8*)&WxT[(size_t)(nt * 16 + l15) * 64 + kb * 32 + quad * 8];
            #pragma unroll
            for (int mt = 0; mt < 2; mt++)
                acc[mt] = __builtin_amdgcn_mfma_f32_16x16x32_bf16(Ah[mt][kb], wh8, acc[mt], 0, 0, 0);
        }
        #pragma unroll
        for (int mt = 0; mt < 2; mt++) {
            uint2 pk;
            pk.x = (unsigned)f2bf(acc[mt][0]) | ((unsigned)f2bf(acc[mt][1]) << 16);
            pk.y = (unsigned)f2bf(acc[mt][2]) | ((unsigned)f2bf(acc[mt][3]) << 16);
            ((uint2*)XWx)[((size_t)win * 64 + mt * 32 + nt) * 64 + lane] = pk;
        }
    }
}

// ---------------------------------------------------------------------------
// Kernel 4: corr -> AS -> Ac -> normalize -> An, then AXWx = An @ XWxb
// (unchanged; prescale rides through An @ XWxb linearly).
// ---------------------------------------------------------------------------
__global__ __launch_bounds__(256) void corr_kernel(
    const float* __restrict__ x, const us* __restrict__ S_bf,
    us* __restrict__ An, us* __restrict__ XWx)
{
    __shared__ __align__(16) float xs[30 * 128];    // aliased by XA
    __shared__ __align__(16) us SsT[32 * 136];
    __shared__ __align__(16) us pool[21760];        // CB | AST, later XWT
    __shared__ float Acs[32 * 33];
    __shared__ __align__(16) us AnL[32 * 40];
    __shared__ float sinv[128];
    __shared__ float dinv[32];
    us* XA  = (us*)xs;                              // [128][40]
    us* CB  = pool;                                 // [128][136]
    us* AST = pool + 17408;                         // [32][136]
    us* XWT = pool;                                 // [512][40]
    const int tid = threadIdx.x;
    const int win = blockIdx.x;
    const int b = win / WN_, w = win - b * WN_;
    const float* xb = x + ((size_t)b * T_ + (size_t)w * WIN_) * N_;
    const int lane = tid & 63, wv = tid >> 6;
    const int l15 = lane & 15, quad = lane >> 4;
    const float inv29 = 1.f / (WIN_ - 1 + 1e-8f);

    for (int i = tid; i < 3840; i += 256) xs[i] = xb[i];
    for (int i = tid; i < 4096; i += 256) {
        int n = i >> 5, k = i & 31;
        SsT[k * 136 + n] = S_bf[(size_t)win * 4096 + i];
    }
    __syncthreads();
    float xr[30];
    if (tid < 128) {
        const int n = tid;
        float mean = 0.f;
        #pragma unroll
        for (int l = 0; l < 30; l++) { xr[l] = xs[l * 128 + n]; mean += xr[l]; }
        mean *= (1.f / 30.f);
        float var = 0.f;
        #pragma unroll
        for (int l = 0; l < 30; l++) {
            float v = xr[l] - mean;
            var += v * v;
            xr[l] = v;
        }
        var *= inv29;
        sinv[tid] = rsqrtf(fmaxf(var, 1e-8f));
    }
    __syncthreads();
    if (tid < 128) {
        #pragma unroll
        for (int l = 0; l < 30; l++) XA[tid * 40 + l] = f2bf(xr[l]);
        XA[tid * 40 + 30] = 0; XA[tid * 40 + 31] = 0;
    }
    __syncthreads();
    #pragma unroll 1
    for (int q = 0; q < 16; q++) {
        const int id = wv * 16 + q, mt = id >> 3, nt = id & 7;
        short8 a = *(const short8*)&XA[(mt * 16 + l15) * 40 + quad * 8];
        short8 bb = *(const short8*)&XA[(nt * 16 + l15) * 40 + quad * 8];
        floatx4 d = {0.f, 0.f, 0.f, 0.f};
        d = __builtin_amdgcn_mfma_f32_16x16x32_bf16(a, bb, d, 0, 0, 0);
        const int m = nt * 16 + l15;
        const float sm = sinv[m];
        #pragma unroll
        for (int r = 0; r < 4; r++) {
            const int n = mt * 16 + quad * 4 + r;
            float v = d[r] * inv29 * sinv[n] * sm;
            if (n == m) v = 1.f;
            CB[n * 136 + m] = f2bf(v);
        }
    }
    __syncthreads();
    #pragma unroll 1
    for (int q = 0; q < 4; q++) {
        const int id = wv * 4 + q, mt = id >> 1, lt = id & 1;
        floatx4 d = {0.f, 0.f, 0.f, 0.f};
        #pragma unroll
        for (int kb = 0; kb < 4; kb++) {
            short8 a = *(const short8*)&CB[(mt * 16 + l15) * 136 + kb * 32 + quad * 8];
            short8 bb = *(const short8*)&SsT[(lt * 16 + l15) * 136 + kb * 32 + quad * 8];
            d = __builtin_amdgcn_mfma_f32_16x16x32_bf16(a, bb, d, 0, 0, 0);
        }
        const int l = lt * 16 + l15;
        #pragma unroll
        for (int r = 0; r < 4; r++)
            AST[l * 136 + mt * 16 + quad * 4 + r] = f2bf(d[r]);
    }
    __syncthreads();
    {
        const int kt = wv >> 1, lt = wv & 1;
        floatx4 d = {0.f, 0.f, 0.f, 0.f};
        #pragma unroll
        for (int kb = 0; kb < 4; kb++) {
            short8 a = *(const short8*)&SsT[(kt * 16 + l15) * 136 + kb * 32 + quad * 8];
            short8 bb = *(const short8*)&AST[(lt * 16 + l15) * 136 + kb * 32 + quad * 8];
            d = __builtin_amdgcn_mfma_f32_16x16x32_bf16(a, bb, d, 0, 0, 0);
        }
        #pragma unroll
        for (int r = 0; r < 4; r++)
            Acs[(kt * 16 + quad * 4 + r) * 33 + lt * 16 + l15] = d[r];
    }
    __syncthreads();
    float symv[4];
    {
        int l = tid & 31, kb = tid >> 5;
        for (int r = 0; r < 4; r++) {
            int k = kb + 8 * r;
            symv[r] = 0.5f * (Acs[k * 33 + l] + Acs[l * 33 + k]) + ((k == l) ? 1.f : 0.f);
        }
    }
    __syncthreads();
    {
        int l = tid & 31, kb = tid >> 5;
        for (int r = 0; r < 4; r++) Acs[(kb + 8 * r) * 33 + l] = symv[r];
    }
    __syncthreads();
    if (tid < K_) {
        float s = 0.f;
        for (int l = 0; l < K_; l++) s += Acs[tid * 33 + l];
        dinv[tid] = rsqrtf(fmaxf(s, 1e-8f));
    }
    __syncthreads();
    us* Anw = An + (size_t)win * K_ * K_;
    for (int i = tid; i < K_ * K_; i += 256) {
        int k = i >> 5, l = i & 31;
        us v = f2bf(dinv[k] * Acs[k * 33 + l] * dinv[l]);
        Anw[i] = v;
        AnL[k * 40 + l] = v;
    }
    __syncthreads();
    // ---- stage XWxb (swizzled uint2) -> XWT[jj][m] (pool reuse) ----
    {
        const uint2* xw2 = (const uint2*)XWx + (size_t)win * 4096;
        for (int i = tid; i < 4096; i += 256) {
            uint2 v = xw2[i];
            int tile = i >> 6, lane2 = i & 63;
            int mt2 = tile >> 5, nt2 = tile & 31;
            int jj = nt2 * 16 + (lane2 & 15);
            int m0 = mt2 * 16 + (lane2 >> 4) * 4;
            *(uint2*)&XWT[jj * 40 + m0] = v;
        }
    }
    __syncthreads();
    // ---- AXWx = An @ XWxb, stored back in-place (swizzled) ----
    short8 anA[2];
    anA[0] = *(const short8*)&AnL[l15 * 40 + quad * 8];
    anA[1] = *(const short8*)&AnL[(16 + l15) * 40 + quad * 8];
    #pragma unroll 1
    for (int i = 0; i < 8; i++) {
        const int nt = wv + 4 * i;
        short8 bfr = *(const short8*)&XWT[(nt * 16 + l15) * 40 + quad * 8];
        #pragma unroll
        for (int mt2 = 0; mt2 < 2; mt2++) {
            floatx4 a = {0.f, 0.f, 0.f, 0.f};
            a = __builtin_amdgcn_mfma_f32_16x16x32_bf16(anA[mt2], bfr, a, 0, 0, 0);
            uint2 pk;
            pk.x = (unsigned)f2bf(a[0]) | ((unsigned)f2bf(a[1]) << 16);
            pk.y = (unsigned)f2bf(a[2]) | ((unsigned)f2bf(a[3]) << 16);
            ((uint2*)XWx)[((size_t)win * 64 + mt2 * 32 + nt) * 64 + lane] = pk;
        }
    }
}

// ---------------------------------------------------------------------------
// Kernel 5: GCLSTM scan — r5 body (verified 226.8 us) with the gate args now
// arriving pre-scaled (r6): sig(x) = rcp(1+2^x'), tanh(x) = 2*rcp(1+2^x')-1
// where x' was scaled by -log2e / -2*log2e in prep.  Removes 16 v_mul per
// thread-step from the hot loop; only tanh(cn) keeps a runtime mul.
// ---------------------------------------------------------------------------
__global__ __launch_bounds__(1024) void scan_kernel(
    const us* __restrict__ An_bf,   // [bt][k][m]
    const us* __restrict__ AXWx,    // swizzled C-frag layout (gate-major jj)
    const us* __restrict__ WhT,     // [jj][h]
    float* __restrict__ Hsq2)       // [bt][2][128] partial sums (fully written)
{
    __shared__ __align__(16) us HpT[2][128 * 40];   // [h][k]
    __shared__ __align__(16) us P_lds[32 * 136];    // [k][h]

    const int tid  = threadIdx.x;
    const int lane = tid & 63;
    const int wv   = tid >> 6;          // 0..15
    const int b    = blockIdx.x;
    const int l15  = lane & 15, quad = lane >> 4;
    const int mt   = wv >> 3, hb = wv & 7;

    // Wh B-fragments: 4 gates x 4 kb = 64 VGPR
    short8 Bw[4][4];
    #pragma unroll
    for (int g4 = 0; g4 < 4; g4++) {
        const int jj = g4 * 128 + hb * 16 + l15;
        #pragma unroll
        for (int kb = 0; kb < 4; kb++)
            Bw[g4][kb] = *(const short8*)&WhT[(size_t)jj * 128 + kb * 32 + quad * 8];
    }
    // state: cells (k = mt*16 + quad*4 + r, h = hb*16 + l15)
    float Cst[4] = {0.f, 0.f, 0.f, 0.f};
    float Hst[4] = {0.f, 0.f, 0.f, 0.f};
    float H2t[4] = {0.f, 0.f, 0.f, 0.f};

    for (int i = tid; i < 2560; i += 1024) ((unsigned*)HpT[0])[i] = 0;

    const size_t bt0 = (size_t)b * WN_;
    // strength-reduced prefetch pointers (advance per step)
    const uint2* xq = (const uint2*)AXWx + (bt0 * 64 + (size_t)mt * 32 + hb) * 64 + lane;
    const us*   anp = An_bf + bt0 * 1024 + (size_t)(mt * 16 + l15) * 32 + quad * 8;

    uint2 xw[4];
    #pragma unroll
    for (int g4 = 0; g4 < 4; g4++) xw[g4] = xq[g4 * 512];
    short8 anf = *(const short8*)anp;

    #pragma unroll 1
    for (int t = 0; t < WN_; t++) {
        const int buf = t & 1;
        ldsbar();                                   // HpT[buf] ready
        // ---- P = An @ Hp (1 MFMA/wave); anf was prefetched last step ----
        short8 hpB = *(const short8*)&HpT[buf][(hb * 16 + l15) * 40 + quad * 8];
        floatx4 Pa = {0.f, 0.f, 0.f, 0.f};
        Pa = __builtin_amdgcn_mfma_f32_16x16x32_bf16(anf, hpB, Pa, 0, 0, 0);
        #pragma unroll
        for (int r = 0; r < 4; r++)
            P_lds[(mt * 16 + quad * 4 + r) * 136 + hb * 16 + l15] = f2bf(Pa[r]);
        // ---- g acc init from AXWx(t) (1-op unpacks) ----
        floatx4 gacc[4];
        #pragma unroll
        for (int g4 = 0; g4 < 4; g4++) {
            gacc[g4][0] = __uint_as_float(xw[g4].x << 16);
            gacc[g4][1] = __uint_as_float(xw[g4].x & 0xffff0000u);
            gacc[g4][2] = __uint_as_float(xw[g4].y << 16);
            gacc[g4][3] = __uint_as_float(xw[g4].y & 0xffff0000u);
        }
        // ---- prefetch t+1 (An and AXWx) — latency hides under the MFMAs ----
        if (t + 1 < WN_) { xq += 4096; anp += 1024; }
        #pragma unroll
        for (int g4 = 0; g4 < 4; g4++) xw[g4] = xq[g4 * 512];
        anf = *(const short8*)anp;
        ldsbar();                                   // P ready
        // ---- g += P @ Wh' ----
        #pragma unroll
        for (int kb = 0; kb < 4; kb++) {
            short8 pA = *(const short8*)&P_lds[(mt * 16 + l15) * 136 + kb * 32 + quad * 8];
            #pragma unroll
            for (int g4 = 0; g4 < 4; g4++)
                gacc[g4] = __builtin_amdgcn_mfma_f32_16x16x32_bf16(pA, Bw[g4][kb], gacc[g4], 0, 0, 0);
        }
        // ---- gates + state (args pre-scaled by -log2e / -2log2e) ----
        #pragma unroll
        for (int r = 0; r < 4; r++) {
            float si = rcpa(1.f + ex2(gacc[0][r]));
            float sf = rcpa(1.f + ex2(gacc[1][r]));
            float so = rcpa(1.f + ex2(gacc[2][r]));
            float tc = 2.f * rcpa(1.f + ex2(gacc[3][r])) - 1.f;
            float cn = sf * Cst[r] + si * tc;
            float tn = 2.f * rcpa(1.f + ex2(cn * SC_C)) - 1.f;
            float hn = so * tn;
            Cst[r] = cn;
            H2t[r] = Hst[r];
            Hst[r] = hn;
        }
        // ---- HpT(t+1): packed b64 write [h][4 consecutive k] ----
        if (t + 1 < WN_) {
            const float dninv = (t + 1 == 1) ? 0.5f : (1.f / 3.f);
            short4v hv;
            #pragma unroll
            for (int r = 0; r < 4; r++)
                hv[r] = (short)f2bf((2.f * Hst[r] + H2t[r]) * dninv);
            *(short4v*)&HpT[buf ^ 1][(hb * 16 + l15) * 40 + mt * 16 + quad * 4] = hv;
        }
        // ---- Hsq partial (per-mt, plain store — LAST VMEM op of the step) ----
        {
            float s = Hst[0] + Hst[1] + Hst[2] + Hst[3];
            s += __shfl_xor(s, 16); s += __shfl_xor(s, 32);
            if (quad == 0)
                Hsq2[((bt0 + t) * 2 + mt) * HID_ + hb * 16 + l15] = s;
        }
    }
}

// ---------------------------------------------------------------------------
// Kernel 6: temporal attention pooling + classifier (unchanged).
// ---------------------------------------------------------------------------
__global__ __launch_bounds__(128) void final_kernel(
    const float* __restrict__ Hsq2, const float* __restrict__ Hsm,
    const float* __restrict__ q_t, const float* __restrict__ q_s,
    const float* __restrict__ cls_w, const float* __restrict__ cls_b,
    float* __restrict__ out)
{
    __shared__ float red[128];
    __shared__ float wt[WN_];
    const int b = blockIdx.x, tid = threadIdx.x;
    float v = q_t[tid];
    red[tid] = v * v;
    __syncthreads();
    for (int off = 64; off; off >>= 1) {
        if (tid < off) red[tid] += red[tid + off];
        __syncthreads();
    }
    const float qtn = sqrtf(red[0]) + 1e-8f;
    __syncthreads();
    float v2 = (tid < D_) ? q_s[tid] : 0.f;
    red[tid] = v2 * v2;
    __syncthreads();
    for (int off = 64; off; off >>= 1) {
        if (tid < off) red[tid] += red[tid + off];
        __syncthreads();
    }
    const float qsn = sqrtf(red[0]) + 1e-8f;
    __syncthreads();
    float sc_t = -1e30f;
    if (tid < WN_) {
        float s = 0.f;
        const float* zr = Hsq2 + ((size_t)b * WN_ + tid) * (2 * HID_);
        for (int h = 0; h < HID_; h++) s += (zr[h] + zr[HID_ + h]) * q_t[h];
        sc_t = s * (1.f / 32.f) / qtn;
    }
    red[tid] = sc_t;
    __syncthreads();
    for (int off = 64; off; off >>= 1) {
        if (tid < off) red[tid] = fmaxf(red[tid], red[tid + off]);
        __syncthreads();
    }
    const float mt_ = red[0];
    __syncthreads();
    float e_t = (tid < WN_) ? expf(sc_t - mt_) : 0.f;
    red[tid] = e_t;
    __syncthreads();
    for (int off = 64; off; off >>= 1) {
        if (tid < off) red[tid] += red[tid + off];
        __syncthreads();
    }
    const float sinv_t = 1.f / red[0];
    __syncthreads();
    if (tid < WN_) wt[tid] = e_t * sinv_t;
    __syncthreads();
    float part = 0.f;
    {
        float z = 0.f;
        for (int w = 0; w < WN_; w++) {
            const float* p = Hsq2 + ((size_t)b * WN_ + w) * (2 * HID_);
            z += wt[w] * (p[tid] + p[HID_ + tid]);
        }
        part += z * (1.f / 32.f) * cls_w[tid];
    }
    __syncthreads();
    float sc_s = -1e30f;
    if (tid < WN_) {
        float s = 0.f;
        const float* zr = Hsm + ((size_t)b * WN_ + tid) * D_;
        for (int dd = 0; dd < D_; dd++) s += zr[dd] * q_s[dd];
        sc_s = s / qsn;
    }
    red[tid] = sc_s;
    __syncthreads();
    for (int off = 64; off; off >>= 1) {
        if (tid < off) red[tid] = fmaxf(red[tid], red[tid + off]);
        __syncthreads();
    }
    const float ms_ = red[0];
    __syncthreads();
    float e_s = (tid < WN_) ? expf(sc_s - ms_) : 0.f;
    red[tid] = e_s;
    __syncthreads();
    for (int off = 64; off; off >>= 1) {
        if (tid < off) red[tid] += red[tid + off];
        __syncthreads();
    }
    const float sinv_s = 1.f / red[0];
    __syncthreads();
    if (tid < WN_) wt[tid] = e_s * sinv_s;
    __syncthreads();
    if (tid < D_) {
        float z = 0.f;
        for (int w = 0; w < WN_; w++)
            z += wt[w] * Hsm[((size_t)b * WN_ + w) * D_ + tid];
        part += z * cls_w[HID_ + tid];
    }
    red[tid] = part;
    __syncthreads();
    for (int off = 64; off; off >>= 1) {
        if (tid < off) red[tid] += red[tid + off];
        __syncthreads();
    }
    if (tid == 0) out[b] = 1.f / (1.f + expf(-(red[0] + cls_b[0])));
}

// ---------------------------------------------------------------------------
extern "C" void kernel_launch(void* const* d_in, const int* in_sizes, int n_in,
                              void* d_out, int out_size, void* d_ws, size_t ws_size,
                              hipStream_t stream)
{
    (void)in_sizes; (void)n_in; (void)out_size; (void)ws_size;
    const float* x     = (const float*)d_in[0];
    const float* w1    = (const float*)d_in[1];
    const float* b1    = (const float*)d_in[2];
    const float* w2    = (const float*)d_in[3];
    const float* b2    = (const float*)d_in[4];
    const float* pw    = (const float*)d_in[5];
    const float* pb    = (const float*)d_in[6];
    const float* proto = (const float*)d_in[7];
    const float* Wx    = (const float*)d_in[8];
    const float* bx    = (const float*)d_in[9];
    const float* Wh    = (const float*)d_in[10];
    const float* bh    = (const float*)d_in[11];
    const float* q_t   = (const float*)d_in[12];
    const float* q_s   = (const float*)d_in[13];
    const float* clw   = (const float*)d_in[14];
    const float* clb   = (const float*)d_in[15];

    float* ws = (float*)d_ws;
    us*    Hs_bf  = (us*)d_ws;                      // [0, 6553600)
    us*    S_bf   = (us*)(ws + 6553600);            // [6553600, 9830400)
    us*    XWx    = (us*)(ws + 9830400);            // XWxb, then AXWx in place
    us*    An_bf  = (us*)(ws + 22937600);           // [22937600, 23756800)
    float* Hsm    = ws + 23756800;                  // [23756800, 23859200)
    // Hsq2 reuses the S_bf region: S is only read by corr_kernel, which
    // completes before scan_kernel writes here (stream-ordered).
    float* Hsq2   = ws + 6553600;
    us*    WhT    = (us*)(ws + 24064000);           // [24064000, 24096768)
    us*    WxT    = (us*)(ws + 24096768);           // [24096768, 24113152)
    float* bs2    = ws + 24129536;                  // [24129536, 24130048)

    prep_kernel<<<386, 256, 0, stream>>>(Wh, Wx, bx, bh, WhT, WxT, bs2);
    conv_kernel<<<B_ * WN_, 256, 0, stream>>>(x, w1, b1, w2, b2, pw, pb, Hs_bf);
    xcwx_kernel<<<B_ * WN_, 256, 0, stream>>>(Hs_bf, proto, WxT, bs2,
                                              S_bf, XWx, Hsm);
    corr_kernel<<<B_ * WN_, 256, 0, stream>>>(x, S_bf, An_bf, XWx);
    scan_kernel<<<B_, 1024, 0, stream>>>(An_bf, XWx, WhT, Hsq2);
    final_kernel<<<B_, 128, 0, stream>>>(Hsq2, Hsm, q_t, q_s, clw, clb,
                                         (float*)d_out);
}

// Round 7
// 547.730 us; speedup vs baseline: 1.3229x; 1.0303x over previous
//
#include <hip/hip_runtime.h>

#define B_   16
#define T_   3000
#define N_   128
#define WIN_ 30
#define WN_  100
#define D_   64
#define HID_ 128
#define K_   32
#define G4_  512   // 4*HID_

typedef unsigned short us;
typedef __attribute__((ext_vector_type(8))) short short8;
typedef __attribute__((ext_vector_type(4))) short short4v;
typedef __attribute__((ext_vector_type(4))) float floatx4;

__device__ __forceinline__ us f2bf(float f) {
    unsigned u = __float_as_uint(f);
    u += 0x7fffu + ((u >> 16) & 1u);
    return (us)(u >> 16);
}
__device__ __forceinline__ float bf2f(us h) {
    return __uint_as_float(((unsigned)h) << 16);
}
// Single-instruction v_rcp_f32 (~1 ulp; rcp(inf)=0 keeps saturation graceful).
__device__ __forceinline__ float rcpa(float x) { return __builtin_amdgcn_rcpf(x); }
__device__ __forceinline__ float ex2(float x) { return __builtin_amdgcn_exp2f(x); }
// Barrier WITHOUT vmcnt drain: LDS ordering only.  Safe when all global
// loads/stores crossing it are wave-private (consumed by issuing wave).
__device__ __forceinline__ void ldsbar() {
    __asm__ volatile("s_waitcnt lgkmcnt(0)\n\ts_barrier" ::: "memory");
}

// exp-prescale constants folded into the gate weights (r6):
//   gates i,f,o:  arg' = -log2e   * arg   -> sig(arg)  = rcp(1+2^arg')
//   gate  c:      arg' = -2*log2e * arg   -> tanh(arg) = 2*rcp(1+2^arg')-1
#define SC_IFO (-1.4426950408889634f)
#define SC_C   (-2.8853900817779268f)

// ---------------------------------------------------------------------------
// Kernel 1: SignalRep conv (unchanged — verified).
// ---------------------------------------------------------------------------
__global__ __launch_bounds__(256) void conv_kernel(
    const float* __restrict__ x, const float* __restrict__ w1,
    const float* __restrict__ b1, const float* __restrict__ w2,
    const float* __restrict__ b2, const float* __restrict__ pw,
    const float* __restrict__ pb, us* __restrict__ Hs)
{
    __shared__ __align__(16) float xs_all[30 * 128];   // [t][n]
    __shared__ __align__(16) us h1s[8 * 36 * 40];      // [s][t'][ci]
    __shared__ __align__(16) float Ms[128 * 40];       // [n][co] means (/30)
    __shared__ __align__(16) us PwT_hi[64 * 40];       // [d][co]
    __shared__ __align__(16) us PwT_lo[64 * 40];
    const int tid = threadIdx.x;
    const int win = blockIdx.x;
    const int b = win / WN_, w = win - b * WN_;
    const float* xb = x + ((size_t)b * T_ + (size_t)w * WIN_) * N_;
    const int lane = tid & 63, wv = tid >> 6;
    const int l15 = lane & 15, quad = lane >> 4;

    {
        const float4* xb4 = (const float4*)xb;
        float4* xs4 = (float4*)xs_all;
        for (int i = tid; i < 960; i += 256) xs4[i] = xb4[i];
    }
    for (int i = tid; i < 2048; i += 256) {
        int co = i >> 6, d = i & 63;
        float v = pw[i];
        us hi = f2bf(v);
        PwT_hi[d * 40 + co] = hi;
        PwT_lo[d * 40 + co] = f2bf(v - bf2f(hi));
    }
    for (int i = tid; i < 1920; i += 256) {            // zero h1 pad rows
        int s = i / 240, r = i % 240;
        int ti = r / 40, c = r % 40;
        int tp = (ti < 2) ? ti : (30 + ti);
        h1s[(s * 36 + tp) * 40 + c] = 0;
    }
    short8 whf[2][5];
    #pragma unroll
    for (int cot = 0; cot < 2; cot++)
        #pragma unroll
        for (int dk = 0; dk < 5; dk++)
            #pragma unroll
            for (int j = 0; j < 8; j++)
                whf[cot][dk][j] = (short)f2bf(w2[(cot * 16 + l15) * 160 + (quad * 8 + j) * 5 + dk]);
    const float b2c0 = b2[l15], b2c1 = b2[16 + l15];
    const int ci2 = lane & 15, th = (lane >> 4) & 1, sloc = lane >> 5;
    float w1ra[5], w1rb[5];
    #pragma unroll
    for (int k = 0; k < 5; k++) {
        w1ra[k] = w1[(2 * ci2) * 5 + k];
        w1rb[k] = w1[(2 * ci2 + 1) * 5 + k];
    }
    const float b1a = b1[2 * ci2], b1b = b1[2 * ci2 + 1];
    float pbv[4];
    #pragma unroll
    for (int nt = 0; nt < 4; nt++) pbv[nt] = pb[nt * 16 + l15];
    ldsbar();

    for (int g = 0; g < 16; g++) {
        const int n1 = g * 8 + wv * 2 + sloc;
        {
            float xr[19];
            #pragma unroll
            for (int u = 0; u < 19; u++) {
                int p = th * 15 - 2 + u;
                xr[u] = ((unsigned)p < 30u) ? xs_all[p * 128 + n1] : 0.f;
            }
            const int rbase = (wv * 2 + sloc) * 36 + 2 + th * 15;
            #pragma unroll
            for (int tt = 0; tt < 15; tt++) {
                float aa = b1a, ab = b1b;
                #pragma unroll
                for (int k = 0; k < 5; k++) {
                    aa += xr[tt + k] * w1ra[k];
                    ab += xr[tt + k] * w1rb[k];
                }
                unsigned pk = (unsigned)f2bf(fmaxf(aa, 0.f))
                            | ((unsigned)f2bf(fmaxf(ab, 0.f)) << 16);
                *(unsigned*)&h1s[(rbase + tt) * 40 + 2 * ci2] = pk;
            }
        }
        __builtin_amdgcn_wave_barrier();
        #pragma unroll
        for (int s2 = 0; s2 < 2; s2++) {
            const int sl = wv * 2 + s2;
            const int nn = g * 8 + sl;
            floatx4 c00 = {b2c0, b2c0, b2c0, b2c0};
            floatx4 c01 = {b2c1, b2c1, b2c1, b2c1};
            floatx4 c10 = {b2c0, b2c0, b2c0, b2c0};
            floatx4 c11 = {b2c1, b2c1, b2c1, b2c1};
            #pragma unroll
            for (int dk = 0; dk < 5; dk++) {
                short8 a0 = *(const short8*)&h1s[(sl * 36 + l15 + dk) * 40 + quad * 8];
                short8 a1 = *(const short8*)&h1s[(sl * 36 + 16 + l15 + dk) * 40 + quad * 8];
                c00 = __builtin_amdgcn_mfma_f32_16x16x32_bf16(a0, whf[0][dk], c00, 0, 0, 0);
                c01 = __builtin_amdgcn_mfma_f32_16x16x32_bf16(a0, whf[1][dk], c01, 0, 0, 0);
                c10 = __builtin_amdgcn_mfma_f32_16x16x32_bf16(a1, whf[0][dk], c10, 0, 0, 0);
                c11 = __builtin_amdgcn_mfma_f32_16x16x32_bf16(a1, whf[1][dk], c11, 0, 0, 0);
            }
            float s0 = 0.f, s1 = 0.f;
            #pragma unroll
            for (int r = 0; r < 4; r++) {
                s0 += fmaxf(c00[r], 0.f);
                s1 += fmaxf(c01[r], 0.f);
                float m0 = (quad * 4 + r < 14) ? fmaxf(c10[r], 0.f) : 0.f;
                float m1 = (quad * 4 + r < 14) ? fmaxf(c11[r], 0.f) : 0.f;
                s0 += m0; s1 += m1;
            }
            s0 += __shfl_xor(s0, 16); s0 += __shfl_xor(s0, 32);
            s1 += __shfl_xor(s1, 16); s1 += __shfl_xor(s1, 32);
            if (quad == 0) {
                Ms[nn * 40 + l15]      = s0 * (1.f / 30.f);
                Ms[nn * 40 + 16 + l15] = s1 * (1.f / 30.f);
            }
        }
        __builtin_amdgcn_wave_barrier();
    }
    ldsbar();
    short8 Ah[2], Al[2];
    #pragma unroll
    for (int i = 0; i < 2; i++) {
        const int mt = wv * 2 + i;
        float4 v0 = *(const float4*)&Ms[(mt * 16 + l15) * 40 + quad * 8];
        float4 v1 = *(const float4*)&Ms[(mt * 16 + l15) * 40 + quad * 8 + 4];
        float vv[8] = {v0.x, v0.y, v0.z, v0.w, v1.x, v1.y, v1.z, v1.w};
        #pragma unroll
        for (int j = 0; j < 8; j++) {
            us hi = f2bf(vv[j]);
            Ah[i][j] = (short)hi;
            Al[i][j] = (short)f2bf(vv[j] - bf2f(hi));
        }
    }
    us* hp = Hs + (size_t)win * 8192;
    #pragma unroll
    for (int id = 0; id < 8; id++) {
        const int i = id >> 2, nt = id & 3;
        short8 Bh = *(const short8*)&PwT_hi[(nt * 16 + l15) * 40 + quad * 8];
        short8 Bl = *(const short8*)&PwT_lo[(nt * 16 + l15) * 40 + quad * 8];
        floatx4 a = {pbv[nt], pbv[nt], pbv[nt], pbv[nt]};
        a = __builtin_amdgcn_mfma_f32_16x16x32_bf16(Ah[i], Bh, a, 0, 0, 0);
        a = __builtin_amdgcn_mfma_f32_16x16x32_bf16(Al[i], Bh, a, 0, 0, 0);
        a = __builtin_amdgcn_mfma_f32_16x16x32_bf16(Ah[i], Bl, a, 0, 0, 0);
        const int mt = wv * 2 + i;
        #pragma unroll
        for (int r = 0; r < 4; r++)
            hp[(mt * 16 + quad * 4 + r) * 64 + nt * 16 + l15] = f2bf(a[r]);
    }
}

// ---------------------------------------------------------------------------
// Kernel 2: prep — r6 exp-prescale fold (verified).
// ---------------------------------------------------------------------------
__global__ __launch_bounds__(256) void prep_kernel(
    const float* __restrict__ Wh, const float* __restrict__ Wx,
    const float* __restrict__ bx, const float* __restrict__ bh,
    us* __restrict__ WhT, us* __restrict__ WxT, float* __restrict__ bs2)
{
    int i = blockIdx.x * 256 + threadIdx.x;
    if (i < 65536) {
        int jj = i >> 7, h = i & 127;
        float sc = (jj >> 7) == 3 ? SC_C : SC_IFO;
        WhT[i] = f2bf(Wh[h * G4_ + jj] * sc);
    } else if (i < 98304) {
        int j = i - 65536;
        int jj = j >> 6, d = j & 63;
        float sc = (jj >> 7) == 3 ? SC_C : SC_IFO;
        WxT[j] = f2bf(Wx[d * G4_ + jj] * sc);
    } else if (i < 98816) {
        int jj = i - 98304;
        float sc = (jj >> 7) == 3 ? SC_C : SC_IFO;
        bs2[jj] = (bx[jj] + bh[jj]) * sc;
    }
}

// ---------------------------------------------------------------------------
// Kernel 3: fused per-window — softmax S, Hsm, Xc = S^T@Hs, XWxb (unchanged).
// ---------------------------------------------------------------------------
__global__ __launch_bounds__(256) void xcwx_kernel(
    const us* __restrict__ Hs, const float* __restrict__ proto,
    const us* __restrict__ WxT, const float* __restrict__ bs2,
    us* __restrict__ S_out, us* __restrict__ XWx, float* __restrict__ Hsm)
{
    __shared__ __align__(16) us Hnd[128 * 72];
    __shared__ __align__(16) us HsT[64 * 136];
    __shared__ __align__(16) us PT_hi[32 * 72];
    __shared__ __align__(16) us SsT_hi[32 * 136];
    __shared__ __align__(16) us XcA_hi[32 * 72];
    __shared__ float bias[512];
    const int tid = threadIdx.x;
    const int win = blockIdx.x;
    const int lane = tid & 63, wv = tid >> 6;
    const int l15 = lane & 15, quad = lane >> 4;

    {
        const uint2* hp = (const uint2*)(Hs + (size_t)win * 8192);
        #pragma unroll
        for (int it = 0; it < 8; it++) {
            int idx4 = tid + 256 * it;
            int n = idx4 >> 4, dpos = (idx4 & 15) * 4;
            uint2 v = hp[idx4];
            *(uint2*)&Hnd[n * 72 + dpos] = v;
            us s0 = (us)(v.x & 0xffff), s1 = (us)(v.x >> 16);
            us s2 = (us)(v.y & 0xffff), s3 = (us)(v.y >> 16);
            HsT[(dpos + 0) * 136 + n] = s0;
            HsT[(dpos + 1) * 136 + n] = s1;
            HsT[(dpos + 2) * 136 + n] = s2;
            HsT[(dpos + 3) * 136 + n] = s3;
        }
        for (int i = tid; i < 2048; i += 256) {
            int k = i >> 6, d = i & 63;
            PT_hi[k * 72 + d] = f2bf(proto[i]);
        }
        for (int i = tid; i < 512; i += 256) bias[i] = bs2[i];
    }
    __syncthreads();
    floatx4 lg[2][2];
    #pragma unroll
    for (int p = 0; p < 2; p++) {
        const int mt = wv * 2 + p;
        #pragma unroll
        for (int kt = 0; kt < 2; kt++) {
            floatx4 a = {0.f, 0.f, 0.f, 0.f};
            #pragma unroll
            for (int kb = 0; kb < 2; kb++) {
                short8 af  = *(const short8*)&Hnd[(mt * 16 + l15) * 72 + kb * 32 + quad * 8];
                short8 bhf = *(const short8*)&PT_hi[(kt * 16 + l15) * 72 + kb * 32 + quad * 8];
                a = __builtin_amdgcn_mfma_f32_16x16x32_bf16(af, bhf, a, 0, 0, 0);
            }
            lg[p][kt] = a;
        }
    }
    #pragma unroll
    for (int p = 0; p < 2; p++) {
        #pragma unroll
        for (int r = 0; r < 4; r++) {
            float v0 = lg[p][0][r], v1 = lg[p][1][r];
            float m = fmaxf(v0, v1);
            #pragma unroll
            for (int off = 8; off; off >>= 1) m = fmaxf(m, __shfl_xor(m, off));
            float e0 = expf(v0 - m), e1 = expf(v1 - m);
            float s = e0 + e1;
            #pragma unroll
            for (int off = 8; off; off >>= 1) s += __shfl_xor(s, off);
            float inv = 1.f / s;
            e0 *= inv; e1 *= inv;
            const int n = (wv * 2 + p) * 16 + quad * 4 + r;
            us h0 = f2bf(e0), h1 = f2bf(e1);
            SsT_hi[l15 * 136 + n]        = h0;
            SsT_hi[(16 + l15) * 136 + n] = h1;
            S_out[(size_t)win * 4096 + n * 32 + l15]      = h0;
            S_out[(size_t)win * 4096 + n * 32 + 16 + l15] = h1;
        }
    }
    __syncthreads();
    {
        const int d = tid >> 2, seg = tid & 3;
        float acc = 0.f;
        const unsigned* hp2 = (const unsigned*)&HsT[d * 136 + seg * 32];
        #pragma unroll
        for (int q = 0; q < 16; q++) {
            unsigned v = hp2[q];
            acc += bf2f((us)(v & 0xffff)) + bf2f((us)(v >> 16));
        }
        acc += __shfl_xor(acc, 1);
        acc += __shfl_xor(acc, 2);
        if (seg == 0) Hsm[(size_t)win * 64 + d] = acc * (1.f / 128.f);
    }
    #pragma unroll
    for (int p = 0; p < 2; p++) {
        const int id = wv * 2 + p, mt = id >> 2, nt = id & 3;
        floatx4 a = {0.f, 0.f, 0.f, 0.f};
        #pragma unroll
        for (int kb = 0; kb < 4; kb++) {
            short8 ah = *(const short8*)&SsT_hi[(mt * 16 + l15) * 136 + kb * 32 + quad * 8];
            short8 bf_ = *(const short8*)&HsT[(nt * 16 + l15) * 136 + kb * 32 + quad * 8];
            a = __builtin_amdgcn_mfma_f32_16x16x32_bf16(ah, bf_, a, 0, 0, 0);
        }
        #pragma unroll
        for (int r = 0; r < 4; r++) {
            const int k = mt * 16 + quad * 4 + r, d = nt * 16 + l15;
            XcA_hi[k * 72 + d] = f2bf(a[r]);
        }
    }
    __syncthreads();
    short8 Ah[2][2];
    #pragma unroll
    for (int mt = 0; mt < 2; mt++)
        #pragma unroll
        for (int kb = 0; kb < 2; kb++)
            Ah[mt][kb] = *(const short8*)&XcA_hi[(mt * 16 + l15) * 72 + kb * 32 + quad * 8];
    #pragma unroll 1
    for (int i = 0; i < 8; i++) {
        const int nt = wv + 4 * i;
        const float bv = bias[nt * 16 + l15];
        floatx4 acc[2];
        acc[0] = (floatx4){bv, bv, bv, bv};
        acc[1] = (floatx4){bv, bv, bv, bv};
        #pragma unroll
        for (int kb = 0; kb < 2; kb++) {
            short8 wh8 = *(const short8*)&WxT[(size_t)(nt * 16 + l15) * 64 + kb * 32 + quad * 8];
            #pragma unroll
            for (int mt = 0; mt < 2; mt++)
                acc[mt] = __builtin_amdgcn_mfma_f32_16x16x32_bf16(Ah[mt][kb], wh8, acc[mt], 0, 0, 0);
        }
        #pragma unroll
        for (int mt = 0; mt < 2; mt++) {
            uint2 pk;
            pk.x = (unsigned)f2bf(acc[mt][0]) | ((unsigned)f2bf(acc[mt][1]) << 16);
            pk.y = (unsigned)f2bf(acc[mt][2]) | ((unsigned)f2bf(acc[mt][3]) << 16);
            ((uint2*)XWx)[((size_t)win * 64 + mt * 32 + nt) * 64 + lane] = pk;
        }
    }
}

// ---------------------------------------------------------------------------
// Kernel 4: corr — r7: vectorized global staging (bit-exact data movement):
//   (a) x window: scalar f32 (15 loads/thr) -> float4 (4 loads/thr)
//   (b) S_bf: scalar us (2 B/lane!, 16 loads) -> uint2 (4 loads)
//   (c) XWxb restage: uint2 -> uint4 (16 -> 8 loads)
// Compute path unchanged.
// ---------------------------------------------------------------------------
__global__ __launch_bounds__(256) void corr_kernel(
    const float* __restrict__ x, const us* __restrict__ S_bf,
    us* __restrict__ An, us* __restrict__ XWx)
{
    __shared__ __align__(16) float xs[30 * 128];    // aliased by XA
    __shared__ __align__(16) us SsT[32 * 136];
    __shared__ __align__(16) us pool[21760];        // CB | AST, later XWT
    __shared__ float Acs[32 * 33];
    __shared__ __align__(16) us AnL[32 * 40];
    __shared__ float sinv[128];
    __shared__ float dinv[32];
    us* XA  = (us*)xs;                              // [128][40]
    us* CB  = pool;                                 // [128][136]
    us* AST = pool + 17408;                         // [32][136]
    us* XWT = pool;                                 // [512][40]
    const int tid = threadIdx.x;
    const int win = blockIdx.x;
    const int b = win / WN_, w = win - b * WN_;
    const float* xb = x + ((size_t)b * T_ + (size_t)w * WIN_) * N_;
    const int lane = tid & 63, wv = tid >> 6;
    const int l15 = lane & 15, quad = lane >> 4;
    const float inv29 = 1.f / (WIN_ - 1 + 1e-8f);

    {
        const float4* xb4 = (const float4*)xb;
        float4* xs4 = (float4*)xs;
        for (int i = tid; i < 960; i += 256) xs4[i] = xb4[i];
    }
    {
        const uint2* sp = (const uint2*)(S_bf + (size_t)win * 4096);
        for (int i4 = tid; i4 < 1024; i4 += 256) {
            uint2 v = sp[i4];                       // 4 us: n = i4>>3, k0 = (i4&7)*4
            int n = i4 >> 3, k0 = (i4 & 7) * 4;
            SsT[(k0 + 0) * 136 + n] = (us)(v.x & 0xffff);
            SsT[(k0 + 1) * 136 + n] = (us)(v.x >> 16);
            SsT[(k0 + 2) * 136 + n] = (us)(v.y & 0xffff);
            SsT[(k0 + 3) * 136 + n] = (us)(v.y >> 16);
        }
    }
    __syncthreads();
    float xr[30];
    if (tid < 128) {
        const int n = tid;
        float mean = 0.f;
        #pragma unroll
        for (int l = 0; l < 30; l++) { xr[l] = xs[l * 128 + n]; mean += xr[l]; }
        mean *= (1.f / 30.f);
        float var = 0.f;
        #pragma unroll
        for (int l = 0; l < 30; l++) {
            float v = xr[l] - mean;
            var += v * v;
            xr[l] = v;
        }
        var *= inv29;
        sinv[tid] = rsqrtf(fmaxf(var, 1e-8f));
    }
    __syncthreads();
    if (tid < 128) {
        #pragma unroll
        for (int l = 0; l < 30; l++) XA[tid * 40 + l] = f2bf(xr[l]);
        XA[tid * 40 + 30] = 0; XA[tid * 40 + 31] = 0;
    }
    __syncthreads();
    #pragma unroll 1
    for (int q = 0; q < 16; q++) {
        const int id = wv * 16 + q, mt = id >> 3, nt = id & 7;
        short8 a = *(const short8*)&XA[(mt * 16 + l15) * 40 + quad * 8];
        short8 bb = *(const short8*)&XA[(nt * 16 + l15) * 40 + quad * 8];
        floatx4 d = {0.f, 0.f, 0.f, 0.f};
        d = __builtin_amdgcn_mfma_f32_16x16x32_bf16(a, bb, d, 0, 0, 0);
        const int m = nt * 16 + l15;
        const float sm = sinv[m];
        #pragma unroll
        for (int r = 0; r < 4; r++) {
            const int n = mt * 16 + quad * 4 + r;
            float v = d[r] * inv29 * sinv[n] * sm;
            if (n == m) v = 1.f;
            CB[n * 136 + m] = f2bf(v);
        }
    }
    __syncthreads();
    #pragma unroll 1
    for (int q = 0; q < 4; q++) {
        const int id = wv * 4 + q, mt = id >> 1, lt = id & 1;
        floatx4 d = {0.f, 0.f, 0.f, 0.f};
        #pragma unroll
        for (int kb = 0; kb < 4; kb++) {
            short8 a = *(const short8*)&CB[(mt * 16 + l15) * 136 + kb * 32 + quad * 8];
            short8 bb = *(const short8*)&SsT[(lt * 16 + l15) * 136 + kb * 32 + quad * 8];
            d = __builtin_amdgcn_mfma_f32_16x16x32_bf16(a, bb, d, 0, 0, 0);
        }
        const int l = lt * 16 + l15;
        #pragma unroll
        for (int r = 0; r < 4; r++)
            AST[l * 136 + mt * 16 + quad * 4 + r] = f2bf(d[r]);
    }
    __syncthreads();
    {
        const int kt = wv >> 1, lt = wv & 1;
        floatx4 d = {0.f, 0.f, 0.f, 0.f};
        #pragma unroll
        for (int kb = 0; kb < 4; kb++) {
            short8 a = *(const short8*)&SsT[(kt * 16 + l15) * 136 + kb * 32 + quad * 8];
            short8 bb = *(const short8*)&AST[(lt * 16 + l15) * 136 + kb * 32 + quad * 8];
            d = __builtin_amdgcn_mfma_f32_16x16x32_bf16(a, bb, d, 0, 0, 0);
        }
        #pragma unroll
        for (int r = 0; r < 4; r++)
            Acs[(kt * 16 + quad * 4 + r) * 33 + lt * 16 + l15] = d[r];
    }
    __syncthreads();
    float symv[4];
    {
        int l = tid & 31, kb = tid >> 5;
        for (int r = 0; r < 4; r++) {
            int k = kb + 8 * r;
            symv[r] = 0.5f * (Acs[k * 33 + l] + Acs[l * 33 + k]) + ((k == l) ? 1.f : 0.f);
        }
    }
    __syncthreads();
    {
        int l = tid & 31, kb = tid >> 5;
        for (int r = 0; r < 4; r++) Acs[(kb + 8 * r) * 33 + l] = symv[r];
    }
    __syncthreads();
    if (tid < K_) {
        float s = 0.f;
        for (int l = 0; l < K_; l++) s += Acs[tid * 33 + l];
        dinv[tid] = rsqrtf(fmaxf(s, 1e-8f));
    }
    __syncthreads();
    us* Anw = An + (size_t)win * K_ * K_;
    for (int i = tid; i < K_ * K_; i += 256) {
        int k = i >> 5, l = i & 31;
        us v = f2bf(dinv[k] * Acs[k * 33 + l] * dinv[l]);
        Anw[i] = v;
        AnL[k * 40 + l] = v;
    }
    __syncthreads();
    // ---- stage XWxb (swizzled, uint4 loads) -> XWT[jj][m] (pool reuse) ----
    {
        const uint4* xw4 = (const uint4*)((const uint2*)XWx + (size_t)win * 4096);
        for (int i2 = tid; i2 < 2048; i2 += 256) {
            uint4 v = xw4[i2];                      // two uint2: i = 2*i2, 2*i2+1
            int i = i2 * 2;
            int tile = i >> 6, lane2 = i & 63;      // lane2 even
            int mt2 = tile >> 5, nt2 = tile & 31;
            int jj = nt2 * 16 + (lane2 & 15);
            int m0 = mt2 * 16 + (lane2 >> 4) * 4;
            *(uint2*)&XWT[jj * 40 + m0] = make_uint2(v.x, v.y);
            int jj1 = nt2 * 16 + ((lane2 + 1) & 15);
            int m01 = mt2 * 16 + (((lane2 + 1) >> 4)) * 4;
            *(uint2*)&XWT[jj1 * 40 + m01] = make_uint2(v.z, v.w);
        }
    }
    __syncthreads();
    // ---- AXWx = An @ XWxb, stored back in-place (swizzled) ----
    short8 anA[2];
    anA[0] = *(const short8*)&AnL[l15 * 40 + quad * 8];
    anA[1] = *(const short8*)&AnL[(16 + l15) * 40 + quad * 8];
    #pragma unroll 1
    for (int i = 0; i < 8; i++) {
        const int nt = wv + 4 * i;
        short8 bfr = *(const short8*)&XWT[(nt * 16 + l15) * 40 + quad * 8];
        #pragma unroll
        for (int mt2 = 0; mt2 < 2; mt2++) {
            floatx4 a = {0.f, 0.f, 0.f, 0.f};
            a = __builtin_amdgcn_mfma_f32_16x16x32_bf16(anA[mt2], bfr, a, 0, 0, 0);
            uint2 pk;
            pk.x = (unsigned)f2bf(a[0]) | ((unsigned)f2bf(a[1]) << 16);
            pk.y = (unsigned)f2bf(a[2]) | ((unsigned)f2bf(a[3]) << 16);
            ((uint2*)XWx)[((size_t)win * 64 + mt2 * 32 + nt) * 64 + lane] = pk;
        }
    }
}

// ---------------------------------------------------------------------------
// Kernel 5: GCLSTM scan — r6 body (verified 216.0 us), untouched.
// ---------------------------------------------------------------------------
__global__ __launch_bounds__(1024) void scan_kernel(
    const us* __restrict__ An_bf,   // [bt][k][m]
    const us* __restrict__ AXWx,    // swizzled C-frag layout (gate-major jj)
    const us* __restrict__ WhT,     // [jj][h]
    float* __restrict__ Hsq2)       // [bt][2][128] partial sums (fully written)
{
    __shared__ __align__(16) us HpT[2][128 * 40];   // [h][k]
    __shared__ __align__(16) us P_lds[32 * 136];    // [k][h]

    const int tid  = threadIdx.x;
    const int lane = tid & 63;
    const int wv   = tid >> 6;          // 0..15
    const int b    = blockIdx.x;
    const int l15  = lane & 15, quad = lane >> 4;
    const int mt   = wv >> 3, hb = wv & 7;

    // Wh B-fragments: 4 gates x 4 kb = 64 VGPR
    short8 Bw[4][4];
    #pragma unroll
    for (int g4 = 0; g4 < 4; g4++) {
        const int jj = g4 * 128 + hb * 16 + l15;
        #pragma unroll
        for (int kb = 0; kb < 4; kb++)
            Bw[g4][kb] = *(const short8*)&WhT[(size_t)jj * 128 + kb * 32 + quad * 8];
    }
    // state: cells (k = mt*16 + quad*4 + r, h = hb*16 + l15)
    float Cst[4] = {0.f, 0.f, 0.f, 0.f};
    float Hst[4] = {0.f, 0.f, 0.f, 0.f};
    float H2t[4] = {0.f, 0.f, 0.f, 0.f};

    for (int i = tid; i < 2560; i += 1024) ((unsigned*)HpT[0])[i] = 0;

    const size_t bt0 = (size_t)b * WN_;
    // strength-reduced prefetch pointers (advance per step)
    const uint2* xq = (const uint2*)AXWx + (bt0 * 64 + (size_t)mt * 32 + hb) * 64 + lane;
    const us*   anp = An_bf + bt0 * 1024 + (size_t)(mt * 16 + l15) * 32 + quad * 8;

    uint2 xw[4];
    #pragma unroll
    for (int g4 = 0; g4 < 4; g4++) xw[g4] = xq[g4 * 512];
    short8 anf = *(const short8*)anp;

    #pragma unroll 1
    for (int t = 0; t < WN_; t++) {
        const int buf = t & 1;
        ldsbar();                                   // HpT[buf] ready
        // ---- P = An @ Hp (1 MFMA/wave); anf was prefetched last step ----
        short8 hpB = *(const short8*)&HpT[buf][(hb * 16 + l15) * 40 + quad * 8];
        floatx4 Pa = {0.f, 0.f, 0.f, 0.f};
        Pa = __builtin_amdgcn_mfma_f32_16x16x32_bf16(anf, hpB, Pa, 0, 0, 0);
        #pragma unroll
        for (int r = 0; r < 4; r++)
            P_lds[(mt * 16 + quad * 4 + r) * 136 + hb * 16 + l15] = f2bf(Pa[r]);
        // ---- g acc init from AXWx(t) (1-op unpacks) ----
        floatx4 gacc[4];
        #pragma unroll
        for (int g4 = 0; g4 < 4; g4++) {
            gacc[g4][0] = __uint_as_float(xw[g4].x << 16);
            gacc[g4][1] = __uint_as_float(xw[g4].x & 0xffff0000u);
            gacc[g4][2] = __uint_as_float(xw[g4].y << 16);
            gacc[g4][3] = __uint_as_float(xw[g4].y & 0xffff0000u);
        }
        // ---- prefetch t+1 (An and AXWx) — latency hides under the MFMAs ----
        if (t + 1 < WN_) { xq += 4096; anp += 1024; }
        #pragma unroll
        for (int g4 = 0; g4 < 4; g4++) xw[g4] = xq[g4 * 512];
        anf = *(const short8*)anp;
        ldsbar();                                   // P ready
        // ---- g += P @ Wh' ----
        #pragma unroll
        for (int kb = 0; kb < 4; kb++) {
            short8 pA = *(const short8*)&P_lds[(mt * 16 + l15) * 136 + kb * 32 + quad * 8];
            #pragma unroll
            for (int g4 = 0; g4 < 4; g4++)
                gacc[g4] = __builtin_amdgcn_mfma_f32_16x16x32_bf16(pA, Bw[g4][kb], gacc[g4], 0, 0, 0);
        }
        // ---- gates + state (args pre-scaled by -log2e / -2log2e) ----
        #pragma unroll
        for (int r = 0; r < 4; r++) {
            float si = rcpa(1.f + ex2(gacc[0][r]));
            float sf = rcpa(1.f + ex2(gacc[1][r]));
            float so = rcpa(1.f + ex2(gacc[2][r]));
            float tc = 2.f * rcpa(1.f + ex2(gacc[3][r])) - 1.f;
            float cn = sf * Cst[r] + si * tc;
            float tn = 2.f * rcpa(1.f + ex2(cn * SC_C)) - 1.f;
            float hn = so * tn;
            Cst[r] = cn;
            H2t[r] = Hst[r];
            Hst[r] = hn;
        }
        // ---- HpT(t+1): packed b64 write [h][4 consecutive k] ----
        if (t + 1 < WN_) {
            const float dninv = (t + 1 == 1) ? 0.5f : (1.f / 3.f);
            short4v hv;
            #pragma unroll
            for (int r = 0; r < 4; r++)
                hv[r] = (short)f2bf((2.f * Hst[r] + H2t[r]) * dninv);
            *(short4v*)&HpT[buf ^ 1][(hb * 16 + l15) * 40 + mt * 16 + quad * 4] = hv;
        }
        // ---- Hsq partial (per-mt, plain store — LAST VMEM op of the step) ----
        {
            float s = Hst[0] + Hst[1] + Hst[2] + Hst[3];
            s += __shfl_xor(s, 16); s += __shfl_xor(s, 32);
            if (quad == 0)
                Hsq2[((bt0 + t) * 2 + mt) * HID_ + hb * 16 + l15] = s;
        }
    }
}

// ---------------------------------------------------------------------------
// Kernel 6: temporal attention pooling + classifier (unchanged).
// ---------------------------------------------------------------------------
__global__ __launch_bounds__(128) void final_kernel(
    const float* __restrict__ Hsq2, const float* __restrict__ Hsm,
    const float* __restrict__ q_t, const float* __restrict__ q_s,
    const float* __restrict__ cls_w, const float* __restrict__ cls_b,
    float* __restrict__ out)
{
    __shared__ float red[128];
    __shared__ float wt[WN_];
    const int b = blockIdx.x, tid = threadIdx.x;
    float v = q_t[tid];
    red[tid] = v * v;
    __syncthreads();
    for (int off = 64; off; off >>= 1) {
        if (tid < off) red[tid] += red[tid + off];
        __syncthreads();
    }
    const float qtn = sqrtf(red[0]) + 1e-8f;
    __syncthreads();
    float v2 = (tid < D_) ? q_s[tid] : 0.f;
    red[tid] = v2 * v2;
    __syncthreads();
    for (int off = 64; off; off >>= 1) {
        if (tid < off) red[tid] += red[tid + off];
        __syncthreads();
    }
    const float qsn = sqrtf(red[0]) + 1e-8f;
    __syncthreads();
    float sc_t = -1e30f;
    if (tid < WN_) {
        float s = 0.f;
        const float* zr = Hsq2 + ((size_t)b * WN_ + tid) * (2 * HID_);
        for (int h = 0; h < HID_; h++) s += (zr[h] + zr[HID_ + h]) * q_t[h];
        sc_t = s * (1.f / 32.f) / qtn;
    }
    red[tid] = sc_t;
    __syncthreads();
    for (int off = 64; off; off >>= 1) {
        if (tid < off) red[tid] = fmaxf(red[tid], red[tid + off]);
        __syncthreads();
    }
    const float mt_ = red[0];
    __syncthreads();
    float e_t = (tid < WN_) ? expf(sc_t - mt_) : 0.f;
    red[tid] = e_t;
    __syncthreads();
    for (int off = 64; off; off >>= 1) {
        if (tid < off) red[tid] += red[tid + off];
        __syncthreads();
    }
    const float sinv_t = 1.f / red[0];
    __syncthreads();
    if (tid < WN_) wt[tid] = e_t * sinv_t;
    __syncthreads();
    float part = 0.f;
    {
        float z = 0.f;
        for (int w = 0; w < WN_; w++) {
            const float* p = Hsq2 + ((size_t)b * WN_ + w) * (2 * HID_);
            z += wt[w] * (p[tid] + p[HID_ + tid]);
        }
        part += z * (1.f / 32.f) * cls_w[tid];
    }
    __syncthreads();
    float sc_s = -1e30f;
    if (tid < WN_) {
        float s = 0.f;
        const float* zr = Hsm + ((size_t)b * WN_ + tid) * D_;
        for (int dd = 0; dd < D_; dd++) s += zr[dd] * q_s[dd];
        sc_s = s / qsn;
    }
    red[tid] = sc_s;
    __syncthreads();
    for (int off = 64; off; off >>= 1) {
        if (tid < off) red[tid] = fmaxf(red[tid], red[tid + off]);
        __syncthreads();
    }
    const float ms_ = red[0];
    __syncthreads();
    float e_s = (tid < WN_) ? expf(sc_s - ms_) : 0.f;
    red[tid] = e_s;
    __syncthreads();
    for (int off = 64; off; off >>= 1) {
        if (tid < off) red[tid] += red[tid + off];
        __syncthreads();
    }
    const float sinv_s = 1.f / red[0];
    __syncthreads();
    if (tid < WN_) wt[tid] = e_s * sinv_s;
    __syncthreads();
    if (tid < D_) {
        float z = 0.f;
        for (int w = 0; w < WN_; w++)
            z += wt[w] * Hsm[((size_t)b * WN_ + w) * D_ + tid];
        part += z * cls_w[HID_ + tid];
    }
    red[tid] = part;
    __syncthreads();
    for (int off = 64; off; off >>= 1) {
        if (tid < off) red[tid] += red[tid + off];
        __syncthreads();
    }
    if (tid == 0) out[b] = 1.f / (1.f + expf(-(red[0] + cls_b[0])));
}

// ---------------------------------------------------------------------------
extern "C" void kernel_launch(void* const* d_in, const int* in_sizes, int n_in,
                              void* d_out, int out_size, void* d_ws, size_t ws_size,
                              hipStream_t stream)
{
    (void)in_sizes; (void)n_in; (void)out_size; (void)ws_size;
    const float* x     = (const float*)d_in[0];
    const float* w1    = (const float*)d_in[1];
    const float* b1    = (const float*)d_in[2];
    const float* w2    = (const float*)d_in[3];
    const float* b2    = (const float*)d_in[4];
    const float* pw    = (const float*)d_in[5];
    const float* pb    = (const float*)d_in[6];
    const float* proto = (const float*)d_in[7];
    const float* Wx    = (const float*)d_in[8];
    const float* bx    = (const float*)d_in[9];
    const float* Wh    = (const float*)d_in[10];
    const float* bh    = (const float*)d_in[11];
    const float* q_t   = (const float*)d_in[12];
    const float* q_s   = (const float*)d_in[13];
    const float* clw   = (const float*)d_in[14];
    const float* clb   = (const float*)d_in[15];

    float* ws = (float*)d_ws;
    us*    Hs_bf  = (us*)d_ws;                      // [0, 6553600)
    us*    S_bf   = (us*)(ws + 6553600);            // [6553600, 9830400)
    us*    XWx    = (us*)(ws + 9830400);            // XWxb, then AXWx in place
    us*    An_bf  = (us*)(ws + 22937600);           // [22937600, 23756800)
    float* Hsm    = ws + 23756800;                  // [23756800, 23859200)
    // Hsq2 reuses the S_bf region: S is only read by corr_kernel, which
    // completes before scan_kernel writes here (stream-ordered).
    float* Hsq2   = ws + 6553600;
    us*    WhT    = (us*)(ws + 24064000);           // [24064000, 24096768)
    us*    WxT    = (us*)(ws + 24096768);           // [24096768, 24113152)
    float* bs2    = ws + 24129536;                  // [24129536, 24130048)

    prep_kernel<<<386, 256, 0, stream>>>(Wh, Wx, bx, bh, WhT, WxT, bs2);
    conv_kernel<<<B_ * WN_, 256, 0, stream>>>(x, w1, b1, w2, b2, pw, pb, Hs_bf);
    xcwx_kernel<<<B_ * WN_, 256, 0, stream>>>(Hs_bf, proto, WxT, bs2,
                                              S_bf, XWx, Hsm);
    corr_kernel<<<B_ * WN_, 256, 0, stream>>>(x, S_bf, An_bf, XWx);
    scan_kernel<<<B_, 1024, 0, stream>>>(An_bf, XWx, WhT, Hsq2);
    final_kernel<<<B_, 128, 0, stream>>>(Hsq2, Hsm, q_t, q_s, clw, clb,
                                         (float*)d_out);
}

// Round 8
// 539.990 us; speedup vs baseline: 1.3419x; 1.0143x over previous
//
#include <hip/hip_runtime.h>

#define B_   16
#define T_   3000
#define N_   128
#define WIN_ 30
#define WN_  100
#define D_   64
#define HID_ 128
#define K_   32
#define G4_  512   // 4*HID_

typedef unsigned short us;
typedef __attribute__((ext_vector_type(8))) short short8;
typedef __attribute__((ext_vector_type(4))) short short4v;
typedef __attribute__((ext_vector_type(4))) float floatx4;

__device__ __forceinline__ us f2bf(float f) {
    unsigned u = __float_as_uint(f);
    u += 0x7fffu + ((u >> 16) & 1u);
    return (us)(u >> 16);
}
__device__ __forceinline__ float bf2f(us h) {
    return __uint_as_float(((unsigned)h) << 16);
}
// Single-instruction v_rcp_f32 (~1 ulp; rcp(inf)=0 keeps saturation graceful).
__device__ __forceinline__ float rcpa(float x) { return __builtin_amdgcn_rcpf(x); }
__device__ __forceinline__ float ex2(float x) { return __builtin_amdgcn_exp2f(x); }
// Barrier WITHOUT vmcnt drain: LDS ordering only.  Safe when all global
// loads/stores crossing it are wave-private (consumed by issuing wave).
__device__ __forceinline__ void ldsbar() {
    __asm__ volatile("s_waitcnt lgkmcnt(0)\n\ts_barrier" ::: "memory");
}

// exp-prescale constants folded into the gate weights (r6):
//   gates i,f,o:  arg' = -log2e   * arg   -> sig(arg)  = rcp(1+2^arg')
//   gate  c:      arg' = -2*log2e * arg   -> tanh(arg) = 2*rcp(1+2^arg')-1
#define SC_IFO (-1.4426950408889634f)
#define SC_C   (-2.8853900817779268f)

// ---------------------------------------------------------------------------
// Kernel 1 (r8): conv + xcwx FUSED.  conv's epilogue writes Hnd[n][d] and
// HsT[d][n] in LDS directly (bit-identical to the old Hs global round-trip
// + xcwx staging decode).  Hs global buffer is gone (26 MB w + 26 MB r
// saved), as is xcwx's staging pass and one 1600-block launch.
// LDS pool = 69120 B, identical to conv's old footprint; xcwx views alias
// conv regions that are dead by the time they're written:
//   us idx: xs_all[0,7680) h1s[7680,19200) Ms[19200,29440)
//           PwT_hi[29440,32000) PwT_lo[32000,34560)
//   Hnd[0,9216) HsT[9216,17920)           <- over dead xs_all+h1s
//   PT_hi[17920,20224) SsT_hi[20224,24576)
//   XcA_hi[24576,26880) bias[26880,27904) <- over dead h1s-tail+Ms
// All short8 bases stay 16B-aligned (strides 72/136 us; bases mult of 8 us).
// ---------------------------------------------------------------------------
__global__ __launch_bounds__(256) void convx_kernel(
    const float* __restrict__ x, const float* __restrict__ w1,
    const float* __restrict__ b1, const float* __restrict__ w2,
    const float* __restrict__ b2, const float* __restrict__ pw,
    const float* __restrict__ pb, const float* __restrict__ proto,
    const us* __restrict__ WxT, const float* __restrict__ bs2,
    us* __restrict__ S_out, us* __restrict__ XWx, float* __restrict__ Hsm)
{
    __shared__ __align__(16) us pool[34560];
    float* xs_all = (float*)pool;            // [30*128]
    us*    h1s    = pool + 7680;             // [8*36*40]
    float* Ms     = (float*)(pool + 19200);  // [128*40]
    us*    PwT_hi = pool + 29440;            // [64*40]
    us*    PwT_lo = pool + 32000;            // [64*40]
    us*    Hnd    = pool;                    // [128*72]
    us*    HsT    = pool + 9216;             // [64*136]
    us*    PT_hi  = pool + 17920;            // [32*72]
    us*    SsT_hi = pool + 20224;            // [32*136]
    us*    XcA_hi = pool + 24576;            // [32*72]
    float* bias   = (float*)(pool + 26880);  // [512]

    const int tid = threadIdx.x;
    const int win = blockIdx.x;
    const int b = win / WN_, w = win - b * WN_;
    const float* xb = x + ((size_t)b * T_ + (size_t)w * WIN_) * N_;
    const int lane = tid & 63, wv = tid >> 6;
    const int l15 = lane & 15, quad = lane >> 4;

    // ======================= conv part (r6-verified) =======================
    {
        const float4* xb4 = (const float4*)xb;
        float4* xs4 = (float4*)xs_all;
        for (int i = tid; i < 960; i += 256) xs4[i] = xb4[i];
    }
    for (int i = tid; i < 2048; i += 256) {
        int co = i >> 6, d = i & 63;
        float v = pw[i];
        us hi = f2bf(v);
        PwT_hi[d * 40 + co] = hi;
        PwT_lo[d * 40 + co] = f2bf(v - bf2f(hi));
    }
    for (int i = tid; i < 1920; i += 256) {            // zero h1 pad rows
        int s = i / 240, r = i % 240;
        int ti = r / 40, c = r % 40;
        int tp = (ti < 2) ? ti : (30 + ti);
        h1s[(s * 36 + tp) * 40 + c] = 0;
    }
    short8 whf[2][5];
    #pragma unroll
    for (int cot = 0; cot < 2; cot++)
        #pragma unroll
        for (int dk = 0; dk < 5; dk++)
            #pragma unroll
            for (int j = 0; j < 8; j++)
                whf[cot][dk][j] = (short)f2bf(w2[(cot * 16 + l15) * 160 + (quad * 8 + j) * 5 + dk]);
    const float b2c0 = b2[l15], b2c1 = b2[16 + l15];
    const int ci2 = lane & 15, th = (lane >> 4) & 1, sloc = lane >> 5;
    float w1ra[5], w1rb[5];
    #pragma unroll
    for (int k = 0; k < 5; k++) {
        w1ra[k] = w1[(2 * ci2) * 5 + k];
        w1rb[k] = w1[(2 * ci2 + 1) * 5 + k];
    }
    const float b1a = b1[2 * ci2], b1b = b1[2 * ci2 + 1];
    float pbv[4];
    #pragma unroll
    for (int nt = 0; nt < 4; nt++) pbv[nt] = pb[nt * 16 + l15];
    ldsbar();

    for (int g = 0; g < 16; g++) {
        const int n1 = g * 8 + wv * 2 + sloc;
        {
            float xr[19];
            #pragma unroll
            for (int u = 0; u < 19; u++) {
                int p = th * 15 - 2 + u;
                xr[u] = ((unsigned)p < 30u) ? xs_all[p * 128 + n1] : 0.f;
            }
            const int rbase = (wv * 2 + sloc) * 36 + 2 + th * 15;
            #pragma unroll
            for (int tt = 0; tt < 15; tt++) {
                float aa = b1a, ab = b1b;
                #pragma unroll
                for (int k = 0; k < 5; k++) {
                    aa += xr[tt + k] * w1ra[k];
                    ab += xr[tt + k] * w1rb[k];
                }
                unsigned pk = (unsigned)f2bf(fmaxf(aa, 0.f))
                            | ((unsigned)f2bf(fmaxf(ab, 0.f)) << 16);
                *(unsigned*)&h1s[(rbase + tt) * 40 + 2 * ci2] = pk;
            }
        }
        __builtin_amdgcn_wave_barrier();
        #pragma unroll
        for (int s2 = 0; s2 < 2; s2++) {
            const int sl = wv * 2 + s2;
            const int nn = g * 8 + sl;
            floatx4 c00 = {b2c0, b2c0, b2c0, b2c0};
            floatx4 c01 = {b2c1, b2c1, b2c1, b2c1};
            floatx4 c10 = {b2c0, b2c0, b2c0, b2c0};
            floatx4 c11 = {b2c1, b2c1, b2c1, b2c1};
            #pragma unroll
            for (int dk = 0; dk < 5; dk++) {
                short8 a0 = *(const short8*)&h1s[(sl * 36 + l15 + dk) * 40 + quad * 8];
                short8 a1 = *(const short8*)&h1s[(sl * 36 + 16 + l15 + dk) * 40 + quad * 8];
                c00 = __builtin_amdgcn_mfma_f32_16x16x32_bf16(a0, whf[0][dk], c00, 0, 0, 0);
                c01 = __builtin_amdgcn_mfma_f32_16x16x32_bf16(a0, whf[1][dk], c01, 0, 0, 0);
                c10 = __builtin_amdgcn_mfma_f32_16x16x32_bf16(a1, whf[0][dk], c10, 0, 0, 0);
                c11 = __builtin_amdgcn_mfma_f32_16x16x32_bf16(a1, whf[1][dk], c11, 0, 0, 0);
            }
            float s0 = 0.f, s1 = 0.f;
            #pragma unroll
            for (int r = 0; r < 4; r++) {
                s0 += fmaxf(c00[r], 0.f);
                s1 += fmaxf(c01[r], 0.f);
                float m0 = (quad * 4 + r < 14) ? fmaxf(c10[r], 0.f) : 0.f;
                float m1 = (quad * 4 + r < 14) ? fmaxf(c11[r], 0.f) : 0.f;
                s0 += m0; s1 += m1;
            }
            s0 += __shfl_xor(s0, 16); s0 += __shfl_xor(s0, 32);
            s1 += __shfl_xor(s1, 16); s1 += __shfl_xor(s1, 32);
            if (quad == 0) {
                Ms[nn * 40 + l15]      = s0 * (1.f / 30.f);
                Ms[nn * 40 + 16 + l15] = s1 * (1.f / 30.f);
            }
        }
        __builtin_amdgcn_wave_barrier();
    }
    ldsbar();
    // ---- epilogue: proj MFMAs; write results DIRECTLY to Hnd/HsT in LDS ----
    {
        short8 Ah[2], Al[2];
        #pragma unroll
        for (int i = 0; i < 2; i++) {
            const int mt = wv * 2 + i;
            float4 v0 = *(const float4*)&Ms[(mt * 16 + l15) * 40 + quad * 8];
            float4 v1 = *(const float4*)&Ms[(mt * 16 + l15) * 40 + quad * 8 + 4];
            float vv[8] = {v0.x, v0.y, v0.z, v0.w, v1.x, v1.y, v1.z, v1.w};
            #pragma unroll
            for (int j = 0; j < 8; j++) {
                us hi = f2bf(vv[j]);
                Ah[i][j] = (short)hi;
                Al[i][j] = (short)f2bf(vv[j] - bf2f(hi));
            }
        }
        #pragma unroll
        for (int id = 0; id < 8; id++) {
            const int i = id >> 2, nt = id & 3;
            short8 Bh = *(const short8*)&PwT_hi[(nt * 16 + l15) * 40 + quad * 8];
            short8 Bl = *(const short8*)&PwT_lo[(nt * 16 + l15) * 40 + quad * 8];
            floatx4 a = {pbv[nt], pbv[nt], pbv[nt], pbv[nt]};
            a = __builtin_amdgcn_mfma_f32_16x16x32_bf16(Ah[i], Bh, a, 0, 0, 0);
            a = __builtin_amdgcn_mfma_f32_16x16x32_bf16(Al[i], Bh, a, 0, 0, 0);
            a = __builtin_amdgcn_mfma_f32_16x16x32_bf16(Ah[i], Bl, a, 0, 0, 0);
            const int mt = wv * 2 + i;
            const int d_ = nt * 16 + l15;
            #pragma unroll
            for (int r = 0; r < 4; r++) {
                const int n_ = mt * 16 + quad * 4 + r;
                us hv = f2bf(a[r]);
                Hnd[n_ * 72 + d_] = hv;        // same bits the old path stored
                HsT[d_ * 136 + n_] = hv;       // and re-decoded from global
            }
        }
    }
    ldsbar();   // Hnd/HsT complete; all Ms/PwT reads complete
    // ---- stage PT + bias (over dead Ms region) ----
    for (int i = tid; i < 2048; i += 256) {
        int k = i >> 6, d = i & 63;
        PT_hi[k * 72 + d] = f2bf(proto[i]);
    }
    for (int i = tid; i < 512; i += 256) bias[i] = bs2[i];
    __syncthreads();

    // ======================= xcwx part (r6-verified) =======================
    floatx4 lg[2][2];
    #pragma unroll
    for (int p = 0; p < 2; p++) {
        const int mt = wv * 2 + p;
        #pragma unroll
        for (int kt = 0; kt < 2; kt++) {
            floatx4 a = {0.f, 0.f, 0.f, 0.f};
            #pragma unroll
            for (int kb = 0; kb < 2; kb++) {
                short8 af  = *(const short8*)&Hnd[(mt * 16 + l15) * 72 + kb * 32 + quad * 8];
                short8 bhf = *(const short8*)&PT_hi[(kt * 16 + l15) * 72 + kb * 32 + quad * 8];
                a = __builtin_amdgcn_mfma_f32_16x16x32_bf16(af, bhf, a, 0, 0, 0);
            }
            lg[p][kt] = a;
        }
    }
    #pragma unroll
    for (int p = 0; p < 2; p++) {
        #pragma unroll
        for (int r = 0; r < 4; r++) {
            float v0 = lg[p][0][r], v1 = lg[p][1][r];
            float m = fmaxf(v0, v1);
            #pragma unroll
            for (int off = 8; off; off >>= 1) m = fmaxf(m, __shfl_xor(m, off));
            float e0 = expf(v0 - m), e1 = expf(v1 - m);
            float s = e0 + e1;
            #pragma unroll
            for (int off = 8; off; off >>= 1) s += __shfl_xor(s, off);
            float inv = 1.f / s;
            e0 *= inv; e1 *= inv;
            const int n = (wv * 2 + p) * 16 + quad * 4 + r;
            us h0 = f2bf(e0), h1 = f2bf(e1);
            SsT_hi[l15 * 136 + n]        = h0;
            SsT_hi[(16 + l15) * 136 + n] = h1;
            S_out[(size_t)win * 4096 + n * 32 + l15]      = h0;
            S_out[(size_t)win * 4096 + n * 32 + 16 + l15] = h1;
        }
    }
    __syncthreads();
    {
        const int d = tid >> 2, seg = tid & 3;
        float acc = 0.f;
        const unsigned* hp2 = (const unsigned*)&HsT[d * 136 + seg * 32];
        #pragma unroll
        for (int q = 0; q < 16; q++) {
            unsigned v = hp2[q];
            acc += bf2f((us)(v & 0xffff)) + bf2f((us)(v >> 16));
        }
        acc += __shfl_xor(acc, 1);
        acc += __shfl_xor(acc, 2);
        if (seg == 0) Hsm[(size_t)win * 64 + d] = acc * (1.f / 128.f);
    }
    #pragma unroll
    for (int p = 0; p < 2; p++) {
        const int id = wv * 2 + p, mt = id >> 2, nt = id & 3;
        floatx4 a = {0.f, 0.f, 0.f, 0.f};
        #pragma unroll
        for (int kb = 0; kb < 4; kb++) {
            short8 ah = *(const short8*)&SsT_hi[(mt * 16 + l15) * 136 + kb * 32 + quad * 8];
            short8 bf_ = *(const short8*)&HsT[(nt * 16 + l15) * 136 + kb * 32 + quad * 8];
            a = __builtin_amdgcn_mfma_f32_16x16x32_bf16(ah, bf_, a, 0, 0, 0);
        }
        #pragma unroll
        for (int r = 0; r < 4; r++) {
            const int k = mt * 16 + quad * 4 + r, d = nt * 16 + l15;
            XcA_hi[k * 72 + d] = f2bf(a[r]);
        }
    }
    __syncthreads();
    {
        short8 Axc[2][2];
        #pragma unroll
        for (int mt = 0; mt < 2; mt++)
            #pragma unroll
            for (int kb = 0; kb < 2; kb++)
                Axc[mt][kb] = *(const short8*)&XcA_hi[(mt * 16 + l15) * 72 + kb * 32 + quad * 8];
        #pragma unroll 1
        for (int i = 0; i < 8; i++) {
            const int nt = wv + 4 * i;
            const float bv = bias[nt * 16 + l15];
            floatx4 acc[2];
            acc[0] = (floatx4){bv, bv, bv, bv};
            acc[1] = (floatx4){bv, bv, bv, bv};
            #pragma unroll
            for (int kb = 0; kb < 2; kb++) {
                short8 wh8 = *(const short8*)&WxT[(size_t)(nt * 16 + l15) * 64 + kb * 32 + quad * 8];
                #pragma unroll
                for (int mt = 0; mt < 2; mt++)
                    acc[mt] = __builtin_amdgcn_mfma_f32_16x16x32_bf16(Axc[mt][kb], wh8, acc[mt], 0, 0, 0);
            }
            #pragma unroll
            for (int mt = 0; mt < 2; mt++) {
                uint2 pk;
                pk.x = (unsigned)f2bf(acc[mt][0]) | ((unsigned)f2bf(acc[mt][1]) << 16);
                pk.y = (unsigned)f2bf(acc[mt][2]) | ((unsigned)f2bf(acc[mt][3]) << 16);
                ((uint2*)XWx)[((size_t)win * 64 + mt * 32 + nt) * 64 + lane] = pk;
            }
        }
    }
}

// ---------------------------------------------------------------------------
// Kernel 2: prep — r6 exp-prescale fold (verified).
// ---------------------------------------------------------------------------
__global__ __launch_bounds__(256) void prep_kernel(
    const float* __restrict__ Wh, const float* __restrict__ Wx,
    const float* __restrict__ bx, const float* __restrict__ bh,
    us* __restrict__ WhT, us* __restrict__ WxT, float* __restrict__ bs2)
{
    int i = blockIdx.x * 256 + threadIdx.x;
    if (i < 65536) {
        int jj = i >> 7, h = i & 127;
        float sc = (jj >> 7) == 3 ? SC_C : SC_IFO;
        WhT[i] = f2bf(Wh[h * G4_ + jj] * sc);
    } else if (i < 98304) {
        int j = i - 65536;
        int jj = j >> 6, d = j & 63;
        float sc = (jj >> 7) == 3 ? SC_C : SC_IFO;
        WxT[j] = f2bf(Wx[d * G4_ + jj] * sc);
    } else if (i < 98816) {
        int jj = i - 98304;
        float sc = (jj >> 7) == 3 ? SC_C : SC_IFO;
        bs2[jj] = (bx[jj] + bh[jj]) * sc;
    }
}

// ---------------------------------------------------------------------------
// Kernel 3: corr — r7 vectorized staging (verified).
// ---------------------------------------------------------------------------
__global__ __launch_bounds__(256) void corr_kernel(
    const float* __restrict__ x, const us* __restrict__ S_bf,
    us* __restrict__ An, us* __restrict__ XWx)
{
    __shared__ __align__(16) float xs[30 * 128];    // aliased by XA
    __shared__ __align__(16) us SsT[32 * 136];
    __shared__ __align__(16) us pool[21760];        // CB | AST, later XWT
    __shared__ float Acs[32 * 33];
    __shared__ __align__(16) us AnL[32 * 40];
    __shared__ float sinv[128];
    __shared__ float dinv[32];
    us* XA  = (us*)xs;                              // [128][40]
    us* CB  = pool;                                 // [128][136]
    us* AST = pool + 17408;                         // [32][136]
    us* XWT = pool;                                 // [512][40]
    const int tid = threadIdx.x;
    const int win = blockIdx.x;
    const int b = win / WN_, w = win - b * WN_;
    const float* xb = x + ((size_t)b * T_ + (size_t)w * WIN_) * N_;
    const int lane = tid & 63, wv = tid >> 6;
    const int l15 = lane & 15, quad = lane >> 4;
    const float inv29 = 1.f / (WIN_ - 1 + 1e-8f);

    {
        const float4* xb4 = (const float4*)xb;
        float4* xs4 = (float4*)xs;
        for (int i = tid; i < 960; i += 256) xs4[i] = xb4[i];
    }
    {
        const uint2* sp = (const uint2*)(S_bf + (size_t)win * 4096);
        for (int i4 = tid; i4 < 1024; i4 += 256) {
            uint2 v = sp[i4];
            int n = i4 >> 3, k0 = (i4 & 7) * 4;
            SsT[(k0 + 0) * 136 + n] = (us)(v.x & 0xffff);
            SsT[(k0 + 1) * 136 + n] = (us)(v.x >> 16);
            SsT[(k0 + 2) * 136 + n] = (us)(v.y & 0xffff);
            SsT[(k0 + 3) * 136 + n] = (us)(v.y >> 16);
        }
    }
    __syncthreads();
    float xr[30];
    if (tid < 128) {
        const int n = tid;
        float mean = 0.f;
        #pragma unroll
        for (int l = 0; l < 30; l++) { xr[l] = xs[l * 128 + n]; mean += xr[l]; }
        mean *= (1.f / 30.f);
        float var = 0.f;
        #pragma unroll
        for (int l = 0; l < 30; l++) {
            float v = xr[l] - mean;
            var += v * v;
            xr[l] = v;
        }
        var *= inv29;
        sinv[tid] = rsqrtf(fmaxf(var, 1e-8f));
    }
    __syncthreads();
    if (tid < 128) {
        #pragma unroll
        for (int l = 0; l < 30; l++) XA[tid * 40 + l] = f2bf(xr[l]);
        XA[tid * 40 + 30] = 0; XA[tid * 40 + 31] = 0;
    }
    __syncthreads();
    #pragma unroll 1
    for (int q = 0; q < 16; q++) {
        const int id = wv * 16 + q, mt = id >> 3, nt = id & 7;
        short8 a = *(const short8*)&XA[(mt * 16 + l15) * 40 + quad * 8];
        short8 bb = *(const short8*)&XA[(nt * 16 + l15) * 40 + quad * 8];
        floatx4 d = {0.f, 0.f, 0.f, 0.f};
        d = __builtin_amdgcn_mfma_f32_16x16x32_bf16(a, bb, d, 0, 0, 0);
        const int m = nt * 16 + l15;
        const float sm = sinv[m];
        #pragma unroll
        for (int r = 0; r < 4; r++) {
            const int n = mt * 16 + quad * 4 + r;
            float v = d[r] * inv29 * sinv[n] * sm;
            if (n == m) v = 1.f;
            CB[n * 136 + m] = f2bf(v);
        }
    }
    __syncthreads();
    #pragma unroll 1
    for (int q = 0; q < 4; q++) {
        const int id = wv * 4 + q, mt = id >> 1, lt = id & 1;
        floatx4 d = {0.f, 0.f, 0.f, 0.f};
        #pragma unroll
        for (int kb = 0; kb < 4; kb++) {
            short8 a = *(const short8*)&CB[(mt * 16 + l15) * 136 + kb * 32 + quad * 8];
            short8 bb = *(const short8*)&SsT[(lt * 16 + l15) * 136 + kb * 32 + quad * 8];
            d = __builtin_amdgcn_mfma_f32_16x16x32_bf16(a, bb, d, 0, 0, 0);
        }
        const int l = lt * 16 + l15;
        #pragma unroll
        for (int r = 0; r < 4; r++)
            AST[l * 136 + mt * 16 + quad * 4 + r] = f2bf(d[r]);
    }
    __syncthreads();
    {
        const int kt = wv >> 1, lt = wv & 1;
        floatx4 d = {0.f, 0.f, 0.f, 0.f};
        #pragma unroll
        for (int kb = 0; kb < 4; kb++) {
            short8 a = *(const short8*)&SsT[(kt * 16 + l15) * 136 + kb * 32 + quad * 8];
            short8 bb = *(const short8*)&AST[(lt * 16 + l15) * 136 + kb * 32 + quad * 8];
            d = __builtin_amdgcn_mfma_f32_16x16x32_bf16(a, bb, d, 0, 0, 0);
        }
        #pragma unroll
        for (int r = 0; r < 4; r++)
            Acs[(kt * 16 + quad * 4 + r) * 33 + lt * 16 + l15] = d[r];
    }
    __syncthreads();
    float symv[4];
    {
        int l = tid & 31, kb = tid >> 5;
        for (int r = 0; r < 4; r++) {
            int k = kb + 8 * r;
            symv[r] = 0.5f * (Acs[k * 33 + l] + Acs[l * 33 + k]) + ((k == l) ? 1.f : 0.f);
        }
    }
    __syncthreads();
    {
        int l = tid & 31, kb = tid >> 5;
        for (int r = 0; r < 4; r++) Acs[(kb + 8 * r) * 33 + l] = symv[r];
    }
    __syncthreads();
    if (tid < K_) {
        float s = 0.f;
        for (int l = 0; l < K_; l++) s += Acs[tid * 33 + l];
        dinv[tid] = rsqrtf(fmaxf(s, 1e-8f));
    }
    __syncthreads();
    us* Anw = An + (size_t)win * K_ * K_;
    for (int i = tid; i < K_ * K_; i += 256) {
        int k = i >> 5, l = i & 31;
        us v = f2bf(dinv[k] * Acs[k * 33 + l] * dinv[l]);
        Anw[i] = v;
        AnL[k * 40 + l] = v;
    }
    __syncthreads();
    // ---- stage XWxb (swizzled, uint4 loads) -> XWT[jj][m] (pool reuse) ----
    {
        const uint4* xw4 = (const uint4*)((const uint2*)XWx + (size_t)win * 4096);
        for (int i2 = tid; i2 < 2048; i2 += 256) {
            uint4 v = xw4[i2];
            int i = i2 * 2;
            int tile = i >> 6, lane2 = i & 63;
            int mt2 = tile >> 5, nt2 = tile & 31;
            int jj = nt2 * 16 + (lane2 & 15);
            int m0 = mt2 * 16 + (lane2 >> 4) * 4;
            *(uint2*)&XWT[jj * 40 + m0] = make_uint2(v.x, v.y);
            int jj1 = nt2 * 16 + ((lane2 + 1) & 15);
            int m01 = mt2 * 16 + (((lane2 + 1) >> 4)) * 4;
            *(uint2*)&XWT[jj1 * 40 + m01] = make_uint2(v.z, v.w);
        }
    }
    __syncthreads();
    // ---- AXWx = An @ XWxb, stored back in-place (swizzled) ----
    short8 anA[2];
    anA[0] = *(const short8*)&AnL[l15 * 40 + quad * 8];
    anA[1] = *(const short8*)&AnL[(16 + l15) * 40 + quad * 8];
    #pragma unroll 1
    for (int i = 0; i < 8; i++) {
        const int nt = wv + 4 * i;
        short8 bfr = *(const short8*)&XWT[(nt * 16 + l15) * 40 + quad * 8];
        #pragma unroll
        for (int mt2 = 0; mt2 < 2; mt2++) {
            floatx4 a = {0.f, 0.f, 0.f, 0.f};
            a = __builtin_amdgcn_mfma_f32_16x16x32_bf16(anA[mt2], bfr, a, 0, 0, 0);
            uint2 pk;
            pk.x = (unsigned)f2bf(a[0]) | ((unsigned)f2bf(a[1]) << 16);
            pk.y = (unsigned)f2bf(a[2]) | ((unsigned)f2bf(a[3]) << 16);
            ((uint2*)XWx)[((size_t)win * 64 + mt2 * 32 + nt) * 64 + lane] = pk;
        }
    }
}

// ---------------------------------------------------------------------------
// Kernel 4: GCLSTM scan — r6 body (verified 216.0 us), untouched.
// ---------------------------------------------------------------------------
__global__ __launch_bounds__(1024) void scan_kernel(
    const us* __restrict__ An_bf,   // [bt][k][m]
    const us* __restrict__ AXWx,    // swizzled C-frag layout (gate-major jj)
    const us* __restrict__ WhT,     // [jj][h]
    float* __restrict__ Hsq2)       // [bt][2][128] partial sums (fully written)
{
    __shared__ __align__(16) us HpT[2][128 * 40];   // [h][k]
    __shared__ __align__(16) us P_lds[32 * 136];    // [k][h]

    const int tid  = threadIdx.x;
    const int lane = tid & 63;
    const int wv   = tid >> 6;          // 0..15
    const int b    = blockIdx.x;
    const int l15  = lane & 15, quad = lane >> 4;
    const int mt   = wv >> 3, hb = wv & 7;

    // Wh B-fragments: 4 gates x 4 kb = 64 VGPR
    short8 Bw[4][4];
    #pragma unroll
    for (int g4 = 0; g4 < 4; g4++) {
        const int jj = g4 * 128 + hb * 16 + l15;
        #pragma unroll
        for (int kb = 0; kb < 4; kb++)
            Bw[g4][kb] = *(const short8*)&WhT[(size_t)jj * 128 + kb * 32 + quad * 8];
    }
    // state: cells (k = mt*16 + quad*4 + r, h = hb*16 + l15)
    float Cst[4] = {0.f, 0.f, 0.f, 0.f};
    float Hst[4] = {0.f, 0.f, 0.f, 0.f};
    float H2t[4] = {0.f, 0.f, 0.f, 0.f};

    for (int i = tid; i < 2560; i += 1024) ((unsigned*)HpT[0])[i] = 0;

    const size_t bt0 = (size_t)b * WN_;
    // strength-reduced prefetch pointers (advance per step)
    const uint2* xq = (const uint2*)AXWx + (bt0 * 64 + (size_t)mt * 32 + hb) * 64 + lane;
    const us*   anp = An_bf + bt0 * 1024 + (size_t)(mt * 16 + l15) * 32 + quad * 8;

    uint2 xw[4];
    #pragma unroll
    for (int g4 = 0; g4 < 4; g4++) xw[g4] = xq[g4 * 512];
    short8 anf = *(const short8*)anp;

    #pragma unroll 1
    for (int t = 0; t < WN_; t++) {
        const int buf = t & 1;
        ldsbar();                                   // HpT[buf] ready
        // ---- P = An @ Hp (1 MFMA/wave); anf was prefetched last step ----
        short8 hpB = *(const short8*)&HpT[buf][(hb * 16 + l15) * 40 + quad * 8];
        floatx4 Pa = {0.f, 0.f, 0.f, 0.f};
        Pa = __builtin_amdgcn_mfma_f32_16x16x32_bf16(anf, hpB, Pa, 0, 0, 0);
        #pragma unroll
        for (int r = 0; r < 4; r++)
            P_lds[(mt * 16 + quad * 4 + r) * 136 + hb * 16 + l15] = f2bf(Pa[r]);
        // ---- g acc init from AXWx(t) (1-op unpacks) ----
        floatx4 gacc[4];
        #pragma unroll
        for (int g4 = 0; g4 < 4; g4++) {
            gacc[g4][0] = __uint_as_float(xw[g4].x << 16);
            gacc[g4][1] = __uint_as_float(xw[g4].x & 0xffff0000u);
            gacc[g4][2] = __uint_as_float(xw[g4].y << 16);
            gacc[g4][3] = __uint_as_float(xw[g4].y & 0xffff0000u);
        }
        // ---- prefetch t+1 (An and AXWx) — latency hides under the MFMAs ----
        if (t + 1 < WN_) { xq += 4096; anp += 1024; }
        #pragma unroll
        for (int g4 = 0; g4 < 4; g4++) xw[g4] = xq[g4 * 512];
        anf = *(const short8*)anp;
        ldsbar();                                   // P ready
        // ---- g += P @ Wh' ----
        #pragma unroll
        for (int kb = 0; kb < 4; kb++) {
            short8 pA = *(const short8*)&P_lds[(mt * 16 + l15) * 136 + kb * 32 + quad * 8];
            #pragma unroll
            for (int g4 = 0; g4 < 4; g4++)
                gacc[g4] = __builtin_amdgcn_mfma_f32_16x16x32_bf16(pA, Bw[g4][kb], gacc[g4], 0, 0, 0);
        }
        // ---- gates + state (args pre-scaled by -log2e / -2log2e) ----
        #pragma unroll
        for (int r = 0; r < 4; r++) {
            float si = rcpa(1.f + ex2(gacc[0][r]));
            float sf = rcpa(1.f + ex2(gacc[1][r]));
            float so = rcpa(1.f + ex2(gacc[2][r]));
            float tc = 2.f * rcpa(1.f + ex2(gacc[3][r])) - 1.f;
            float cn = sf * Cst[r] + si * tc;
            float tn = 2.f * rcpa(1.f + ex2(cn * SC_C)) - 1.f;
            float hn = so * tn;
            Cst[r] = cn;
            H2t[r] = Hst[r];
            Hst[r] = hn;
        }
        // ---- HpT(t+1): packed b64 write [h][4 consecutive k] ----
        if (t + 1 < WN_) {
            const float dninv = (t + 1 == 1) ? 0.5f : (1.f / 3.f);
            short4v hv;
            #pragma unroll
            for (int r = 0; r < 4; r++)
                hv[r] = (short)f2bf((2.f * Hst[r] + H2t[r]) * dninv);
            *(short4v*)&HpT[buf ^ 1][(hb * 16 + l15) * 40 + mt * 16 + quad * 4] = hv;
        }
        // ---- Hsq partial (per-mt, plain store — LAST VMEM op of the step) ----
        {
            float s = Hst[0] + Hst[1] + Hst[2] + Hst[3];
            s += __shfl_xor(s, 16); s += __shfl_xor(s, 32);
            if (quad == 0)
                Hsq2[((bt0 + t) * 2 + mt) * HID_ + hb * 16 + l15] = s;
        }
    }
}

// ---------------------------------------------------------------------------
// Kernel 5: temporal attention pooling + classifier (unchanged).
// ---------------------------------------------------------------------------
__global__ __launch_bounds__(128) void final_kernel(
    const float* __restrict__ Hsq2, const float* __restrict__ Hsm,
    const float* __restrict__ q_t, const float* __restrict__ q_s,
    const float* __restrict__ cls_w, const float* __restrict__ cls_b,
    float* __restrict__ out)
{
    __shared__ float red[128];
    __shared__ float wt[WN_];
    const int b = blockIdx.x, tid = threadIdx.x;
    float v = q_t[tid];
    red[tid] = v * v;
    __syncthreads();
    for (int off = 64; off; off >>= 1) {
        if (tid < off) red[tid] += red[tid + off];
        __syncthreads();
    }
    const float qtn = sqrtf(red[0]) + 1e-8f;
    __syncthreads();
    float v2 = (tid < D_) ? q_s[tid] : 0.f;
    red[tid] = v2 * v2;
    __syncthreads();
    for (int off = 64; off; off >>= 1) {
        if (tid < off) red[tid] += red[tid + off];
        __syncthreads();
    }
    const float qsn = sqrtf(red[0]) + 1e-8f;
    __syncthreads();
    float sc_t = -1e30f;
    if (tid < WN_) {
        float s = 0.f;
        const float* zr = Hsq2 + ((size_t)b * WN_ + tid) * (2 * HID_);
        for (int h = 0; h < HID_; h++) s += (zr[h] + zr[HID_ + h]) * q_t[h];
        sc_t = s * (1.f / 32.f) / qtn;
    }
    red[tid] = sc_t;
    __syncthreads();
    for (int off = 64; off; off >>= 1) {
        if (tid < off) red[tid] = fmaxf(red[tid], red[tid + off]);
        __syncthreads();
    }
    const float mt_ = red[0];
    __syncthreads();
    float e_t = (tid < WN_) ? expf(sc_t - mt_) : 0.f;
    red[tid] = e_t;
    __syncthreads();
    for (int off = 64; off; off >>= 1) {
        if (tid < off) red[tid] += red[tid + off];
        __syncthreads();
    }
    const float sinv_t = 1.f / red[0];
    __syncthreads();
    if (tid < WN_) wt[tid] = e_t * sinv_t;
    __syncthreads();
    float part = 0.f;
    {
        float z = 0.f;
        for (int w = 0; w < WN_; w++) {
            const float* p = Hsq2 + ((size_t)b * WN_ + w) * (2 * HID_);
            z += wt[w] * (p[tid] + p[HID_ + tid]);
        }
        part += z * (1.f / 32.f) * cls_w[tid];
    }
    __syncthreads();
    float sc_s = -1e30f;
    if (tid < WN_) {
        float s = 0.f;
        const float* zr = Hsm + ((size_t)b * WN_ + tid) * D_;
        for (int dd = 0; dd < D_; dd++) s += zr[dd] * q_s[dd];
        sc_s = s / qsn;
    }
    red[tid] = sc_s;
    __syncthreads();
    for (int off = 64; off; off >>= 1) {
        if (tid < off) red[tid] = fmaxf(red[tid], red[tid + off]);
        __syncthreads();
    }
    const float ms_ = red[0];
    __syncthreads();
    float e_s = (tid < WN_) ? expf(sc_s - ms_) : 0.f;
    red[tid] = e_s;
    __syncthreads();
    for (int off = 64; off; off >>= 1) {
        if (tid < off) red[tid] += red[tid + off];
        __syncthreads();
    }
    const float sinv_s = 1.f / red[0];
    __syncthreads();
    if (tid < WN_) wt[tid] = e_s * sinv_s;
    __syncthreads();
    if (tid < D_) {
        float z = 0.f;
        for (int w = 0; w < WN_; w++)
            z += wt[w] * Hsm[((size_t)b * WN_ + w) * D_ + tid];
        part += z * cls_w[HID_ + tid];
    }
    red[tid] = part;
    __syncthreads();
    for (int off = 64; off; off >>= 1) {
        if (tid < off) red[tid] += red[tid + off];
        __syncthreads();
    }
    if (tid == 0) out[b] = 1.f / (1.f + expf(-(red[0] + cls_b[0])));
}

// ---------------------------------------------------------------------------
extern "C" void kernel_launch(void* const* d_in, const int* in_sizes, int n_in,
                              void* d_out, int out_size, void* d_ws, size_t ws_size,
                              hipStream_t stream)
{
    (void)in_sizes; (void)n_in; (void)out_size; (void)ws_size;
    const float* x     = (const float*)d_in[0];
    const float* w1    = (const float*)d_in[1];
    const float* b1    = (const float*)d_in[2];
    const float* w2    = (const float*)d_in[3];
    const float* b2    = (const float*)d_in[4];
    const float* pw    = (const float*)d_in[5];
    const float* pb    = (const float*)d_in[6];
    const float* proto = (const float*)d_in[7];
    const float* Wx    = (const float*)d_in[8];
    const float* bx    = (const float*)d_in[9];
    const float* Wh    = (const float*)d_in[10];
    const float* bh    = (const float*)d_in[11];
    const float* q_t   = (const float*)d_in[12];
    const float* q_s   = (const float*)d_in[13];
    const float* clw   = (const float*)d_in[14];
    const float* clb   = (const float*)d_in[15];

    float* ws = (float*)d_ws;
    // (Hs region [0, 6553600) now unused — conv+xcwx fused, no global Hs.)
    us*    S_bf   = (us*)(ws + 6553600);            // [6553600, 9830400)
    us*    XWx    = (us*)(ws + 9830400);            // XWxb, then AXWx in place
    us*    An_bf  = (us*)(ws + 22937600);           // [22937600, 23756800)
    float* Hsm    = ws + 23756800;                  // [23756800, 23859200)
    // Hsq2 reuses the S_bf region: S is only read by corr_kernel, which
    // completes before scan_kernel writes here (stream-ordered).
    float* Hsq2   = ws + 6553600;
    us*    WhT    = (us*)(ws + 24064000);           // [24064000, 24096768)
    us*    WxT    = (us*)(ws + 24096768);           // [24096768, 24113152)
    float* bs2    = ws + 24129536;                  // [24129536, 24130048)

    prep_kernel<<<386, 256, 0, stream>>>(Wh, Wx, bx, bh, WhT, WxT, bs2);
    convx_kernel<<<B_ * WN_, 256, 0, stream>>>(x, w1, b1, w2, b2, pw, pb,
                                               proto, WxT, bs2,
                                               S_bf, XWx, Hsm);
    corr_kernel<<<B_ * WN_, 256, 0, stream>>>(x, S_bf, An_bf, XWx);
    scan_kernel<<<B_, 1024, 0, stream>>>(An_bf, XWx, WhT, Hsq2);
    final_kernel<<<B_, 128, 0, stream>>>(Hsq2, Hsm, q_t, q_s, clw, clb,
                                         (float*)d_out);
}

// Round 9
// 537.577 us; speedup vs baseline: 1.3479x; 1.0045x over previous
//
#include <hip/hip_runtime.h>

#define B_   16
#define T_   3000
#define N_   128
#define WIN_ 30
#define WN_  100
#define D_   64
#define HID_ 128
#define K_   32
#define G4_  512   // 4*HID_

typedef unsigned short us;
typedef __attribute__((ext_vector_type(8))) short short8;
typedef __attribute__((ext_vector_type(4))) short short4v;
typedef __attribute__((ext_vector_type(4))) float floatx4;

__device__ __forceinline__ us f2bf(float f) {
    unsigned u = __float_as_uint(f);
    u += 0x7fffu + ((u >> 16) & 1u);
    return (us)(u >> 16);
}
__device__ __forceinline__ float bf2f(us h) {
    return __uint_as_float(((unsigned)h) << 16);
}
// Single-instruction v_rcp_f32 (~1 ulp; rcp(inf)=0 keeps saturation graceful).
__device__ __forceinline__ float rcpa(float x) { return __builtin_amdgcn_rcpf(x); }
__device__ __forceinline__ float ex2(float x) { return __builtin_amdgcn_exp2f(x); }
// Barrier WITHOUT vmcnt drain: LDS ordering only.  Safe when all global
// loads/stores crossing it are wave-private (consumed by issuing wave).
__device__ __forceinline__ void ldsbar() {
    __asm__ volatile("s_waitcnt lgkmcnt(0)\n\ts_barrier" ::: "memory");
}

// exp-prescale constants folded into the gate weights (r6):
//   gates i,f,o:  arg' = -log2e   * arg   -> sig(arg)  = rcp(1+2^arg')
//   gate  c:      arg' = -2*log2e * arg   -> tanh(arg) = 2*rcp(1+2^arg')-1
#define SC_IFO (-1.4426950408889634f)
#define SC_C   (-2.8853900817779268f)

// ---------------------------------------------------------------------------
// Kernel 1: conv + xcwx fused (r8-verified).  r9 change: S is written to
// global in S^T layout [k][n] with packed 8B stores (corr consumes [k][n];
// the lane already holds 4 consecutive n).  Bit-exact layout change.
// ---------------------------------------------------------------------------
__global__ __launch_bounds__(256) void convx_kernel(
    const float* __restrict__ x, const float* __restrict__ w1,
    const float* __restrict__ b1, const float* __restrict__ w2,
    const float* __restrict__ b2, const float* __restrict__ pw,
    const float* __restrict__ pb, const float* __restrict__ proto,
    const us* __restrict__ WxT, const float* __restrict__ bs2,
    us* __restrict__ S_out, us* __restrict__ XWx, float* __restrict__ Hsm)
{
    __shared__ __align__(16) us pool[34560];
    float* xs_all = (float*)pool;            // [30*128]
    us*    h1s    = pool + 7680;             // [8*36*40]
    float* Ms     = (float*)(pool + 19200);  // [128*40]
    us*    PwT_hi = pool + 29440;            // [64*40]
    us*    PwT_lo = pool + 32000;            // [64*40]
    us*    Hnd    = pool;                    // [128*72]
    us*    HsT    = pool + 9216;             // [64*136]
    us*    PT_hi  = pool + 17920;            // [32*72]
    us*    SsT_hi = pool + 20224;            // [32*136]
    us*    XcA_hi = pool + 24576;            // [32*72]
    float* bias   = (float*)(pool + 26880);  // [512]

    const int tid = threadIdx.x;
    const int win = blockIdx.x;
    const int b = win / WN_, w = win - b * WN_;
    const float* xb = x + ((size_t)b * T_ + (size_t)w * WIN_) * N_;
    const int lane = tid & 63, wv = tid >> 6;
    const int l15 = lane & 15, quad = lane >> 4;

    // ======================= conv part (r6-verified) =======================
    {
        const float4* xb4 = (const float4*)xb;
        float4* xs4 = (float4*)xs_all;
        for (int i = tid; i < 960; i += 256) xs4[i] = xb4[i];
    }
    for (int i = tid; i < 2048; i += 256) {
        int co = i >> 6, d = i & 63;
        float v = pw[i];
        us hi = f2bf(v);
        PwT_hi[d * 40 + co] = hi;
        PwT_lo[d * 40 + co] = f2bf(v - bf2f(hi));
    }
    for (int i = tid; i < 1920; i += 256) {            // zero h1 pad rows
        int s = i / 240, r = i % 240;
        int ti = r / 40, c = r % 40;
        int tp = (ti < 2) ? ti : (30 + ti);
        h1s[(s * 36 + tp) * 40 + c] = 0;
    }
    short8 whf[2][5];
    #pragma unroll
    for (int cot = 0; cot < 2; cot++)
        #pragma unroll
        for (int dk = 0; dk < 5; dk++)
            #pragma unroll
            for (int j = 0; j < 8; j++)
                whf[cot][dk][j] = (short)f2bf(w2[(cot * 16 + l15) * 160 + (quad * 8 + j) * 5 + dk]);
    const float b2c0 = b2[l15], b2c1 = b2[16 + l15];
    const int ci2 = lane & 15, th = (lane >> 4) & 1, sloc = lane >> 5;
    float w1ra[5], w1rb[5];
    #pragma unroll
    for (int k = 0; k < 5; k++) {
        w1ra[k] = w1[(2 * ci2) * 5 + k];
        w1rb[k] = w1[(2 * ci2 + 1) * 5 + k];
    }
    const float b1a = b1[2 * ci2], b1b = b1[2 * ci2 + 1];
    float pbv[4];
    #pragma unroll
    for (int nt = 0; nt < 4; nt++) pbv[nt] = pb[nt * 16 + l15];
    ldsbar();

    for (int g = 0; g < 16; g++) {
        const int n1 = g * 8 + wv * 2 + sloc;
        {
            float xr[19];
            #pragma unroll
            for (int u = 0; u < 19; u++) {
                int p = th * 15 - 2 + u;
                xr[u] = ((unsigned)p < 30u) ? xs_all[p * 128 + n1] : 0.f;
            }
            const int rbase = (wv * 2 + sloc) * 36 + 2 + th * 15;
            #pragma unroll
            for (int tt = 0; tt < 15; tt++) {
                float aa = b1a, ab = b1b;
                #pragma unroll
                for (int k = 0; k < 5; k++) {
                    aa += xr[tt + k] * w1ra[k];
                    ab += xr[tt + k] * w1rb[k];
                }
                unsigned pk = (unsigned)f2bf(fmaxf(aa, 0.f))
                            | ((unsigned)f2bf(fmaxf(ab, 0.f)) << 16);
                *(unsigned*)&h1s[(rbase + tt) * 40 + 2 * ci2] = pk;
            }
        }
        __builtin_amdgcn_wave_barrier();
        #pragma unroll
        for (int s2 = 0; s2 < 2; s2++) {
            const int sl = wv * 2 + s2;
            const int nn = g * 8 + sl;
            floatx4 c00 = {b2c0, b2c0, b2c0, b2c0};
            floatx4 c01 = {b2c1, b2c1, b2c1, b2c1};
            floatx4 c10 = {b2c0, b2c0, b2c0, b2c0};
            floatx4 c11 = {b2c1, b2c1, b2c1, b2c1};
            #pragma unroll
            for (int dk = 0; dk < 5; dk++) {
                short8 a0 = *(const short8*)&h1s[(sl * 36 + l15 + dk) * 40 + quad * 8];
                short8 a1 = *(const short8*)&h1s[(sl * 36 + 16 + l15 + dk) * 40 + quad * 8];
                c00 = __builtin_amdgcn_mfma_f32_16x16x32_bf16(a0, whf[0][dk], c00, 0, 0, 0);
                c01 = __builtin_amdgcn_mfma_f32_16x16x32_bf16(a0, whf[1][dk], c01, 0, 0, 0);
                c10 = __builtin_amdgcn_mfma_f32_16x16x32_bf16(a1, whf[0][dk], c10, 0, 0, 0);
                c11 = __builtin_amdgcn_mfma_f32_16x16x32_bf16(a1, whf[1][dk], c11, 0, 0, 0);
            }
            float s0 = 0.f, s1 = 0.f;
            #pragma unroll
            for (int r = 0; r < 4; r++) {
                s0 += fmaxf(c00[r], 0.f);
                s1 += fmaxf(c01[r], 0.f);
                float m0 = (quad * 4 + r < 14) ? fmaxf(c10[r], 0.f) : 0.f;
                float m1 = (quad * 4 + r < 14) ? fmaxf(c11[r], 0.f) : 0.f;
                s0 += m0; s1 += m1;
            }
            s0 += __shfl_xor(s0, 16); s0 += __shfl_xor(s0, 32);
            s1 += __shfl_xor(s1, 16); s1 += __shfl_xor(s1, 32);
            if (quad == 0) {
                Ms[nn * 40 + l15]      = s0 * (1.f / 30.f);
                Ms[nn * 40 + 16 + l15] = s1 * (1.f / 30.f);
            }
        }
        __builtin_amdgcn_wave_barrier();
    }
    ldsbar();
    // ---- epilogue: proj MFMAs; write results DIRECTLY to Hnd/HsT in LDS ----
    {
        short8 Ah[2], Al[2];
        #pragma unroll
        for (int i = 0; i < 2; i++) {
            const int mt = wv * 2 + i;
            float4 v0 = *(const float4*)&Ms[(mt * 16 + l15) * 40 + quad * 8];
            float4 v1 = *(const float4*)&Ms[(mt * 16 + l15) * 40 + quad * 8 + 4];
            float vv[8] = {v0.x, v0.y, v0.z, v0.w, v1.x, v1.y, v1.z, v1.w};
            #pragma unroll
            for (int j = 0; j < 8; j++) {
                us hi = f2bf(vv[j]);
                Ah[i][j] = (short)hi;
                Al[i][j] = (short)f2bf(vv[j] - bf2f(hi));
            }
        }
        #pragma unroll
        for (int id = 0; id < 8; id++) {
            const int i = id >> 2, nt = id & 3;
            short8 Bh = *(const short8*)&PwT_hi[(nt * 16 + l15) * 40 + quad * 8];
            short8 Bl = *(const short8*)&PwT_lo[(nt * 16 + l15) * 40 + quad * 8];
            floatx4 a = {pbv[nt], pbv[nt], pbv[nt], pbv[nt]};
            a = __builtin_amdgcn_mfma_f32_16x16x32_bf16(Ah[i], Bh, a, 0, 0, 0);
            a = __builtin_amdgcn_mfma_f32_16x16x32_bf16(Al[i], Bh, a, 0, 0, 0);
            a = __builtin_amdgcn_mfma_f32_16x16x32_bf16(Ah[i], Bl, a, 0, 0, 0);
            const int mt = wv * 2 + i;
            const int d_ = nt * 16 + l15;
            #pragma unroll
            for (int r = 0; r < 4; r++) {
                const int n_ = mt * 16 + quad * 4 + r;
                us hv = f2bf(a[r]);
                Hnd[n_ * 72 + d_] = hv;
                HsT[d_ * 136 + n_] = hv;
            }
        }
    }
    ldsbar();   // Hnd/HsT complete; all Ms/PwT reads complete
    // ---- stage PT + bias (over dead Ms region) ----
    for (int i = tid; i < 2048; i += 256) {
        int k = i >> 6, d = i & 63;
        PT_hi[k * 72 + d] = f2bf(proto[i]);
    }
    for (int i = tid; i < 512; i += 256) bias[i] = bs2[i];
    __syncthreads();

    // ======================= xcwx part (r6-verified) =======================
    floatx4 lg[2][2];
    #pragma unroll
    for (int p = 0; p < 2; p++) {
        const int mt = wv * 2 + p;
        #pragma unroll
        for (int kt = 0; kt < 2; kt++) {
            floatx4 a = {0.f, 0.f, 0.f, 0.f};
            #pragma unroll
            for (int kb = 0; kb < 2; kb++) {
                short8 af  = *(const short8*)&Hnd[(mt * 16 + l15) * 72 + kb * 32 + quad * 8];
                short8 bhf = *(const short8*)&PT_hi[(kt * 16 + l15) * 72 + kb * 32 + quad * 8];
                a = __builtin_amdgcn_mfma_f32_16x16x32_bf16(af, bhf, a, 0, 0, 0);
            }
            lg[p][kt] = a;
        }
    }
    #pragma unroll
    for (int p = 0; p < 2; p++) {
        short4v hv0, hv1;
        #pragma unroll
        for (int r = 0; r < 4; r++) {
            float v0 = lg[p][0][r], v1 = lg[p][1][r];
            float m = fmaxf(v0, v1);
            #pragma unroll
            for (int off = 8; off; off >>= 1) m = fmaxf(m, __shfl_xor(m, off));
            float e0 = expf(v0 - m), e1 = expf(v1 - m);
            float s = e0 + e1;
            #pragma unroll
            for (int off = 8; off; off >>= 1) s += __shfl_xor(s, off);
            float inv = 1.f / s;
            e0 *= inv; e1 *= inv;
            const int n = (wv * 2 + p) * 16 + quad * 4 + r;
            us h0 = f2bf(e0), h1 = f2bf(e1);
            SsT_hi[l15 * 136 + n]        = h0;
            SsT_hi[(16 + l15) * 136 + n] = h1;
            hv0[r] = (short)h0;
            hv1[r] = (short)h1;
        }
        // r9: S^T global layout [k][n], packed 8B stores (4 consecutive n)
        const int n0 = (wv * 2 + p) * 16 + quad * 4;
        *(short4v*)&S_out[(size_t)win * 4096 + l15 * 128 + n0]        = hv0;
        *(short4v*)&S_out[(size_t)win * 4096 + (16 + l15) * 128 + n0] = hv1;
    }
    __syncthreads();
    {
        const int d = tid >> 2, seg = tid & 3;
        float acc = 0.f;
        const unsigned* hp2 = (const unsigned*)&HsT[d * 136 + seg * 32];
        #pragma unroll
        for (int q = 0; q < 16; q++) {
            unsigned v = hp2[q];
            acc += bf2f((us)(v & 0xffff)) + bf2f((us)(v >> 16));
        }
        acc += __shfl_xor(acc, 1);
        acc += __shfl_xor(acc, 2);
        if (seg == 0) Hsm[(size_t)win * 64 + d] = acc * (1.f / 128.f);
    }
    #pragma unroll
    for (int p = 0; p < 2; p++) {
        const int id = wv * 2 + p, mt = id >> 2, nt = id & 3;
        floatx4 a = {0.f, 0.f, 0.f, 0.f};
        #pragma unroll
        for (int kb = 0; kb < 4; kb++) {
            short8 ah = *(const short8*)&SsT_hi[(mt * 16 + l15) * 136 + kb * 32 + quad * 8];
            short8 bf_ = *(const short8*)&HsT[(nt * 16 + l15) * 136 + kb * 32 + quad * 8];
            a = __builtin_amdgcn_mfma_f32_16x16x32_bf16(ah, bf_, a, 0, 0, 0);
        }
        #pragma unroll
        for (int r = 0; r < 4; r++) {
            const int k = mt * 16 + quad * 4 + r, d = nt * 16 + l15;
            XcA_hi[k * 72 + d] = f2bf(a[r]);
        }
    }
    __syncthreads();
    {
        short8 Axc[2][2];
        #pragma unroll
        for (int mt = 0; mt < 2; mt++)
            #pragma unroll
            for (int kb = 0; kb < 2; kb++)
                Axc[mt][kb] = *(const short8*)&XcA_hi[(mt * 16 + l15) * 72 + kb * 32 + quad * 8];
        #pragma unroll 1
        for (int i = 0; i < 8; i++) {
            const int nt = wv + 4 * i;
            const float bv = bias[nt * 16 + l15];
            floatx4 acc[2];
            acc[0] = (floatx4){bv, bv, bv, bv};
            acc[1] = (floatx4){bv, bv, bv, bv};
            #pragma unroll
            for (int kb = 0; kb < 2; kb++) {
                short8 wh8 = *(const short8*)&WxT[(size_t)(nt * 16 + l15) * 64 + kb * 32 + quad * 8];
                #pragma unroll
                for (int mt = 0; mt < 2; mt++)
                    acc[mt] = __builtin_amdgcn_mfma_f32_16x16x32_bf16(Axc[mt][kb], wh8, acc[mt], 0, 0, 0);
            }
            #pragma unroll
            for (int mt = 0; mt < 2; mt++) {
                uint2 pk;
                pk.x = (unsigned)f2bf(acc[mt][0]) | ((unsigned)f2bf(acc[mt][1]) << 16);
                pk.y = (unsigned)f2bf(acc[mt][2]) | ((unsigned)f2bf(acc[mt][3]) << 16);
                ((uint2*)XWx)[((size_t)win * 64 + mt * 32 + nt) * 64 + lane] = pk;
            }
        }
    }
}

// ---------------------------------------------------------------------------
// Kernel 2: prep — r6 exp-prescale fold (verified).
// ---------------------------------------------------------------------------
__global__ __launch_bounds__(256) void prep_kernel(
    const float* __restrict__ Wh, const float* __restrict__ Wx,
    const float* __restrict__ bx, const float* __restrict__ bh,
    us* __restrict__ WhT, us* __restrict__ WxT, float* __restrict__ bs2)
{
    int i = blockIdx.x * 256 + threadIdx.x;
    if (i < 65536) {
        int jj = i >> 7, h = i & 127;
        float sc = (jj >> 7) == 3 ? SC_C : SC_IFO;
        WhT[i] = f2bf(Wh[h * G4_ + jj] * sc);
    } else if (i < 98304) {
        int j = i - 65536;
        int jj = j >> 6, d = j & 63;
        float sc = (jj >> 7) == 3 ? SC_C : SC_IFO;
        WxT[j] = f2bf(Wx[d * G4_ + jj] * sc);
    } else if (i < 98816) {
        int jj = i - 98304;
        float sc = (jj >> 7) == 3 ? SC_C : SC_IFO;
        bs2[jj] = (bx[jj] + bh[jj]) * sc;
    }
}

// ---------------------------------------------------------------------------
// Kernel 3: corr — r9 changes:
//   (a) S^T read: 2 uint4 loads + 2 ds_write_b128 (was 4 uint2 + 16 scalar
//       LDS writes).  Alignment: SsT stride 136 us = 272 B = 17*16.
//   (b) stats phase parallelized over all 256 threads (n = tid>>1, 15
//       elements each, shfl_xor(1) combine) — halves the serial chain and
//       removes the half-idle block.  Reassociation is ulp-class.
// ---------------------------------------------------------------------------
__global__ __launch_bounds__(256) void corr_kernel(
    const float* __restrict__ x, const us* __restrict__ S_bf,
    us* __restrict__ An, us* __restrict__ XWx)
{
    __shared__ __align__(16) float xs[30 * 128];    // aliased by XA
    __shared__ __align__(16) us SsT[32 * 136];
    __shared__ __align__(16) us pool[21760];        // CB | AST, later XWT
    __shared__ float Acs[32 * 33];
    __shared__ __align__(16) us AnL[32 * 40];
    __shared__ float sinv[128];
    __shared__ float dinv[32];
    us* XA  = (us*)xs;                              // [128][40]
    us* CB  = pool;                                 // [128][136]
    us* AST = pool + 17408;                         // [32][136]
    us* XWT = pool;                                 // [512][40]
    const int tid = threadIdx.x;
    const int win = blockIdx.x;
    const int b = win / WN_, w = win - b * WN_;
    const float* xb = x + ((size_t)b * T_ + (size_t)w * WIN_) * N_;
    const int lane = tid & 63, wv = tid >> 6;
    const int l15 = lane & 15, quad = lane >> 4;
    const float inv29 = 1.f / (WIN_ - 1 + 1e-8f);

    {
        const float4* xb4 = (const float4*)xb;
        float4* xs4 = (float4*)xs;
        for (int i = tid; i < 960; i += 256) xs4[i] = xb4[i];
    }
    {
        const uint4* sp = (const uint4*)(S_bf + (size_t)win * 4096);
        for (int i4 = tid; i4 < 512; i4 += 256) {
            uint4 v = sp[i4];
            int k = i4 >> 4, n0 = (i4 & 15) * 8;
            *(uint4*)&SsT[k * 136 + n0] = v;
        }
    }
    __syncthreads();
    // ---- stats: all 256 threads; pair (n = tid>>1, half = tid&1) ----
    float xr[15];
    const int sn = tid >> 1, shalf = tid & 1;
    {
        const int l0 = shalf * 15;
        float sum = 0.f;
        #pragma unroll
        for (int l = 0; l < 15; l++) { xr[l] = xs[(l0 + l) * 128 + sn]; sum += xr[l]; }
        sum += __shfl_xor(sum, 1);
        float mean = sum * (1.f / 30.f);
        float var = 0.f;
        #pragma unroll
        for (int l = 0; l < 15; l++) {
            float v = xr[l] - mean;
            var += v * v;
            xr[l] = v;
        }
        var += __shfl_xor(var, 1);
        var *= inv29;
        if (shalf == 0) sinv[sn] = rsqrtf(fmaxf(var, 1e-8f));
    }
    __syncthreads();
    {
        const int l0 = shalf * 15;
        #pragma unroll
        for (int l = 0; l < 15; l++) XA[sn * 40 + l0 + l] = f2bf(xr[l]);
        if (shalf) { XA[sn * 40 + 30] = 0; XA[sn * 40 + 31] = 0; }
    }
    __syncthreads();
    #pragma unroll 1
    for (int q = 0; q < 16; q++) {
        const int id = wv * 16 + q, mt = id >> 3, nt = id & 7;
        short8 a = *(const short8*)&XA[(mt * 16 + l15) * 40 + quad * 8];
        short8 bb = *(const short8*)&XA[(nt * 16 + l15) * 40 + quad * 8];
        floatx4 d = {0.f, 0.f, 0.f, 0.f};
        d = __builtin_amdgcn_mfma_f32_16x16x32_bf16(a, bb, d, 0, 0, 0);
        const int m = nt * 16 + l15;
        const float sm = sinv[m];
        #pragma unroll
        for (int r = 0; r < 4; r++) {
            const int n = mt * 16 + quad * 4 + r;
            float v = d[r] * inv29 * sinv[n] * sm;
            if (n == m) v = 1.f;
            CB[n * 136 + m] = f2bf(v);
        }
    }
    __syncthreads();
    #pragma unroll 1
    for (int q = 0; q < 4; q++) {
        const int id = wv * 4 + q, mt = id >> 1, lt = id & 1;
        floatx4 d = {0.f, 0.f, 0.f, 0.f};
        #pragma unroll
        for (int kb = 0; kb < 4; kb++) {
            short8 a = *(const short8*)&CB[(mt * 16 + l15) * 136 + kb * 32 + quad * 8];
            short8 bb = *(const short8*)&SsT[(lt * 16 + l15) * 136 + kb * 32 + quad * 8];
            d = __builtin_amdgcn_mfma_f32_16x16x32_bf16(a, bb, d, 0, 0, 0);
        }
        const int l = lt * 16 + l15;
        #pragma unroll
        for (int r = 0; r < 4; r++)
            AST[l * 136 + mt * 16 + quad * 4 + r] = f2bf(d[r]);
    }
    __syncthreads();
    {
        const int kt = wv >> 1, lt = wv & 1;
        floatx4 d = {0.f, 0.f, 0.f, 0.f};
        #pragma unroll
        for (int kb = 0; kb < 4; kb++) {
            short8 a = *(const short8*)&SsT[(kt * 16 + l15) * 136 + kb * 32 + quad * 8];
            short8 bb = *(const short8*)&AST[(lt * 16 + l15) * 136 + kb * 32 + quad * 8];
            d = __builtin_amdgcn_mfma_f32_16x16x32_bf16(a, bb, d, 0, 0, 0);
        }
        #pragma unroll
        for (int r = 0; r < 4; r++)
            Acs[(kt * 16 + quad * 4 + r) * 33 + lt * 16 + l15] = d[r];
    }
    __syncthreads();
    float symv[4];
    {
        int l = tid & 31, kb = tid >> 5;
        for (int r = 0; r < 4; r++) {
            int k = kb + 8 * r;
            symv[r] = 0.5f * (Acs[k * 33 + l] + Acs[l * 33 + k]) + ((k == l) ? 1.f : 0.f);
        }
    }
    __syncthreads();
    {
        int l = tid & 31, kb = tid >> 5;
        for (int r = 0; r < 4; r++) Acs[(kb + 8 * r) * 33 + l] = symv[r];
    }
    __syncthreads();
    if (tid < K_) {
        float s = 0.f;
        for (int l = 0; l < K_; l++) s += Acs[tid * 33 + l];
        dinv[tid] = rsqrtf(fmaxf(s, 1e-8f));
    }
    __syncthreads();
    us* Anw = An + (size_t)win * K_ * K_;
    for (int i = tid; i < K_ * K_; i += 256) {
        int k = i >> 5, l = i & 31;
        us v = f2bf(dinv[k] * Acs[k * 33 + l] * dinv[l]);
        Anw[i] = v;
        AnL[k * 40 + l] = v;
    }
    __syncthreads();
    // ---- stage XWxb (swizzled, uint4 loads) -> XWT[jj][m] (pool reuse) ----
    {
        const uint4* xw4 = (const uint4*)((const uint2*)XWx + (size_t)win * 4096);
        for (int i2 = tid; i2 < 2048; i2 += 256) {
            uint4 v = xw4[i2];
            int i = i2 * 2;
            int tile = i >> 6, lane2 = i & 63;
            int mt2 = tile >> 5, nt2 = tile & 31;
            int jj = nt2 * 16 + (lane2 & 15);
            int m0 = mt2 * 16 + (lane2 >> 4) * 4;
            *(uint2*)&XWT[jj * 40 + m0] = make_uint2(v.x, v.y);
            int jj1 = nt2 * 16 + ((lane2 + 1) & 15);
            int m01 = mt2 * 16 + (((lane2 + 1) >> 4)) * 4;
            *(uint2*)&XWT[jj1 * 40 + m01] = make_uint2(v.z, v.w);
        }
    }
    __syncthreads();
    // ---- AXWx = An @ XWxb, stored back in-place (swizzled) ----
    short8 anA[2];
    anA[0] = *(const short8*)&AnL[l15 * 40 + quad * 8];
    anA[1] = *(const short8*)&AnL[(16 + l15) * 40 + quad * 8];
    #pragma unroll 1
    for (int i = 0; i < 8; i++) {
        const int nt = wv + 4 * i;
        short8 bfr = *(const short8*)&XWT[(nt * 16 + l15) * 40 + quad * 8];
        #pragma unroll
        for (int mt2 = 0; mt2 < 2; mt2++) {
            floatx4 a = {0.f, 0.f, 0.f, 0.f};
            a = __builtin_amdgcn_mfma_f32_16x16x32_bf16(anA[mt2], bfr, a, 0, 0, 0);
            uint2 pk;
            pk.x = (unsigned)f2bf(a[0]) | ((unsigned)f2bf(a[1]) << 16);
            pk.y = (unsigned)f2bf(a[2]) | ((unsigned)f2bf(a[3]) << 16);
            ((uint2*)XWx)[((size_t)win * 64 + mt2 * 32 + nt) * 64 + lane] = pk;
        }
    }
}

// ---------------------------------------------------------------------------
// Kernel 4: GCLSTM scan — r6 body (verified 216.0 us), untouched.
// ---------------------------------------------------------------------------
__global__ __launch_bounds__(1024) void scan_kernel(
    const us* __restrict__ An_bf,   // [bt][k][m]
    const us* __restrict__ AXWx,    // swizzled C-frag layout (gate-major jj)
    const us* __restrict__ WhT,     // [jj][h]
    float* __restrict__ Hsq2)       // [bt][2][128] partial sums (fully written)
{
    __shared__ __align__(16) us HpT[2][128 * 40];   // [h][k]
    __shared__ __align__(16) us P_lds[32 * 136];    // [k][h]

    const int tid  = threadIdx.x;
    const int lane = tid & 63;
    const int wv   = tid >> 6;          // 0..15
    const int b    = blockIdx.x;
    const int l15  = lane & 15, quad = lane >> 4;
    const int mt   = wv >> 3, hb = wv & 7;

    // Wh B-fragments: 4 gates x 4 kb = 64 VGPR
    short8 Bw[4][4];
    #pragma unroll
    for (int g4 = 0; g4 < 4; g4++) {
        const int jj = g4 * 128 + hb * 16 + l15;
        #pragma unroll
        for (int kb = 0; kb < 4; kb++)
            Bw[g4][kb] = *(const short8*)&WhT[(size_t)jj * 128 + kb * 32 + quad * 8];
    }
    // state: cells (k = mt*16 + quad*4 + r, h = hb*16 + l15)
    float Cst[4] = {0.f, 0.f, 0.f, 0.f};
    float Hst[4] = {0.f, 0.f, 0.f, 0.f};
    float H2t[4] = {0.f, 0.f, 0.f, 0.f};

    for (int i = tid; i < 2560; i += 1024) ((unsigned*)HpT[0])[i] = 0;

    const size_t bt0 = (size_t)b * WN_;
    // strength-reduced prefetch pointers (advance per step)
    const uint2* xq = (const uint2*)AXWx + (bt0 * 64 + (size_t)mt * 32 + hb) * 64 + lane;
    const us*   anp = An_bf + bt0 * 1024 + (size_t)(mt * 16 + l15) * 32 + quad * 8;

    uint2 xw[4];
    #pragma unroll
    for (int g4 = 0; g4 < 4; g4++) xw[g4] = xq[g4 * 512];
    short8 anf = *(const short8*)anp;

    #pragma unroll 1
    for (int t = 0; t < WN_; t++) {
        const int buf = t & 1;
        ldsbar();                                   // HpT[buf] ready
        // ---- P = An @ Hp (1 MFMA/wave); anf was prefetched last step ----
        short8 hpB = *(const short8*)&HpT[buf][(hb * 16 + l15) * 40 + quad * 8];
        floatx4 Pa = {0.f, 0.f, 0.f, 0.f};
        Pa = __builtin_amdgcn_mfma_f32_16x16x32_bf16(anf, hpB, Pa, 0, 0, 0);
        #pragma unroll
        for (int r = 0; r < 4; r++)
            P_lds[(mt * 16 + quad * 4 + r) * 136 + hb * 16 + l15] = f2bf(Pa[r]);
        // ---- g acc init from AXWx(t) (1-op unpacks) ----
        floatx4 gacc[4];
        #pragma unroll
        for (int g4 = 0; g4 < 4; g4++) {
            gacc[g4][0] = __uint_as_float(xw[g4].x << 16);
            gacc[g4][1] = __uint_as_float(xw[g4].x & 0xffff0000u);
            gacc[g4][2] = __uint_as_float(xw[g4].y << 16);
            gacc[g4][3] = __uint_as_float(xw[g4].y & 0xffff0000u);
        }
        // ---- prefetch t+1 (An and AXWx) — latency hides under the MFMAs ----
        if (t + 1 < WN_) { xq += 4096; anp += 1024; }
        #pragma unroll
        for (int g4 = 0; g4 < 4; g4++) xw[g4] = xq[g4 * 512];
        anf = *(const short8*)anp;
        ldsbar();                                   // P ready
        // ---- g += P @ Wh' ----
        #pragma unroll
        for (int kb = 0; kb < 4; kb++) {
            short8 pA = *(const short8*)&P_lds[(mt * 16 + l15) * 136 + kb * 32 + quad * 8];
            #pragma unroll
            for (int g4 = 0; g4 < 4; g4++)
                gacc[g4] = __builtin_amdgcn_mfma_f32_16x16x32_bf16(pA, Bw[g4][kb], gacc[g4], 0, 0, 0);
        }
        // ---- gates + state (args pre-scaled by -log2e / -2log2e) ----
        #pragma unroll
        for (int r = 0; r < 4; r++) {
            float si = rcpa(1.f + ex2(gacc[0][r]));
            float sf = rcpa(1.f + ex2(gacc[1][r]));
            float so = rcpa(1.f + ex2(gacc[2][r]));
            float tc = 2.f * rcpa(1.f + ex2(gacc[3][r])) - 1.f;
            float cn = sf * Cst[r] + si * tc;
            float tn = 2.f * rcpa(1.f + ex2(cn * SC_C)) - 1.f;
            float hn = so * tn;
            Cst[r] = cn;
            H2t[r] = Hst[r];
            Hst[r] = hn;
        }
        // ---- HpT(t+1): packed b64 write [h][4 consecutive k] ----
        if (t + 1 < WN_) {
            const float dninv = (t + 1 == 1) ? 0.5f : (1.f / 3.f);
            short4v hv;
            #pragma unroll
            for (int r = 0; r < 4; r++)
                hv[r] = (short)f2bf((2.f * Hst[r] + H2t[r]) * dninv);
            *(short4v*)&HpT[buf ^ 1][(hb * 16 + l15) * 40 + mt * 16 + quad * 4] = hv;
        }
        // ---- Hsq partial (per-mt, plain store — LAST VMEM op of the step) ----
        {
            float s = Hst[0] + Hst[1] + Hst[2] + Hst[3];
            s += __shfl_xor(s, 16); s += __shfl_xor(s, 32);
            if (quad == 0)
                Hsq2[((bt0 + t) * 2 + mt) * HID_ + hb * 16 + l15] = s;
        }
    }
}

// ---------------------------------------------------------------------------
// Kernel 5: temporal attention pooling + classifier (unchanged).
// ---------------------------------------------------------------------------
__global__ __launch_bounds__(128) void final_kernel(
    const float* __restrict__ Hsq2, const float* __restrict__ Hsm,
    const float* __restrict__ q_t, const float* __restrict__ q_s,
    const float* __restrict__ cls_w, const float* __restrict__ cls_b,
    float* __restrict__ out)
{
    __shared__ float red[128];
    __shared__ float wt[WN_];
    const int b = blockIdx.x, tid = threadIdx.x;
    float v = q_t[tid];
    red[tid] = v * v;
    __syncthreads();
    for (int off = 64; off; off >>= 1) {
        if (tid < off) red[tid] += red[tid + off];
        __syncthreads();
    }
    const float qtn = sqrtf(red[0]) + 1e-8f;
    __syncthreads();
    float v2 = (tid < D_) ? q_s[tid] : 0.f;
    red[tid] = v2 * v2;
    __syncthreads();
    for (int off = 64; off; off >>= 1) {
        if (tid < off) red[tid] += red[tid + off];
        __syncthreads();
    }
    const float qsn = sqrtf(red[0]) + 1e-8f;
    __syncthreads();
    float sc_t = -1e30f;
    if (tid < WN_) {
        float s = 0.f;
        const float* zr = Hsq2 + ((size_t)b * WN_ + tid) * (2 * HID_);
        for (int h = 0; h < HID_; h++) s += (zr[h] + zr[HID_ + h]) * q_t[h];
        sc_t = s * (1.f / 32.f) / qtn;
    }
    red[tid] = sc_t;
    __syncthreads();
    for (int off = 64; off; off >>= 1) {
        if (tid < off) red[tid] = fmaxf(red[tid], red[tid + off]);
        __syncthreads();
    }
    const float mt_ = red[0];
    __syncthreads();
    float e_t = (tid < WN_) ? expf(sc_t - mt_) : 0.f;
    red[tid] = e_t;
    __syncthreads();
    for (int off = 64; off; off >>= 1) {
        if (tid < off) red[tid] += red[tid + off];
        __syncthreads();
    }
    const float sinv_t = 1.f / red[0];
    __syncthreads();
    if (tid < WN_) wt[tid] = e_t * sinv_t;
    __syncthreads();
    float part = 0.f;
    {
        float z = 0.f;
        for (int w = 0; w < WN_; w++) {
            const float* p = Hsq2 + ((size_t)b * WN_ + w) * (2 * HID_);
            z += wt[w] * (p[tid] + p[HID_ + tid]);
        }
        part += z * (1.f / 32.f) * cls_w[tid];
    }
    __syncthreads();
    float sc_s = -1e30f;
    if (tid < WN_) {
        float s = 0.f;
        const float* zr = Hsm + ((size_t)b * WN_ + tid) * D_;
        for (int dd = 0; dd < D_; dd++) s += zr[dd] * q_s[dd];
        sc_s = s / qsn;
    }
    red[tid] = sc_s;
    __syncthreads();
    for (int off = 64; off; off >>= 1) {
        if (tid < off) red[tid] = fmaxf(red[tid], red[tid + off]);
        __syncthreads();
    }
    const float ms_ = red[0];
    __syncthreads();
    float e_s = (tid < WN_) ? expf(sc_s - ms_) : 0.f;
    red[tid] = e_s;
    __syncthreads();
    for (int off = 64; off; off >>= 1) {
        if (tid < off) red[tid] += red[tid + off];
        __syncthreads();
    }
    const float sinv_s = 1.f / red[0];
    __syncthreads();
    if (tid < WN_) wt[tid] = e_s * sinv_s;
    __syncthreads();
    if (tid < D_) {
        float z = 0.f;
        for (int w = 0; w < WN_; w++)
            z += wt[w] * Hsm[((size_t)b * WN_ + w) * D_ + tid];
        part += z * cls_w[HID_ + tid];
    }
    red[tid] = part;
    __syncthreads();
    for (int off = 64; off; off >>= 1) {
        if (tid < off) red[tid] += red[tid + off];
        __syncthreads();
    }
    if (tid == 0) out[b] = 1.f / (1.f + expf(-(red[0] + cls_b[0])));
}

// ---------------------------------------------------------------------------
extern "C" void kernel_launch(void* const* d_in, const int* in_sizes, int n_in,
                              void* d_out, int out_size, void* d_ws, size_t ws_size,
                              hipStream_t stream)
{
    (void)in_sizes; (void)n_in; (void)out_size; (void)ws_size;
    const float* x     = (const float*)d_in[0];
    const float* w1    = (const float*)d_in[1];
    const float* b1    = (const float*)d_in[2];
    const float* w2    = (const float*)d_in[3];
    const float* b2    = (const float*)d_in[4];
    const float* pw    = (const float*)d_in[5];
    const float* pb    = (const float*)d_in[6];
    const float* proto = (const float*)d_in[7];
    const float* Wx    = (const float*)d_in[8];
    const float* bx    = (const float*)d_in[9];
    const float* Wh    = (const float*)d_in[10];
    const float* bh    = (const float*)d_in[11];
    const float* q_t   = (const float*)d_in[12];
    const float* q_s   = (const float*)d_in[13];
    const float* clw   = (const float*)d_in[14];
    const float* clb   = (const float*)d_in[15];

    float* ws = (float*)d_ws;
    // (Hs region [0, 6553600) unused — conv+xcwx fused, no global Hs.)
    us*    S_bf   = (us*)(ws + 6553600);            // S^T [k][n] per win
    us*    XWx    = (us*)(ws + 9830400);            // XWxb, then AXWx in place
    us*    An_bf  = (us*)(ws + 22937600);           // [22937600, 23756800)
    float* Hsm    = ws + 23756800;                  // [23756800, 23859200)
    // Hsq2 reuses the S_bf region: S is only read by corr_kernel, which
    // completes before scan_kernel writes here (stream-ordered).
    float* Hsq2   = ws + 6553600;
    us*    WhT    = (us*)(ws + 24064000);           // [24064000, 24096768)
    us*    WxT    = (us*)(ws + 24096768);           // [24096768, 24113152)
    float* bs2    = ws + 24129536;                  // [24129536, 24130048)

    prep_kernel<<<386, 256, 0, stream>>>(Wh, Wx, bx, bh, WhT, WxT, bs2);
    convx_kernel<<<B_ * WN_, 256, 0, stream>>>(x, w1, b1, w2, b2, pw, pb,
                                               proto, WxT, bs2,
                                               S_bf, XWx, Hsm);
    corr_kernel<<<B_ * WN_, 256, 0, stream>>>(x, S_bf, An_bf, XWx);
    scan_kernel<<<B_, 1024, 0, stream>>>(An_bf, XWx, WhT, Hsq2);
    final_kernel<<<B_, 128, 0, stream>>>(Hsq2, Hsm, q_t, q_s, clw, clb,
                                         (float*)d_out);
}